// Round 2
// baseline (1538.592 us; speedup 1.0000x reference)
//
#include <hip/hip_runtime.h>

#define NUM_HEADS 16
#define HEAD_D 64
#define EMB 1024
#define SEQ 2048
#define BATCH 2
#define MTOT (BATCH * SEQ) // 4096

// ---------------------------------------------------------------------------
// fp32 tiled GEMM: C[M,N] = A[M,K] @ B[K,N] (+ bias). 64x64 tile, BK=16,
// 256 threads, 4x4 per-thread micro-tile. A staged transposed in LDS so the
// inner loop is 2x ds_read_b128 per 16 FMA.
// ---------------------------------------------------------------------------
__global__ __launch_bounds__(256) void gemm_f32(
    const float* __restrict__ A, const float* __restrict__ B,
    const float* __restrict__ bias, float* __restrict__ Cv,
    int Mdim, int Ndim, int Kdim)
{
    __shared__ float As[16][68]; // [k][m], +4 pad: 2-way worst case (free)
    __shared__ float Bs[16][64];
    const int tid = threadIdx.x;
    const int tx = tid & 15, ty = tid >> 4;
    const int row0 = blockIdx.y * 64, col0 = blockIdx.x * 64;
    float acc[4][4] = {};

    for (int k0 = 0; k0 < Kdim; k0 += 16) {
        {
            int r  = tid >> 2;         // 0..63
            int c4 = (tid & 3) << 2;   // 0,4,8,12
            float4 a = *(const float4*)&A[(size_t)(row0 + r) * Kdim + k0 + c4];
            As[c4 + 0][r] = a.x;
            As[c4 + 1][r] = a.y;
            As[c4 + 2][r] = a.z;
            As[c4 + 3][r] = a.w;
        }
        {
            int r  = tid >> 4;         // 0..15
            int c4 = (tid & 15) << 2;  // 0..60
            *(float4*)&Bs[r][c4] =
                *(const float4*)&B[(size_t)(k0 + r) * Ndim + col0 + c4];
        }
        __syncthreads();
        #pragma unroll
        for (int kk = 0; kk < 16; ++kk) {
            float4 a4 = *(const float4*)&As[kk][ty << 2];
            float4 b4 = *(const float4*)&Bs[kk][tx << 2];
            const float av[4] = {a4.x, a4.y, a4.z, a4.w};
            const float bv[4] = {b4.x, b4.y, b4.z, b4.w};
            #pragma unroll
            for (int i = 0; i < 4; ++i)
                #pragma unroll
                for (int j = 0; j < 4; ++j)
                    acc[i][j] += av[i] * bv[j];
        }
        __syncthreads();
    }

    #pragma unroll
    for (int i = 0; i < 4; ++i) {
        int row = row0 + (ty << 2) + i;
        int col = col0 + (tx << 2);
        float4 o;
        o.x = acc[i][0]; o.y = acc[i][1]; o.z = acc[i][2]; o.w = acc[i][3];
        if (bias) {
            o.x += bias[col + 0];
            o.y += bias[col + 1];
            o.z += bias[col + 2];
            o.w += bias[col + 3];
        }
        *(float4*)&Cv[(size_t)row * Ndim + col] = o;
    }
}

// ---------------------------------------------------------------------------
// fp32 flash attention, causal. One block = one (b,h) x 64-query tile.
// LDS tiles Qs/Ks/Vs/Ps are [64][64] with a 16B-granular XOR swizzle
// (col16 ^= row>>2) making every ds_read_b128 in the S and PV phases
// conflict-free. Online softmax with 16-lane shfl_xor row reductions.
// ---------------------------------------------------------------------------
__global__ __launch_bounds__(256) void attn_f32(
    const float* __restrict__ Q, const float* __restrict__ K,
    const float* __restrict__ V, float* __restrict__ O)
{
    __shared__ float Qs[64][64];
    __shared__ float Ks[64][64];
    __shared__ float Vs[64][64];
    __shared__ float Ps[64][64];

    const int qt = blockIdx.x, bh = blockIdx.y;
    const int b = bh >> 4, h = bh & 15;
    const int q0 = qt << 6;
    const size_t baseq = (size_t)b * SEQ * EMB + (size_t)h * HEAD_D;
    const int tid = threadIdx.x;
    const int tx = tid & 15, ty = tid >> 4;

    // load + scale Q tile (swizzled)
    #pragma unroll
    for (int it = 0; it < 4; ++it) {
        int idx = (it << 8) + tid;
        int i = idx >> 4, d4 = idx & 15;
        float4 v = *(const float4*)&Q[baseq + (size_t)(q0 + i) * EMB + (d4 << 2)];
        v.x *= 0.125f; v.y *= 0.125f; v.z *= 0.125f; v.w *= 0.125f;
        int ds = ((d4 ^ (i >> 2)) & 15) << 2;
        *(float4*)&Qs[i][ds] = v;
    }

    float acc[4][4] = {};
    float mrow[4], lrow[4];
    #pragma unroll
    for (int r = 0; r < 4; ++r) { mrow[r] = -1e30f; lrow[r] = 0.f; }

    for (int kt = 0; kt <= qt; ++kt) {
        const int k0 = kt << 6;
        __syncthreads(); // prev PV done with Vs/Ps
        #pragma unroll
        for (int it = 0; it < 4; ++it) {
            int idx = (it << 8) + tid;
            int i = idx >> 4, d4 = idx & 15;
            int ds = ((d4 ^ (i >> 2)) & 15) << 2;
            *(float4*)&Ks[i][ds] =
                *(const float4*)&K[baseq + (size_t)(k0 + i) * EMB + (d4 << 2)];
            *(float4*)&Vs[i][ds] =
                *(const float4*)&V[baseq + (size_t)(k0 + i) * EMB + (d4 << 2)];
        }
        __syncthreads();

        // S = Q K^T  (thread: rows ty*4+r, key cols tx*4+c)
        float s[4][4] = {};
        #pragma unroll
        for (int d4 = 0; d4 < 16; ++d4) {
            float4 q4[4], k4[4];
            #pragma unroll
            for (int r = 0; r < 4; ++r)
                q4[r] = *(const float4*)&Qs[(ty << 2) + r][((d4 ^ ty) & 15) << 2];
            #pragma unroll
            for (int c = 0; c < 4; ++c)
                k4[c] = *(const float4*)&Ks[(tx << 2) + c][((d4 ^ tx) & 15) << 2];
            #pragma unroll
            for (int r = 0; r < 4; ++r)
                #pragma unroll
                for (int c = 0; c < 4; ++c)
                    s[r][c] += q4[r].x * k4[c].x + q4[r].y * k4[c].y
                             + q4[r].z * k4[c].z + q4[r].w * k4[c].w;
        }
        if (kt == qt) { // causal mask on the diagonal tile
            #pragma unroll
            for (int r = 0; r < 4; ++r)
                #pragma unroll
                for (int c = 0; c < 4; ++c)
                    if ((tx << 2) + c > (ty << 2) + r) s[r][c] = -1e30f;
        }

        // online softmax (row groups = 16 lanes sharing ty)
        #pragma unroll
        for (int r = 0; r < 4; ++r) {
            float v = fmaxf(fmaxf(s[r][0], s[r][1]), fmaxf(s[r][2], s[r][3]));
            v = fmaxf(v, __shfl_xor(v, 1));
            v = fmaxf(v, __shfl_xor(v, 2));
            v = fmaxf(v, __shfl_xor(v, 4));
            v = fmaxf(v, __shfl_xor(v, 8));
            float nm = fmaxf(mrow[r], v);
            float sc = __expf(mrow[r] - nm);
            mrow[r] = nm;
            lrow[r] *= sc;
            acc[r][0] *= sc; acc[r][1] *= sc; acc[r][2] *= sc; acc[r][3] *= sc;
            float psum = 0.f;
            #pragma unroll
            for (int c = 0; c < 4; ++c) {
                float p = __expf(s[r][c] - nm);
                psum += p;
                Ps[(ty << 2) + r][(((tx ^ ty) & 15) << 2) + c] = p;
            }
            psum += __shfl_xor(psum, 1);
            psum += __shfl_xor(psum, 2);
            psum += __shfl_xor(psum, 4);
            psum += __shfl_xor(psum, 8);
            lrow[r] += psum;
        }
        __syncthreads(); // Ps visible to all

        // acc += P @ V  (thread: rows ty*4+r, out dims tx*4+c)
        #pragma unroll
        for (int j4 = 0; j4 < 16; ++j4) {
            float4 p4[4];
            #pragma unroll
            for (int r = 0; r < 4; ++r)
                p4[r] = *(const float4*)&Ps[(ty << 2) + r][((j4 ^ ty) & 15) << 2];
            float4 v4[4];
            #pragma unroll
            for (int jj = 0; jj < 4; ++jj)
                v4[jj] = *(const float4*)&Vs[(j4 << 2) + jj][((tx ^ j4) & 15) << 2];
            #pragma unroll
            for (int r = 0; r < 4; ++r) {
                const float* pp = (const float*)&p4[r];
                #pragma unroll
                for (int jj = 0; jj < 4; ++jj) {
                    const float* vv = (const float*)&v4[jj];
                    float pv = pp[jj];
                    acc[r][0] += pv * vv[0];
                    acc[r][1] += pv * vv[1];
                    acc[r][2] += pv * vv[2];
                    acc[r][3] += pv * vv[3];
                }
            }
        }
    }

    // epilogue: normalize and store
    #pragma unroll
    for (int r = 0; r < 4; ++r) {
        float inv = 1.f / lrow[r];
        float4 o;
        o.x = acc[r][0] * inv; o.y = acc[r][1] * inv;
        o.z = acc[r][2] * inv; o.w = acc[r][3] * inv;
        *(float4*)&O[baseq + (size_t)(q0 + (ty << 2) + r) * EMB + (tx << 2)] = o;
    }
}

// ---------------------------------------------------------------------------
extern "C" void kernel_launch(void* const* d_in, const int* in_sizes, int n_in,
                              void* d_out, int out_size, void* d_ws, size_t ws_size,
                              hipStream_t stream)
{
    const float* x  = (const float*)d_in[0];
    const float* Wq = (const float*)d_in[1];
    const float* Wk = (const float*)d_in[2];
    const float* Wv = (const float*)d_in[3];
    const float* Wo = (const float*)d_in[4];
    const float* bo = (const float*)d_in[5];
    float* out = (float*)d_out;

    // Workspace layout: Q, K, V, attn-out — 4 x 16 MB fp32.
    const size_t need = (size_t)4 * MTOT * EMB * sizeof(float);
    if (ws_size < need) return; // fail validation loudly rather than fault

    float* Qw = (float*)d_ws;
    float* Kw = Qw + (size_t)MTOT * EMB;
    float* Vw = Kw + (size_t)MTOT * EMB;
    float* Ow = Vw + (size_t)MTOT * EMB;

    dim3 gg(EMB / 64, MTOT / 64); // (16, 64)
    gemm_f32<<<gg, 256, 0, stream>>>(x,  Wq, nullptr, Qw, MTOT, EMB, EMB);
    gemm_f32<<<gg, 256, 0, stream>>>(x,  Wk, nullptr, Kw, MTOT, EMB, EMB);
    gemm_f32<<<gg, 256, 0, stream>>>(x,  Wv, nullptr, Vw, MTOT, EMB, EMB);

    attn_f32<<<dim3(SEQ / 64, BATCH * NUM_HEADS), 256, 0, stream>>>(Qw, Kw, Vw, Ow);

    gemm_f32<<<gg, 256, 0, stream>>>(Ow, Wo, bo, out, MTOT, EMB, EMB);
}

// Round 3
// 676.292 us; speedup vs baseline: 2.2750x; 2.2750x over previous
//
#include <hip/hip_runtime.h>

typedef __attribute__((ext_vector_type(8))) _Float16 f16x8;
typedef __attribute__((ext_vector_type(4))) _Float16 f16x4;
typedef __attribute__((ext_vector_type(4))) float    f32x4;

#define NUM_HEADS 16
#define HEAD_D 64
#define EMB 1024
#define SEQ 2048
#define BATCH 2
#define MTOT (BATCH * SEQ) // 4096

// ---------------------------------------------------------------------------
// fp32 tiled GEMM (final projection): C = A@B + bias. 64x64 tile, BK=16.
// ---------------------------------------------------------------------------
__global__ __launch_bounds__(256) void gemm_f32(
    const float* __restrict__ A, const float* __restrict__ B,
    const float* __restrict__ bias, float* __restrict__ Cv,
    int Mdim, int Ndim, int Kdim)
{
    __shared__ float As[16][68];
    __shared__ float Bs[16][64];
    const int tid = threadIdx.x;
    const int tx = tid & 15, ty = tid >> 4;
    const int row0 = blockIdx.y * 64, col0 = blockIdx.x * 64;
    float acc[4][4] = {};

    for (int k0 = 0; k0 < Kdim; k0 += 16) {
        {
            int r  = tid >> 2;
            int c4 = (tid & 3) << 2;
            float4 a = *(const float4*)&A[(size_t)(row0 + r) * Kdim + k0 + c4];
            As[c4 + 0][r] = a.x; As[c4 + 1][r] = a.y;
            As[c4 + 2][r] = a.z; As[c4 + 3][r] = a.w;
        }
        {
            int r  = tid >> 4;
            int c4 = (tid & 15) << 2;
            *(float4*)&Bs[r][c4] =
                *(const float4*)&B[(size_t)(k0 + r) * Ndim + col0 + c4];
        }
        __syncthreads();
        #pragma unroll
        for (int kk = 0; kk < 16; ++kk) {
            float4 a4 = *(const float4*)&As[kk][ty << 2];
            float4 b4 = *(const float4*)&Bs[kk][tx << 2];
            const float av[4] = {a4.x, a4.y, a4.z, a4.w};
            const float bv[4] = {b4.x, b4.y, b4.z, b4.w};
            #pragma unroll
            for (int i = 0; i < 4; ++i)
                #pragma unroll
                for (int j = 0; j < 4; ++j)
                    acc[i][j] += av[i] * bv[j];
        }
        __syncthreads();
    }

    #pragma unroll
    for (int i = 0; i < 4; ++i) {
        int row = row0 + (ty << 2) + i;
        int col = col0 + (tx << 2);
        float4 o;
        o.x = acc[i][0]; o.y = acc[i][1]; o.z = acc[i][2]; o.w = acc[i][3];
        if (bias) {
            o.x += bias[col + 0]; o.y += bias[col + 1];
            o.z += bias[col + 2]; o.w += bias[col + 3];
        }
        *(float4*)&Cv[(size_t)row * Ndim + col] = o;
    }
}

// ---------------------------------------------------------------------------
// QKV projection GEMM: fp32 compute, writes fp16 in [B,H,T,D] layout with
// optional alpha scale (Q gets 1/sqrt(D) folded in). M=MTOT,N=EMB,K=EMB.
// ---------------------------------------------------------------------------
__global__ __launch_bounds__(256) void gemm_qkv_f16(
    const float* __restrict__ A, const float* __restrict__ B,
    _Float16* __restrict__ Outh, float alpha)
{
    __shared__ float As[16][68];
    __shared__ float Bs[16][64];
    const int tid = threadIdx.x;
    const int tx = tid & 15, ty = tid >> 4;
    const int row0 = blockIdx.y * 64, col0 = blockIdx.x * 64;
    float acc[4][4] = {};

    for (int k0 = 0; k0 < EMB; k0 += 16) {
        {
            int r  = tid >> 2;
            int c4 = (tid & 3) << 2;
            float4 a = *(const float4*)&A[(size_t)(row0 + r) * EMB + k0 + c4];
            As[c4 + 0][r] = a.x; As[c4 + 1][r] = a.y;
            As[c4 + 2][r] = a.z; As[c4 + 3][r] = a.w;
        }
        {
            int r  = tid >> 4;
            int c4 = (tid & 15) << 2;
            *(float4*)&Bs[r][c4] =
                *(const float4*)&B[(size_t)(k0 + r) * EMB + col0 + c4];
        }
        __syncthreads();
        #pragma unroll
        for (int kk = 0; kk < 16; ++kk) {
            float4 a4 = *(const float4*)&As[kk][ty << 2];
            float4 b4 = *(const float4*)&Bs[kk][tx << 2];
            const float av[4] = {a4.x, a4.y, a4.z, a4.w};
            const float bv[4] = {b4.x, b4.y, b4.z, b4.w};
            #pragma unroll
            for (int i = 0; i < 4; ++i)
                #pragma unroll
                for (int j = 0; j < 4; ++j)
                    acc[i][j] += av[i] * bv[j];
        }
        __syncthreads();
    }

    // epilogue: out[b, h, t, d] = fp16(acc * alpha)
    #pragma unroll
    for (int i = 0; i < 4; ++i) {
        int row = row0 + (ty << 2) + i;       // token index
        int b = row >> 11, t = row & 2047;
        int col = col0 + (tx << 2);
        int h = col >> 6, dl = col & 63;
        f16x4 o;
        o[0] = (_Float16)(acc[i][0] * alpha);
        o[1] = (_Float16)(acc[i][1] * alpha);
        o[2] = (_Float16)(acc[i][2] * alpha);
        o[3] = (_Float16)(acc[i][3] * alpha);
        *(f16x4*)&Outh[(((size_t)(b * NUM_HEADS + h)) * SEQ + t) * HEAD_D + dl] = o;
    }
}

// ---------------------------------------------------------------------------
// Flash attention, causal, fp16 MFMA (16x16x32, fp32 accum).
// Block = 4 waves = one (b,h) x 64-query tile. Wave w owns q rows w*16..+15.
// K in LDS [kv][d] XOR-swizzled; V in LDS transposed [d][kv] XOR-swizzled;
// P round-trips through wave-private LDS to reshape C/D-layout -> A-frag.
// ---------------------------------------------------------------------------
__global__ __launch_bounds__(256) void attn_mfma(
    const _Float16* __restrict__ Qh, const _Float16* __restrict__ Kh,
    const _Float16* __restrict__ Vh, float* __restrict__ O)
{
    __shared__ char lds[24 * 1024];
    char* Ks = lds;             // 8 KB: K[kv][d]  (64 rows x 128 B, swizzled)
    char* Vt = lds + 8192;      // 8 KB: V^T[d][kv] (64 rows x 128 B, swizzled)
    char* Pw = lds + 16384;     // 8 KB: per-wave P[16][64] f16 (2 KB each)

    const int qt = blockIdx.x, bh = blockIdx.y;
    const int q0 = qt << 6;
    const int tid = threadIdx.x;
    const int w = tid >> 6, lane = tid & 63;
    const int l15 = lane & 15, g = lane >> 4;

    const size_t headbase = (size_t)bh * SEQ * HEAD_D;

    // Q fragments for this wave's 16 rows (held in registers all loop long).
    // A-frag convention: lane holds m = lane&15, 8 contiguous k at 8*(lane>>4).
    const int qrow = q0 + (w << 4) + l15;
    f16x8 qf0 = *(const f16x8*)&Qh[headbase + (size_t)qrow * HEAD_D + (g << 3)];
    f16x8 qf1 = *(const f16x8*)&Qh[headbase + (size_t)qrow * HEAD_D + 32 + (g << 3)];

    f32x4 acc_o[4];
    #pragma unroll
    for (int dn = 0; dn < 4; ++dn) acc_o[dn] = (f32x4){0.f, 0.f, 0.f, 0.f};
    float mreg[4], lreg[4];
    #pragma unroll
    for (int r = 0; r < 4; ++r) { mreg[r] = -1e30f; lreg[r] = 0.f; }

    for (int kt = 0; kt <= qt; ++kt) {
        const int kv0 = kt << 6;
        __syncthreads(); // previous iteration done reading Ks/Vt
        // ---- stage K (row-major, swizzled) and V (transposed, swizzled) ----
        #pragma unroll
        for (int i = 0; i < 2; ++i) {
            int c = (i << 8) + tid;      // 512 chunks of 16 B
            int row = c >> 3, u = c & 7; // kv row, 16B-unit (8 d's)
            f16x8 k8 = *(const f16x8*)&Kh[headbase + (size_t)(kv0 + row) * HEAD_D + (u << 3)];
            *(f16x8*)&Ks[row * 128 + ((u ^ (row & 7)) << 4)] = k8;
            f16x8 v8 = *(const f16x8*)&Vh[headbase + (size_t)(kv0 + row) * HEAD_D + (u << 3)];
            #pragma unroll
            for (int j = 0; j < 8; ++j) {
                int d = (u << 3) + j;
                *(_Float16*)&Vt[d * 128 + ((row << 1) ^ ((d & 7) << 4))] = v8[j];
            }
        }
        __syncthreads();

        // ---- S = Q K^T : 4 column tiles x 2 chained MFMAs (K=64) ----
        f32x4 sa[4];
        #pragma unroll
        for (int nt = 0; nt < 4; ++nt) {
            int kvl = (nt << 4) + l15; // B-frag: lane holds n = kv col
            f16x8 kf0 = *(const f16x8*)&Ks[kvl * 128 + (((g << 4)) ^ ((kvl & 7) << 4))];
            f16x8 kf1 = *(const f16x8*)&Ks[kvl * 128 + ((64 + (g << 4)) ^ ((kvl & 7) << 4))];
            f32x4 z = (f32x4){0.f, 0.f, 0.f, 0.f};
            z = __builtin_amdgcn_mfma_f32_16x16x32_f16(qf0, kf0, z, 0, 0, 0);
            z = __builtin_amdgcn_mfma_f32_16x16x32_f16(qf1, kf1, z, 0, 0, 0);
            sa[nt] = z;
        }

        // causal mask (diagonal tile only). C/D: col=lane&15 (kv), row=4g+reg (q).
        if (kt == qt) {
            #pragma unroll
            for (int nt = 0; nt < 4; ++nt)
                #pragma unroll
                for (int r = 0; r < 4; ++r) {
                    int kva = kv0 + (nt << 4) + l15;
                    int qa  = q0 + (w << 4) + (g << 2) + r;
                    if (kva > qa) sa[nt][r] = -1e30f;
                }
        }

        // ---- online softmax; rows live in 16-lane groups ----
        #pragma unroll
        for (int r = 0; r < 4; ++r) {
            float mx = fmaxf(fmaxf(sa[0][r], sa[1][r]), fmaxf(sa[2][r], sa[3][r]));
            mx = fmaxf(mx, __shfl_xor(mx, 1));
            mx = fmaxf(mx, __shfl_xor(mx, 2));
            mx = fmaxf(mx, __shfl_xor(mx, 4));
            mx = fmaxf(mx, __shfl_xor(mx, 8));
            float nm = fmaxf(mreg[r], mx);
            float sc = __expf(mreg[r] - nm);
            mreg[r] = nm;
            float ps = 0.f;
            #pragma unroll
            for (int nt = 0; nt < 4; ++nt) {
                float p = __expf(sa[nt][r] - nm);
                sa[nt][r] = p;
                ps += p;
            }
            ps += __shfl_xor(ps, 1);
            ps += __shfl_xor(ps, 2);
            ps += __shfl_xor(ps, 4);
            ps += __shfl_xor(ps, 8);
            lreg[r] = lreg[r] * sc + ps;
            acc_o[0][r] *= sc; acc_o[1][r] *= sc;
            acc_o[2][r] *= sc; acc_o[3][r] *= sc;
        }

        // ---- P -> wave-private LDS (reshape C/D layout -> A-frag layout) ----
        char* pwv = Pw + (w << 11);
        #pragma unroll
        for (int nt = 0; nt < 4; ++nt)
            #pragma unroll
            for (int r = 0; r < 4; ++r) {
                int q = (g << 2) + r;
                int kvl = (nt << 4) + l15;
                *(_Float16*)&pwv[q * 128 + ((kvl << 1) ^ ((q & 7) << 4))] =
                    (_Float16)sa[nt][r];
            }
        // same-wave read-back (compiler inserts lgkmcnt wait)
        f16x8 pa0 = *(const f16x8*)&pwv[l15 * 128 + (((g << 4)) ^ ((l15 & 7) << 4))];
        f16x8 pa1 = *(const f16x8*)&pwv[l15 * 128 + ((64 + (g << 4)) ^ ((l15 & 7) << 4))];

        // ---- acc_o += P @ V : 4 d-tiles x 2 chained MFMAs (K=64 kv) ----
        #pragma unroll
        for (int dn = 0; dn < 4; ++dn) {
            int d = (dn << 4) + l15; // B-frag: lane holds n = d col
            f16x8 vf0 = *(const f16x8*)&Vt[d * 128 + (((g << 4)) ^ ((d & 7) << 4))];
            f16x8 vf1 = *(const f16x8*)&Vt[d * 128 + ((64 + (g << 4)) ^ ((d & 7) << 4))];
            acc_o[dn] = __builtin_amdgcn_mfma_f32_16x16x32_f16(pa0, vf0, acc_o[dn], 0, 0, 0);
            acc_o[dn] = __builtin_amdgcn_mfma_f32_16x16x32_f16(pa1, vf1, acc_o[dn], 0, 0, 0);
        }
    }

    // ---- epilogue: normalize, write fp32 O[tok][h*64+d] ----
    const int b = bh >> 4, h = bh & 15;
    #pragma unroll
    for (int r = 0; r < 4; ++r) {
        float inv = 1.f / lreg[r];
        int tok = (b << 11) + q0 + (w << 4) + (g << 2) + r;
        #pragma unroll
        for (int dn = 0; dn < 4; ++dn)
            O[(size_t)tok * EMB + (h << 6) + (dn << 4) + l15] = acc_o[dn][r] * inv;
    }
}

// ---------------------------------------------------------------------------
extern "C" void kernel_launch(void* const* d_in, const int* in_sizes, int n_in,
                              void* d_out, int out_size, void* d_ws, size_t ws_size,
                              hipStream_t stream)
{
    const float* x  = (const float*)d_in[0];
    const float* Wq = (const float*)d_in[1];
    const float* Wk = (const float*)d_in[2];
    const float* Wv = (const float*)d_in[3];
    const float* Wo = (const float*)d_in[4];
    const float* bo = (const float*)d_in[5];
    float* out = (float*)d_out;

    // Workspace: Qh,Kh,Vh fp16 [B,H,T,D] (8 MB each) + Ow fp32 (16 MB) = 40 MB
    const size_t headElems = (size_t)BATCH * NUM_HEADS * SEQ * HEAD_D; // 4M
    const size_t need = 3 * headElems * sizeof(_Float16)
                      + (size_t)MTOT * EMB * sizeof(float);
    if (ws_size < need) return;

    _Float16* Qhp = (_Float16*)d_ws;
    _Float16* Khp = Qhp + headElems;
    _Float16* Vhp = Khp + headElems;
    float*    Ow  = (float*)(Vhp + headElems);

    dim3 gg(EMB / 64, MTOT / 64); // (16, 64)
    gemm_qkv_f16<<<gg, 256, 0, stream>>>(x, Wq, Qhp, 0.125f); // 1/sqrt(64)
    gemm_qkv_f16<<<gg, 256, 0, stream>>>(x, Wk, Khp, 1.0f);
    gemm_qkv_f16<<<gg, 256, 0, stream>>>(x, Wv, Vhp, 1.0f);

    attn_mfma<<<dim3(SEQ / 64, BATCH * NUM_HEADS), 256, 0, stream>>>(Qhp, Khp, Vhp, Ow);

    gemm_f32<<<gg, 256, 0, stream>>>(Ow, Wo, bo, out, MTOT, EMB, EMB);
}

// Round 5
// 241.665 us; speedup vs baseline: 6.3666x; 2.7985x over previous
//
#include <hip/hip_runtime.h>

typedef __attribute__((ext_vector_type(8))) _Float16 f16x8;
typedef __attribute__((ext_vector_type(4))) _Float16 f16x4;
typedef __attribute__((ext_vector_type(4))) float    f32x4;

#define NUM_HEADS 16
#define HEAD_D 64
#define EMB 1024
#define SEQ 2048
#define BATCH 2
#define MTOT (BATCH * SEQ) // 4096

// ---------------------------------------------------------------------------
// global -> LDS direct staging (16 B per lane). LDS dest is wave-uniform
// base + lane*16 (HW behavior); fallback reg-stages to the same address.
// ---------------------------------------------------------------------------
#if defined(__has_builtin)
#if __has_builtin(__builtin_amdgcn_global_load_lds)
#define HAVE_GLOAD_LDS 1
#endif
#endif

__device__ __forceinline__ void stage16(const void* g, void* ldsWaveBase, int lane)
{
#ifdef HAVE_GLOAD_LDS
    __builtin_amdgcn_global_load_lds(
        (const __attribute__((address_space(1))) void*)g,
        (__attribute__((address_space(3))) void*)ldsWaveBase, 16, 0, 0);
    (void)lane;
#else
    *(f16x8*)((char*)ldsWaveBase + lane * 16) = *(const f16x8*)g;
#endif
}

// ---------------------------------------------------------------------------
// cast fp32 -> fp16, 8 elems/thread
// ---------------------------------------------------------------------------
__global__ __launch_bounds__(256) void cast_f32_f16(
    const float* __restrict__ in, _Float16* __restrict__ out)
{
    int i = blockIdx.x * blockDim.x + threadIdx.x;
    float4 a = ((const float4*)in)[i * 2];
    float4 b = ((const float4*)in)[i * 2 + 1];
    f16x8 o;
    o[0] = (_Float16)a.x; o[1] = (_Float16)a.y;
    o[2] = (_Float16)a.z; o[3] = (_Float16)a.w;
    o[4] = (_Float16)b.x; o[5] = (_Float16)b.y;
    o[6] = (_Float16)b.z; o[7] = (_Float16)b.w;
    ((f16x8*)out)[i] = o;
}

// ---------------------------------------------------------------------------
// W [K=1024][N=1024] fp32 -> Wt [N][K] fp16 (tiled transpose, 32x32)
// ---------------------------------------------------------------------------
__global__ __launch_bounds__(256) void transpose_w(
    const float* __restrict__ W, _Float16* __restrict__ Wt)
{
    __shared__ float tile[32][33];
    const int tx = threadIdx.x, ty = threadIdx.y; // (32, 8)
    const int n0 = blockIdx.x * 32, k0 = blockIdx.y * 32;
    #pragma unroll
    for (int j = 0; j < 4; ++j)
        tile[ty + j * 8][tx] = W[(size_t)(k0 + ty + j * 8) * EMB + n0 + tx];
    __syncthreads();
    #pragma unroll
    for (int j = 0; j < 4; ++j)
        Wt[(size_t)(n0 + ty + j * 8) * EMB + k0 + tx] =
            (_Float16)tile[tx][ty + j * 8];
}

// ---------------------------------------------------------------------------
// fp16 MFMA GEMM: C[M,N] = A[M,K=1024] @ Bt[N,K]^T.
// 128x128 tile, BK=32, 4 waves (2x2), wave tile 64x64 = 4x4 16x16 frags.
// MODE 0: N=3072 fused QKV -> writes fp16 [B,H,T,D], alpha=0.125 on Q.
// MODE 1: N=1024 -> writes fp32 out + bias.
// ---------------------------------------------------------------------------
template <int MODE>
__global__ __launch_bounds__(256) void gemm_mfma(
    const _Float16* __restrict__ A, const _Float16* __restrict__ Bt,
    _Float16* __restrict__ Qh, _Float16* __restrict__ Kh,
    _Float16* __restrict__ Vh,
    float* __restrict__ outf, const float* __restrict__ bias)
{
    __shared__ __align__(16) _Float16 As[128 * 32]; // 8 KB, row-major [m][k]
    __shared__ __align__(16) _Float16 Bs[128 * 32]; // 8 KB, row-major [n][k]

    const int tid = threadIdx.x;
    const int w = tid >> 6, lane = tid & 63;
    const int l15 = lane & 15, g4 = lane >> 4;
    const int wm = w >> 1, wn = w & 1;
    const int row0 = blockIdx.y * 128, col0 = blockIdx.x * 128;

    f32x4 acc[4][4];
    #pragma unroll
    for (int mt = 0; mt < 4; ++mt)
        #pragma unroll
        for (int nt = 0; nt < 4; ++nt)
            acc[mt][nt] = (f32x4){0.f, 0.f, 0.f, 0.f};

    for (int k0 = 0; k0 < EMB; k0 += 32) {
        __syncthreads(); // previous compute done; safe to overwrite tiles
        #pragma unroll
        for (int i = 0; i < 2; ++i) {
            int c = (i << 8) + tid;       // 16B chunk id, 0..511
            int row = c >> 2, u = c & 3;  // row 0..127, 16B-unit in k
            stage16(&A[(size_t)(row0 + row) * EMB + k0 + (u << 3)],
                    (char*)As + (i << 12) + (w << 10), lane);
            stage16(&Bt[(size_t)(col0 + row) * EMB + k0 + (u << 3)],
                    (char*)Bs + (i << 12) + (w << 10), lane);
        }
        __syncthreads(); // staging visible (compiler drains vmcnt pre-barrier)

        f16x8 af[4], bf[4];
        #pragma unroll
        for (int mt = 0; mt < 4; ++mt)
            af[mt] = *(const f16x8*)((const char*)As +
                     ((wm << 6) + (mt << 4) + l15) * 64 + (g4 << 4));
        #pragma unroll
        for (int nt = 0; nt < 4; ++nt)
            bf[nt] = *(const f16x8*)((const char*)Bs +
                     ((wn << 6) + (nt << 4) + l15) * 64 + (g4 << 4));
        #pragma unroll
        for (int mt = 0; mt < 4; ++mt)
            #pragma unroll
            for (int nt = 0; nt < 4; ++nt)
                acc[mt][nt] = __builtin_amdgcn_mfma_f32_16x16x32_f16(
                    af[mt], bf[nt], acc[mt][nt], 0, 0, 0);
    }

    // Epilogue. C/D layout: col = lane&15, row = 4*(lane>>4) + reg.
    #pragma unroll
    for (int mt = 0; mt < 4; ++mt) {
        int m = row0 + (wm << 6) + (mt << 4) + (g4 << 2);
        #pragma unroll
        for (int nt = 0; nt < 4; ++nt) {
            int gcol = col0 + (wn << 6) + (nt << 4) + l15;
            if (MODE == 0) {
                int proj = gcol >> 10, pc = gcol & 1023;
                int h = pc >> 6, d = pc & 63;
                _Float16* dst = proj == 0 ? Qh : (proj == 1 ? Kh : Vh);
                float alpha = proj == 0 ? 0.125f : 1.0f;
                int b = m >> 11, t = m & 2047;
                #pragma unroll
                for (int r = 0; r < 4; ++r)
                    dst[(((size_t)(b * NUM_HEADS + h)) * SEQ + t + r) * HEAD_D + d] =
                        (_Float16)(acc[mt][nt][r] * alpha);
            } else {
                float bz = bias[gcol];
                #pragma unroll
                for (int r = 0; r < 4; ++r)
                    outf[(size_t)(m + r) * EMB + gcol] = acc[mt][nt][r] + bz;
            }
        }
    }
}

// ---------------------------------------------------------------------------
// Flash attention, causal, fp16 MFMA (16x16x32, fp32 accum). Output fp16
// [M][EMB] (feeds final GEMM directly).
// ---------------------------------------------------------------------------
__global__ __launch_bounds__(256) void attn_mfma(
    const _Float16* __restrict__ Qh, const _Float16* __restrict__ Kh,
    const _Float16* __restrict__ Vh, _Float16* __restrict__ O)
{
    __shared__ char lds[24 * 1024];
    char* Ks = lds;             // 8 KB: K[kv][d]  (64 rows x 128 B, swizzled)
    char* Vt = lds + 8192;      // 8 KB: V^T[d][kv] (64 rows x 128 B, swizzled)
    char* Pw = lds + 16384;     // 8 KB: per-wave P[16][64] f16 (2 KB each)

    const int qt = blockIdx.x, bh = blockIdx.y;
    const int q0 = qt << 6;
    const int tid = threadIdx.x;
    const int w = tid >> 6, lane = tid & 63;
    const int l15 = lane & 15, g = lane >> 4;

    const size_t headbase = (size_t)bh * SEQ * HEAD_D;

    const int qrow = q0 + (w << 4) + l15;
    f16x8 qf0 = *(const f16x8*)&Qh[headbase + (size_t)qrow * HEAD_D + (g << 3)];
    f16x8 qf1 = *(const f16x8*)&Qh[headbase + (size_t)qrow * HEAD_D + 32 + (g << 3)];

    f32x4 acc_o[4];
    #pragma unroll
    for (int dn = 0; dn < 4; ++dn) acc_o[dn] = (f32x4){0.f, 0.f, 0.f, 0.f};
    float mreg[4], lreg[4];
    #pragma unroll
    for (int r = 0; r < 4; ++r) { mreg[r] = -1e30f; lreg[r] = 0.f; }

    for (int kt = 0; kt <= qt; ++kt) {
        const int kv0 = kt << 6;
        __syncthreads();
        #pragma unroll
        for (int i = 0; i < 2; ++i) {
            int c = (i << 8) + tid;
            int row = c >> 3, u = c & 7;
            f16x8 k8 = *(const f16x8*)&Kh[headbase + (size_t)(kv0 + row) * HEAD_D + (u << 3)];
            *(f16x8*)&Ks[row * 128 + ((u ^ (row & 7)) << 4)] = k8;
            f16x8 v8 = *(const f16x8*)&Vh[headbase + (size_t)(kv0 + row) * HEAD_D + (u << 3)];
            #pragma unroll
            for (int j = 0; j < 8; ++j) {
                int d = (u << 3) + j;
                *(_Float16*)&Vt[d * 128 + ((row << 1) ^ ((d & 7) << 4))] = v8[j];
            }
        }
        __syncthreads();

        f32x4 sa[4];
        #pragma unroll
        for (int nt = 0; nt < 4; ++nt) {
            int kvl = (nt << 4) + l15;
            f16x8 kf0 = *(const f16x8*)&Ks[kvl * 128 + (((g << 4)) ^ ((kvl & 7) << 4))];
            f16x8 kf1 = *(const f16x8*)&Ks[kvl * 128 + ((64 + (g << 4)) ^ ((kvl & 7) << 4))];
            f32x4 z = (f32x4){0.f, 0.f, 0.f, 0.f};
            z = __builtin_amdgcn_mfma_f32_16x16x32_f16(qf0, kf0, z, 0, 0, 0);
            z = __builtin_amdgcn_mfma_f32_16x16x32_f16(qf1, kf1, z, 0, 0, 0);
            sa[nt] = z;
        }

        if (kt == qt) {
            #pragma unroll
            for (int nt = 0; nt < 4; ++nt)
                #pragma unroll
                for (int r = 0; r < 4; ++r) {
                    int kva = kv0 + (nt << 4) + l15;
                    int qa  = q0 + (w << 4) + (g << 2) + r;
                    if (kva > qa) sa[nt][r] = -1e30f;
                }
        }

        #pragma unroll
        for (int r = 0; r < 4; ++r) {
            float mx = fmaxf(fmaxf(sa[0][r], sa[1][r]), fmaxf(sa[2][r], sa[3][r]));
            mx = fmaxf(mx, __shfl_xor(mx, 1));
            mx = fmaxf(mx, __shfl_xor(mx, 2));
            mx = fmaxf(mx, __shfl_xor(mx, 4));
            mx = fmaxf(mx, __shfl_xor(mx, 8));
            float nm = fmaxf(mreg[r], mx);
            float sc = __expf(mreg[r] - nm);
            mreg[r] = nm;
            float ps = 0.f;
            #pragma unroll
            for (int nt = 0; nt < 4; ++nt) {
                float p = __expf(sa[nt][r] - nm);
                sa[nt][r] = p;
                ps += p;
            }
            ps += __shfl_xor(ps, 1);
            ps += __shfl_xor(ps, 2);
            ps += __shfl_xor(ps, 4);
            ps += __shfl_xor(ps, 8);
            lreg[r] = lreg[r] * sc + ps;
            acc_o[0][r] *= sc; acc_o[1][r] *= sc;
            acc_o[2][r] *= sc; acc_o[3][r] *= sc;
        }

        char* pwv = Pw + (w << 11);
        #pragma unroll
        for (int nt = 0; nt < 4; ++nt)
            #pragma unroll
            for (int r = 0; r < 4; ++r) {
                int q = (g << 2) + r;
                int kvl = (nt << 4) + l15;
                *(_Float16*)&pwv[q * 128 + ((kvl << 1) ^ ((q & 7) << 4))] =
                    (_Float16)sa[nt][r];
            }
        f16x8 pa0 = *(const f16x8*)&pwv[l15 * 128 + (((g << 4)) ^ ((l15 & 7) << 4))];
        f16x8 pa1 = *(const f16x8*)&pwv[l15 * 128 + ((64 + (g << 4)) ^ ((l15 & 7) << 4))];

        #pragma unroll
        for (int dn = 0; dn < 4; ++dn) {
            int d = (dn << 4) + l15;
            f16x8 vf0 = *(const f16x8*)&Vt[d * 128 + (((g << 4)) ^ ((d & 7) << 4))];
            f16x8 vf1 = *(const f16x8*)&Vt[d * 128 + ((64 + (g << 4)) ^ ((d & 7) << 4))];
            acc_o[dn] = __builtin_amdgcn_mfma_f32_16x16x32_f16(pa0, vf0, acc_o[dn], 0, 0, 0);
            acc_o[dn] = __builtin_amdgcn_mfma_f32_16x16x32_f16(pa1, vf1, acc_o[dn], 0, 0, 0);
        }
    }

    const int b = bh >> 4, h = bh & 15;
    #pragma unroll
    for (int r = 0; r < 4; ++r) {
        float inv = 1.f / lreg[r];
        int tok = (b << 11) + q0 + (w << 4) + (g << 2) + r;
        #pragma unroll
        for (int dn = 0; dn < 4; ++dn)
            O[(size_t)tok * EMB + (h << 6) + (dn << 4) + l15] =
                (_Float16)(acc_o[dn][r] * inv);
    }
}

// ---------------------------------------------------------------------------
extern "C" void kernel_launch(void* const* d_in, const int* in_sizes, int n_in,
                              void* d_out, int out_size, void* d_ws, size_t ws_size,
                              hipStream_t stream)
{
    const float* x  = (const float*)d_in[0];
    const float* Wq = (const float*)d_in[1];
    const float* Wk = (const float*)d_in[2];
    const float* Wv = (const float*)d_in[3];
    const float* Wo = (const float*)d_in[4];
    const float* bo = (const float*)d_in[5];
    float* out = (float*)d_out;

    // Workspace layout (fp16):
    //  xh  [4096][1024]           8 MB
    //  Wt  [3072][1024]           6 MB  (Wq^T | Wk^T | Wv^T)
    //  Wto [1024][1024]           2 MB
    //  Qh,Kh,Vh [B,H,T,D] = 4M ea 8 MB each = 24 MB   (FIX: ME each, not ME/4)
    //  Ow  [4096][1024]           8 MB
    const size_t ME = (size_t)MTOT * EMB;        // 4M elems
    const size_t WE = (size_t)EMB * EMB;         // 1M elems
    const size_t need = (ME + 3 * WE + WE + 3 * ME + ME) * sizeof(_Float16);
    if (ws_size < need) return;

    _Float16* xh  = (_Float16*)d_ws;
    _Float16* Wt  = xh + ME;
    _Float16* Wto = Wt + 3 * WE;
    _Float16* Qh  = Wto + WE;
    _Float16* Kh  = Qh + ME;   // FIX: was Qh + ME/4 (Q/K/V overlapped)
    _Float16* Vh  = Kh + ME;
    _Float16* Ow  = Vh + ME;

    // prep: cast x, transpose+cast weights
    cast_f32_f16<<<(int)(ME / 8 / 256), 256, 0, stream>>>(x, xh);
    dim3 tb(32, 8), tg(EMB / 32, EMB / 32);
    transpose_w<<<tg, tb, 0, stream>>>(Wq, Wt);
    transpose_w<<<tg, tb, 0, stream>>>(Wk, Wt + WE);
    transpose_w<<<tg, tb, 0, stream>>>(Wv, Wt + 2 * WE);
    transpose_w<<<tg, tb, 0, stream>>>(Wo, Wto);

    // fused QKV projection: [4096, 3072]
    gemm_mfma<0><<<dim3(3 * EMB / 128, MTOT / 128), 256, 0, stream>>>(
        xh, Wt, Qh, Kh, Vh, nullptr, nullptr);

    attn_mfma<<<dim3(SEQ / 64, BATCH * NUM_HEADS), 256, 0, stream>>>(Qh, Kh, Vh, Ow);

    // output projection + bias: [4096, 1024] fp32
    gemm_mfma<1><<<dim3(EMB / 128, MTOT / 128), 256, 0, stream>>>(
        Ow, Wto, nullptr, nullptr, nullptr, out, bo);
}

// Round 6
// 210.683 us; speedup vs baseline: 7.3029x; 1.1471x over previous
//
#include <hip/hip_runtime.h>

typedef __attribute__((ext_vector_type(8))) _Float16 f16x8;
typedef __attribute__((ext_vector_type(4))) _Float16 f16x4;
typedef __attribute__((ext_vector_type(4))) float    f32x4;

#define NUM_HEADS 16
#define HEAD_D 64
#define EMB 1024
#define SEQ 2048
#define BATCH 2
#define MTOT (BATCH * SEQ) // 4096

// ---------------------------------------------------------------------------
// global -> LDS direct staging (16 B per lane). LDS dest is wave-uniform
// base + lane*16 (HW behavior); fallback reg-stages to the same address.
// ---------------------------------------------------------------------------
#if defined(__has_builtin)
#if __has_builtin(__builtin_amdgcn_global_load_lds)
#define HAVE_GLOAD_LDS 1
#endif
#endif

__device__ __forceinline__ void stage16(const void* g, void* ldsWaveBase, int lane)
{
#ifdef HAVE_GLOAD_LDS
    __builtin_amdgcn_global_load_lds(
        (const __attribute__((address_space(1))) void*)g,
        (__attribute__((address_space(3))) void*)ldsWaveBase, 16, 0, 0);
    (void)lane;
#else
    *(f16x8*)((char*)ldsWaveBase + lane * 16) = *(const f16x8*)g;
#endif
}

// ---------------------------------------------------------------------------
// cast fp32 -> fp16, 8 elems/thread
// ---------------------------------------------------------------------------
__global__ __launch_bounds__(256) void cast_f32_f16(
    const float* __restrict__ in, _Float16* __restrict__ out)
{
    int i = blockIdx.x * blockDim.x + threadIdx.x;
    float4 a = ((const float4*)in)[i * 2];
    float4 b = ((const float4*)in)[i * 2 + 1];
    f16x8 o;
    o[0] = (_Float16)a.x; o[1] = (_Float16)a.y;
    o[2] = (_Float16)a.z; o[3] = (_Float16)a.w;
    o[4] = (_Float16)b.x; o[5] = (_Float16)b.y;
    o[6] = (_Float16)b.z; o[7] = (_Float16)b.w;
    ((f16x8*)out)[i] = o;
}

// ---------------------------------------------------------------------------
// W [K=1024][N=1024] fp32 -> Wt [N][K] fp16 (tiled transpose, 32x32)
// ---------------------------------------------------------------------------
__global__ __launch_bounds__(256) void transpose_w(
    const float* __restrict__ W, _Float16* __restrict__ Wt)
{
    __shared__ float tile[32][33];
    const int tx = threadIdx.x, ty = threadIdx.y; // (32, 8)
    const int n0 = blockIdx.x * 32, k0 = blockIdx.y * 32;
    #pragma unroll
    for (int j = 0; j < 4; ++j)
        tile[ty + j * 8][tx] = W[(size_t)(k0 + ty + j * 8) * EMB + n0 + tx];
    __syncthreads();
    #pragma unroll
    for (int j = 0; j < 4; ++j)
        Wt[(size_t)(n0 + ty + j * 8) * EMB + k0 + tx] =
            (_Float16)tile[tx][ty + j * 8];
}

// ---------------------------------------------------------------------------
// fp16 MFMA GEMM: C[M,N] = A[M,K=1024] @ Bt[N,K]^T.
// 128x128 tile, BK=32, 4 waves (2x2), wave tile 64x64 = 4x4 16x16 frags.
// MODE 0: N=3072 fused QKV -> writes fp16 [B,H,T,D], alpha=0.125 on Q.
// MODE 1: N=1024 -> writes fp32 out + bias.
// ---------------------------------------------------------------------------
template <int MODE>
__global__ __launch_bounds__(256) void gemm_mfma(
    const _Float16* __restrict__ A, const _Float16* __restrict__ Bt,
    _Float16* __restrict__ Qh, _Float16* __restrict__ Kh,
    _Float16* __restrict__ Vh,
    float* __restrict__ outf, const float* __restrict__ bias)
{
    __shared__ __align__(16) _Float16 As[128 * 32]; // 8 KB, row-major [m][k]
    __shared__ __align__(16) _Float16 Bs[128 * 32]; // 8 KB, row-major [n][k]

    const int tid = threadIdx.x;
    const int w = tid >> 6, lane = tid & 63;
    const int l15 = lane & 15, g4 = lane >> 4;
    const int wm = w >> 1, wn = w & 1;
    const int row0 = blockIdx.y * 128, col0 = blockIdx.x * 128;

    f32x4 acc[4][4];
    #pragma unroll
    for (int mt = 0; mt < 4; ++mt)
        #pragma unroll
        for (int nt = 0; nt < 4; ++nt)
            acc[mt][nt] = (f32x4){0.f, 0.f, 0.f, 0.f};

    for (int k0 = 0; k0 < EMB; k0 += 32) {
        __syncthreads(); // previous compute done; safe to overwrite tiles
        #pragma unroll
        for (int i = 0; i < 2; ++i) {
            int c = (i << 8) + tid;       // 16B chunk id, 0..511
            int row = c >> 2, u = c & 3;  // row 0..127, 16B-unit in k
            stage16(&A[(size_t)(row0 + row) * EMB + k0 + (u << 3)],
                    (char*)As + (i << 12) + (w << 10), lane);
            stage16(&Bt[(size_t)(col0 + row) * EMB + k0 + (u << 3)],
                    (char*)Bs + (i << 12) + (w << 10), lane);
        }
        __syncthreads(); // staging visible (compiler drains vmcnt pre-barrier)

        f16x8 af[4], bf[4];
        #pragma unroll
        for (int mt = 0; mt < 4; ++mt)
            af[mt] = *(const f16x8*)((const char*)As +
                     ((wm << 6) + (mt << 4) + l15) * 64 + (g4 << 4));
        #pragma unroll
        for (int nt = 0; nt < 4; ++nt)
            bf[nt] = *(const f16x8*)((const char*)Bs +
                     ((wn << 6) + (nt << 4) + l15) * 64 + (g4 << 4));
        #pragma unroll
        for (int mt = 0; mt < 4; ++mt)
            #pragma unroll
            for (int nt = 0; nt < 4; ++nt)
                acc[mt][nt] = __builtin_amdgcn_mfma_f32_16x16x32_f16(
                    af[mt], bf[nt], acc[mt][nt], 0, 0, 0);
    }

    // Epilogue. C/D layout: col = lane&15, row = 4*(lane>>4) + reg.
    #pragma unroll
    for (int mt = 0; mt < 4; ++mt) {
        int m = row0 + (wm << 6) + (mt << 4) + (g4 << 2);
        #pragma unroll
        for (int nt = 0; nt < 4; ++nt) {
            int gcol = col0 + (wn << 6) + (nt << 4) + l15;
            if (MODE == 0) {
                int proj = gcol >> 10, pc = gcol & 1023;
                int h = pc >> 6, d = pc & 63;
                _Float16* dst = proj == 0 ? Qh : (proj == 1 ? Kh : Vh);
                float alpha = proj == 0 ? 0.125f : 1.0f;
                int b = m >> 11, t = m & 2047;
                #pragma unroll
                for (int r = 0; r < 4; ++r)
                    dst[(((size_t)(b * NUM_HEADS + h)) * SEQ + t + r) * HEAD_D + d] =
                        (_Float16)(acc[mt][nt][r] * alpha);
            } else {
                float bz = bias[gcol];
                #pragma unroll
                for (int r = 0; r < 4; ++r)
                    outf[(size_t)(m + r) * EMB + gcol] = acc[mt][nt][r] + bz;
            }
        }
    }
}

// ---------------------------------------------------------------------------
// Flash attention, causal, fp16 MFMA (16x16x32, fp32 accum). Output fp16.
// R6 changes: (1) V^T LDS swizzle now folds d>>3 into the bank bits
// (was 16-way conflicted per ds_write_b16: bank bits only carried d&7,
// which is constant per scatter instruction); (2) qt reversed so the
// longest causal blocks dispatch first (tail balance).
// ---------------------------------------------------------------------------
__global__ __launch_bounds__(256) void attn_mfma(
    const _Float16* __restrict__ Qh, const _Float16* __restrict__ Kh,
    const _Float16* __restrict__ Vh, _Float16* __restrict__ O)
{
    __shared__ char lds[24 * 1024];
    char* Ks = lds;             // 8 KB: K[kv][d]  (64 rows x 128 B, swizzled)
    char* Vt = lds + 8192;      // 8 KB: V^T[d][kv] (64 rows x 128 B, swizzled)
    char* Pw = lds + 16384;     // 8 KB: per-wave P[16][64] f16 (2 KB each)

    const int qt = gridDim.x - 1 - blockIdx.x; // heavy tiles first
    const int bh = blockIdx.y;
    const int q0 = qt << 6;
    const int tid = threadIdx.x;
    const int w = tid >> 6, lane = tid & 63;
    const int l15 = lane & 15, g = lane >> 4;

    const size_t headbase = (size_t)bh * SEQ * HEAD_D;

    const int qrow = q0 + (w << 4) + l15;
    f16x8 qf0 = *(const f16x8*)&Qh[headbase + (size_t)qrow * HEAD_D + (g << 3)];
    f16x8 qf1 = *(const f16x8*)&Qh[headbase + (size_t)qrow * HEAD_D + 32 + (g << 3)];

    f32x4 acc_o[4];
    #pragma unroll
    for (int dn = 0; dn < 4; ++dn) acc_o[dn] = (f32x4){0.f, 0.f, 0.f, 0.f};
    float mreg[4], lreg[4];
    #pragma unroll
    for (int r = 0; r < 4; ++r) { mreg[r] = -1e30f; lreg[r] = 0.f; }

    for (int kt = 0; kt <= qt; ++kt) {
        const int kv0 = kt << 6;
        __syncthreads();
        #pragma unroll
        for (int i = 0; i < 2; ++i) {
            int c = (i << 8) + tid;
            int row = c >> 3, u = c & 7;
            f16x8 k8 = *(const f16x8*)&Kh[headbase + (size_t)(kv0 + row) * HEAD_D + (u << 3)];
            *(f16x8*)&Ks[row * 128 + ((u ^ (row & 7)) << 4)] = k8;
            f16x8 v8 = *(const f16x8*)&Vh[headbase + (size_t)(kv0 + row) * HEAD_D + (u << 3)];
            #pragma unroll
            for (int j = 0; j < 8; ++j) {
                int d = (u << 3) + j;
                // bank-spread: fold u=d>>3 in, else all lanes share bank bits
                *(_Float16*)&Vt[d * 128 +
                    ((row << 1) ^ ((((d & 7) ^ (d >> 3)) & 7) << 4))] = v8[j];
            }
        }
        __syncthreads();

        f32x4 sa[4];
        #pragma unroll
        for (int nt = 0; nt < 4; ++nt) {
            int kvl = (nt << 4) + l15;
            f16x8 kf0 = *(const f16x8*)&Ks[kvl * 128 + (((g << 4)) ^ ((kvl & 7) << 4))];
            f16x8 kf1 = *(const f16x8*)&Ks[kvl * 128 + ((64 + (g << 4)) ^ ((kvl & 7) << 4))];
            f32x4 z = (f32x4){0.f, 0.f, 0.f, 0.f};
            z = __builtin_amdgcn_mfma_f32_16x16x32_f16(qf0, kf0, z, 0, 0, 0);
            z = __builtin_amdgcn_mfma_f32_16x16x32_f16(qf1, kf1, z, 0, 0, 0);
            sa[nt] = z;
        }

        if (kt == qt) {
            #pragma unroll
            for (int nt = 0; nt < 4; ++nt)
                #pragma unroll
                for (int r = 0; r < 4; ++r) {
                    int kva = kv0 + (nt << 4) + l15;
                    int qa  = q0 + (w << 4) + (g << 2) + r;
                    if (kva > qa) sa[nt][r] = -1e30f;
                }
        }

        #pragma unroll
        for (int r = 0; r < 4; ++r) {
            float mx = fmaxf(fmaxf(sa[0][r], sa[1][r]), fmaxf(sa[2][r], sa[3][r]));
            mx = fmaxf(mx, __shfl_xor(mx, 1));
            mx = fmaxf(mx, __shfl_xor(mx, 2));
            mx = fmaxf(mx, __shfl_xor(mx, 4));
            mx = fmaxf(mx, __shfl_xor(mx, 8));
            float nm = fmaxf(mreg[r], mx);
            float sc = __expf(mreg[r] - nm);
            mreg[r] = nm;
            float ps = 0.f;
            #pragma unroll
            for (int nt = 0; nt < 4; ++nt) {
                float p = __expf(sa[nt][r] - nm);
                sa[nt][r] = p;
                ps += p;
            }
            ps += __shfl_xor(ps, 1);
            ps += __shfl_xor(ps, 2);
            ps += __shfl_xor(ps, 4);
            ps += __shfl_xor(ps, 8);
            lreg[r] = lreg[r] * sc + ps;
            acc_o[0][r] *= sc; acc_o[1][r] *= sc;
            acc_o[2][r] *= sc; acc_o[3][r] *= sc;
        }

        char* pwv = Pw + (w << 11);
        #pragma unroll
        for (int nt = 0; nt < 4; ++nt)
            #pragma unroll
            for (int r = 0; r < 4; ++r) {
                int q = (g << 2) + r;
                int kvl = (nt << 4) + l15;
                *(_Float16*)&pwv[q * 128 + ((kvl << 1) ^ ((q & 7) << 4))] =
                    (_Float16)sa[nt][r];
            }
        f16x8 pa0 = *(const f16x8*)&pwv[l15 * 128 + (((g << 4)) ^ ((l15 & 7) << 4))];
        f16x8 pa1 = *(const f16x8*)&pwv[l15 * 128 + ((64 + (g << 4)) ^ ((l15 & 7) << 4))];

        #pragma unroll
        for (int dn = 0; dn < 4; ++dn) {
            int d = (dn << 4) + l15;
            int swz = ((d & 7) ^ (d >> 3)) & 7;
            f16x8 vf0 = *(const f16x8*)&Vt[d * 128 + (((g << 4)) ^ (swz << 4))];
            f16x8 vf1 = *(const f16x8*)&Vt[d * 128 + ((64 + (g << 4)) ^ (swz << 4))];
            acc_o[dn] = __builtin_amdgcn_mfma_f32_16x16x32_f16(pa0, vf0, acc_o[dn], 0, 0, 0);
            acc_o[dn] = __builtin_amdgcn_mfma_f32_16x16x32_f16(pa1, vf1, acc_o[dn], 0, 0, 0);
        }
    }

    const int b = bh >> 4, h = bh & 15;
    #pragma unroll
    for (int r = 0; r < 4; ++r) {
        float inv = 1.f / lreg[r];
        int tok = (b << 11) + q0 + (w << 4) + (g << 2) + r;
        #pragma unroll
        for (int dn = 0; dn < 4; ++dn)
            O[(size_t)tok * EMB + (h << 6) + (dn << 4) + l15] =
                (_Float16)(acc_o[dn][r] * inv);
    }
}

// ---------------------------------------------------------------------------
extern "C" void kernel_launch(void* const* d_in, const int* in_sizes, int n_in,
                              void* d_out, int out_size, void* d_ws, size_t ws_size,
                              hipStream_t stream)
{
    const float* x  = (const float*)d_in[0];
    const float* Wq = (const float*)d_in[1];
    const float* Wk = (const float*)d_in[2];
    const float* Wv = (const float*)d_in[3];
    const float* Wo = (const float*)d_in[4];
    const float* bo = (const float*)d_in[5];
    float* out = (float*)d_out;

    const size_t ME = (size_t)MTOT * EMB;        // 4M elems
    const size_t WE = (size_t)EMB * EMB;         // 1M elems
    const size_t need = (ME + 3 * WE + WE + 3 * ME + ME) * sizeof(_Float16);
    if (ws_size < need) return;

    _Float16* xh  = (_Float16*)d_ws;
    _Float16* Wt  = xh + ME;
    _Float16* Wto = Wt + 3 * WE;
    _Float16* Qh  = Wto + WE;
    _Float16* Kh  = Qh + ME;
    _Float16* Vh  = Kh + ME;
    _Float16* Ow  = Vh + ME;

    cast_f32_f16<<<(int)(ME / 8 / 256), 256, 0, stream>>>(x, xh);
    dim3 tb(32, 8), tg(EMB / 32, EMB / 32);
    transpose_w<<<tg, tb, 0, stream>>>(Wq, Wt);
    transpose_w<<<tg, tb, 0, stream>>>(Wk, Wt + WE);
    transpose_w<<<tg, tb, 0, stream>>>(Wv, Wt + 2 * WE);
    transpose_w<<<tg, tb, 0, stream>>>(Wo, Wto);

    gemm_mfma<0><<<dim3(3 * EMB / 128, MTOT / 128), 256, 0, stream>>>(
        xh, Wt, Qh, Kh, Vh, nullptr, nullptr);

    attn_mfma<<<dim3(SEQ / 64, BATCH * NUM_HEADS), 256, 0, stream>>>(Qh, Kh, Vh, Ow);

    gemm_mfma<1><<<dim3(EMB / 128, MTOT / 128), 256, 0, stream>>>(
        Ow, Wto, nullptr, nullptr, nullptr, out, bo);
}

// Round 7
// 169.588 us; speedup vs baseline: 9.0725x; 1.2423x over previous
//
#include <hip/hip_runtime.h>

typedef __attribute__((ext_vector_type(8))) _Float16 f16x8;
typedef __attribute__((ext_vector_type(4))) _Float16 f16x4;
typedef __attribute__((ext_vector_type(2))) _Float16 f16x2;
typedef __attribute__((ext_vector_type(4))) float    f32x4;

#define NUM_HEADS 16
#define HEAD_D 64
#define EMB 1024
#define SEQ 2048
#define BATCH 2
#define MTOT (BATCH * SEQ) // 4096

// ---------------------------------------------------------------------------
// global -> LDS direct staging (16 B per lane). LDS dest is wave-uniform
// base + lane*16 (HW behavior); fallback reg-stages to the same address.
// ---------------------------------------------------------------------------
#if defined(__has_builtin)
#if __has_builtin(__builtin_amdgcn_global_load_lds)
#define HAVE_GLOAD_LDS 1
#endif
#endif

__device__ __forceinline__ void stage16(const void* g, void* ldsWaveBase, int lane)
{
#ifdef HAVE_GLOAD_LDS
    __builtin_amdgcn_global_load_lds(
        (const __attribute__((address_space(1))) void*)g,
        (__attribute__((address_space(3))) void*)ldsWaveBase, 16, 0, 0);
    (void)lane;
#else
    *(f16x8*)((char*)ldsWaveBase + lane * 16) = *(const f16x8*)g;
#endif
}

// ---------------------------------------------------------------------------
// cast fp32 -> fp16, 8 elems/thread
// ---------------------------------------------------------------------------
__global__ __launch_bounds__(256) void cast_f32_f16(
    const float* __restrict__ in, _Float16* __restrict__ out)
{
    int i = blockIdx.x * blockDim.x + threadIdx.x;
    float4 a = ((const float4*)in)[i * 2];
    float4 b = ((const float4*)in)[i * 2 + 1];
    f16x8 o;
    o[0] = (_Float16)a.x; o[1] = (_Float16)a.y;
    o[2] = (_Float16)a.z; o[3] = (_Float16)a.w;
    o[4] = (_Float16)b.x; o[5] = (_Float16)b.y;
    o[6] = (_Float16)b.z; o[7] = (_Float16)b.w;
    ((f16x8*)out)[i] = o;
}

// ---------------------------------------------------------------------------
// W [K=1024][N=1024] fp32 -> Wt [N][K] fp16 (tiled transpose, 32x32)
// ---------------------------------------------------------------------------
__global__ __launch_bounds__(256) void transpose_w(
    const float* __restrict__ W, _Float16* __restrict__ Wt)
{
    __shared__ float tile[32][33];
    const int tx = threadIdx.x, ty = threadIdx.y; // (32, 8)
    const int n0 = blockIdx.x * 32, k0 = blockIdx.y * 32;
    #pragma unroll
    for (int j = 0; j < 4; ++j)
        tile[ty + j * 8][tx] = W[(size_t)(k0 + ty + j * 8) * EMB + n0 + tx];
    __syncthreads();
    #pragma unroll
    for (int j = 0; j < 4; ++j)
        Wt[(size_t)(n0 + ty + j * 8) * EMB + k0 + tx] =
            (_Float16)tile[tx][ty + j * 8];
}

// ---------------------------------------------------------------------------
// fp16 MFMA GEMM: C[M,N] = A[M,K=1024] @ Bt[N,K]^T.
// 128x128 tile, BK=32, 4 waves (2x2), wave tile 64x64 = 4x4 16x16 frags.
// MODE 0: N=3072 fused QKV -> writes fp16 [B,H,T,D], alpha=0.125 on Q.
// MODE 1: N=1024 -> writes fp32 out + bias.
// ---------------------------------------------------------------------------
template <int MODE>
__global__ __launch_bounds__(256) void gemm_mfma(
    const _Float16* __restrict__ A, const _Float16* __restrict__ Bt,
    _Float16* __restrict__ Qh, _Float16* __restrict__ Kh,
    _Float16* __restrict__ Vh,
    float* __restrict__ outf, const float* __restrict__ bias)
{
    __shared__ __align__(16) _Float16 As[128 * 32]; // 8 KB, row-major [m][k]
    __shared__ __align__(16) _Float16 Bs[128 * 32]; // 8 KB, row-major [n][k]

    const int tid = threadIdx.x;
    const int w = tid >> 6, lane = tid & 63;
    const int l15 = lane & 15, g4 = lane >> 4;
    const int wm = w >> 1, wn = w & 1;
    const int row0 = blockIdx.y * 128, col0 = blockIdx.x * 128;

    f32x4 acc[4][4];
    #pragma unroll
    for (int mt = 0; mt < 4; ++mt)
        #pragma unroll
        for (int nt = 0; nt < 4; ++nt)
            acc[mt][nt] = (f32x4){0.f, 0.f, 0.f, 0.f};

    for (int k0 = 0; k0 < EMB; k0 += 32) {
        __syncthreads(); // previous compute done; safe to overwrite tiles
        #pragma unroll
        for (int i = 0; i < 2; ++i) {
            int c = (i << 8) + tid;       // 16B chunk id, 0..511
            int row = c >> 2, u = c & 3;  // row 0..127, 16B-unit in k
            stage16(&A[(size_t)(row0 + row) * EMB + k0 + (u << 3)],
                    (char*)As + (i << 12) + (w << 10), lane);
            stage16(&Bt[(size_t)(col0 + row) * EMB + k0 + (u << 3)],
                    (char*)Bs + (i << 12) + (w << 10), lane);
        }
        __syncthreads(); // staging visible (compiler drains vmcnt pre-barrier)

        f16x8 af[4], bf[4];
        #pragma unroll
        for (int mt = 0; mt < 4; ++mt)
            af[mt] = *(const f16x8*)((const char*)As +
                     ((wm << 6) + (mt << 4) + l15) * 64 + (g4 << 4));
        #pragma unroll
        for (int nt = 0; nt < 4; ++nt)
            bf[nt] = *(const f16x8*)((const char*)Bs +
                     ((wn << 6) + (nt << 4) + l15) * 64 + (g4 << 4));
        #pragma unroll
        for (int mt = 0; mt < 4; ++mt)
            #pragma unroll
            for (int nt = 0; nt < 4; ++nt)
                acc[mt][nt] = __builtin_amdgcn_mfma_f32_16x16x32_f16(
                    af[mt], bf[nt], acc[mt][nt], 0, 0, 0);
    }

    // Epilogue. C/D layout: col = lane&15, row = 4*(lane>>4) + reg.
    #pragma unroll
    for (int mt = 0; mt < 4; ++mt) {
        int m = row0 + (wm << 6) + (mt << 4) + (g4 << 2);
        #pragma unroll
        for (int nt = 0; nt < 4; ++nt) {
            int gcol = col0 + (wn << 6) + (nt << 4) + l15;
            if (MODE == 0) {
                int proj = gcol >> 10, pc = gcol & 1023;
                int h = pc >> 6, d = pc & 63;
                _Float16* dst = proj == 0 ? Qh : (proj == 1 ? Kh : Vh);
                float alpha = proj == 0 ? 0.125f : 1.0f;
                int b = m >> 11, t = m & 2047;
                #pragma unroll
                for (int r = 0; r < 4; ++r)
                    dst[(((size_t)(b * NUM_HEADS + h)) * SEQ + t + r) * HEAD_D + d] =
                        (_Float16)(acc[mt][nt][r] * alpha);
            } else {
                float bz = bias[gcol];
                #pragma unroll
                for (int r = 0; r < 4; ++r)
                    outf[(size_t)(m + r) * EMB + gcol] = acc[mt][nt][r] + bz;
            }
        }
    }
}

// ---------------------------------------------------------------------------
// Flash attention, causal, fp16 MFMA. R7 restructure:
//  - Double-buffered K/V LDS (2x16 KB): global loads for tile kt+1 issued at
//    iteration top into regs, ds_written to buf[cur^1] after compute; ONE
//    barrier per iteration. Global latency hides under compute.
//  - Swapped QK^T: S^T = mfma(K_frag, Q_frag) (A/B frags share per-lane
//    layout, so the same registers work). Each lane owns one q-row ->
//    softmax = in-register 16-reduce + 2 shfl_xor; m/l are scalars.
//    Per-C/D-row scale factors redistributed with 4 __shfl.
//  - PV and epilogue unchanged from R6 (verified address formulas).
// ---------------------------------------------------------------------------
__global__ __launch_bounds__(256) void attn_mfma(
    const _Float16* __restrict__ Qh, const _Float16* __restrict__ Kh,
    const _Float16* __restrict__ Vh, _Float16* __restrict__ O)
{
    __shared__ char lds[40 * 1024];
    // Ks buf b at b*8192; Vt buf b at 16384 + b*8192; Pw at 32768 (2KB/wave)

    const int qt = gridDim.x - 1 - blockIdx.x; // heavy tiles first
    const int bh = blockIdx.y;
    const int q0 = qt << 6;
    const int tid = threadIdx.x;
    const int w = tid >> 6, lane = tid & 63;
    const int l15 = lane & 15, g = lane >> 4;

    const size_t headbase = (size_t)bh * SEQ * HEAD_D;

    // Q fragment (lane -> q row l15 of wave tile, k = d at 8g / 32+8g)
    const int qrow = q0 + (w << 4) + l15;
    f16x8 qf0 = *(const f16x8*)&Qh[headbase + (size_t)qrow * HEAD_D + (g << 3)];
    f16x8 qf1 = *(const f16x8*)&Qh[headbase + (size_t)qrow * HEAD_D + 32 + (g << 3)];

    f32x4 acc_o[4];
    #pragma unroll
    for (int dn = 0; dn < 4; ++dn) acc_o[dn] = (f32x4){0.f, 0.f, 0.f, 0.f};
    float mreg = -1e30f, lreg = 0.f; // per-lane: this lane's q row

    const int c0 = tid, c1 = 256 + tid;
    const int row_a = c0 >> 3, u_a = c0 & 7; // staging chunk A
    const int row_b = c1 >> 3, u_b = c1 & 7; // staging chunk B

    // ---- prologue: stage tile 0 into buffer 0 ----
    {
        f16x8 k8a = *(const f16x8*)&Kh[headbase + (size_t)row_a * HEAD_D + (u_a << 3)];
        f16x8 v8a = *(const f16x8*)&Vh[headbase + (size_t)row_a * HEAD_D + (u_a << 3)];
        f16x8 k8b = *(const f16x8*)&Kh[headbase + (size_t)row_b * HEAD_D + (u_b << 3)];
        f16x8 v8b = *(const f16x8*)&Vh[headbase + (size_t)row_b * HEAD_D + (u_b << 3)];
        char* Ks0 = lds;
        char* Vt0 = lds + 16384;
        *(f16x8*)&Ks0[row_a * 128 + ((u_a ^ (row_a & 7)) << 4)] = k8a;
        *(f16x8*)&Ks0[row_b * 128 + ((u_b ^ (row_b & 7)) << 4)] = k8b;
        #pragma unroll
        for (int j = 0; j < 8; ++j) {
            int da = (u_a << 3) + j, db = (u_b << 3) + j;
            *(_Float16*)&Vt0[da * 128 +
                ((row_a << 1) ^ ((((da & 7) ^ (da >> 3)) & 7) << 4))] = v8a[j];
            *(_Float16*)&Vt0[db * 128 +
                ((row_b << 1) ^ ((((db & 7) ^ (db >> 3)) & 7) << 4))] = v8b[j];
        }
    }
    __syncthreads();

    int cur = 0;
    for (int kt = 0; kt <= qt; ++kt) {
        const int kv0 = kt << 6;
        const bool have_next = (kt < qt);

        // ---- issue next tile's global loads early (latency hides) ----
        f16x8 k8a, v8a, k8b, v8b;
        if (have_next) {
            const size_t nb = headbase + (size_t)((kt + 1) << 6) * HEAD_D;
            k8a = *(const f16x8*)&Kh[nb + (size_t)row_a * HEAD_D + (u_a << 3)];
            v8a = *(const f16x8*)&Vh[nb + (size_t)row_a * HEAD_D + (u_a << 3)];
            k8b = *(const f16x8*)&Kh[nb + (size_t)row_b * HEAD_D + (u_b << 3)];
            v8b = *(const f16x8*)&Vh[nb + (size_t)row_b * HEAD_D + (u_b << 3)];
        }

        char* KsC = lds + (cur << 13);
        char* VtC = lds + 16384 + (cur << 13);

        // ---- S^T = K Q^T : lane holds q = q0+16w+l15; kv = 16nt+4g+r ----
        f32x4 st[4];
        #pragma unroll
        for (int nt = 0; nt < 4; ++nt) {
            int kvl = (nt << 4) + l15;
            f16x8 kf0 = *(const f16x8*)&KsC[kvl * 128 + (((g << 4)) ^ ((kvl & 7) << 4))];
            f16x8 kf1 = *(const f16x8*)&KsC[kvl * 128 + ((64 + (g << 4)) ^ ((kvl & 7) << 4))];
            f32x4 z = (f32x4){0.f, 0.f, 0.f, 0.f};
            z = __builtin_amdgcn_mfma_f32_16x16x32_f16(kf0, qf0, z, 0, 0, 0);
            z = __builtin_amdgcn_mfma_f32_16x16x32_f16(kf1, qf1, z, 0, 0, 0);
            st[nt] = z;
        }

        // causal mask on diagonal tile
        if (kt == qt) {
            const int qa = q0 + (w << 4) + l15;
            #pragma unroll
            for (int nt = 0; nt < 4; ++nt)
                #pragma unroll
                for (int r = 0; r < 4; ++r) {
                    int kva = kv0 + (nt << 4) + (g << 2) + r;
                    if (kva > qa) st[nt][r] = -1e30f;
                }
        }

        // ---- online softmax: in-register 16-reduce + 2 shuffles ----
        float mx;
        {
            float a0 = fmaxf(fmaxf(st[0][0], st[0][1]), fmaxf(st[0][2], st[0][3]));
            float a1 = fmaxf(fmaxf(st[1][0], st[1][1]), fmaxf(st[1][2], st[1][3]));
            float a2 = fmaxf(fmaxf(st[2][0], st[2][1]), fmaxf(st[2][2], st[2][3]));
            float a3 = fmaxf(fmaxf(st[3][0], st[3][1]), fmaxf(st[3][2], st[3][3]));
            mx = fmaxf(fmaxf(a0, a1), fmaxf(a2, a3));
        }
        mx = fmaxf(mx, __shfl_xor(mx, 16));
        mx = fmaxf(mx, __shfl_xor(mx, 32));
        const float nm = fmaxf(mreg, mx);
        const float sc = __expf(mreg - nm);
        mreg = nm;
        float ps = 0.f;
        #pragma unroll
        for (int nt = 0; nt < 4; ++nt)
            #pragma unroll
            for (int r = 0; r < 4; ++r) {
                float p = __expf(st[nt][r] - nm);
                st[nt][r] = p;
                ps += p;
            }
        ps += __shfl_xor(ps, 16);
        ps += __shfl_xor(ps, 32);
        lreg = lreg * sc + ps;

        // redistribute scale to C/D rows (q = 4g + r lives in lane 4g+r)
        #pragma unroll
        for (int r = 0; r < 4; ++r) {
            float scr = __shfl(sc, (g << 2) + r);
            acc_o[0][r] *= scr; acc_o[1][r] *= scr;
            acc_o[2][r] *= scr; acc_o[3][r] *= scr;
        }

        // ---- P -> wave-private LDS as P[q][kv] (8x b32 writes) ----
        char* pwv = lds + 32768 + (w << 11);
        #pragma unroll
        for (int nt = 0; nt < 4; ++nt)
            #pragma unroll
            for (int rr = 0; rr < 2; ++rr) {
                int kvb = (nt << 4) + (g << 2) + (rr << 1); // even kv base
                f16x2 pv;
                pv[0] = (_Float16)st[nt][rr * 2];
                pv[1] = (_Float16)st[nt][rr * 2 + 1];
                *(f16x2*)&pwv[l15 * 128 + ((kvb << 1) ^ ((l15 & 7) << 4))] = pv;
            }
        f16x8 pa0 = *(const f16x8*)&pwv[l15 * 128 + (((g << 4)) ^ ((l15 & 7) << 4))];
        f16x8 pa1 = *(const f16x8*)&pwv[l15 * 128 + ((64 + (g << 4)) ^ ((l15 & 7) << 4))];

        // ---- acc_o += P @ V ----
        #pragma unroll
        for (int dn = 0; dn < 4; ++dn) {
            int d = (dn << 4) + l15;
            int swz = ((d & 7) ^ (d >> 3)) & 7;
            f16x8 vf0 = *(const f16x8*)&VtC[d * 128 + (((g << 4)) ^ (swz << 4))];
            f16x8 vf1 = *(const f16x8*)&VtC[d * 128 + ((64 + (g << 4)) ^ (swz << 4))];
            acc_o[dn] = __builtin_amdgcn_mfma_f32_16x16x32_f16(pa0, vf0, acc_o[dn], 0, 0, 0);
            acc_o[dn] = __builtin_amdgcn_mfma_f32_16x16x32_f16(pa1, vf1, acc_o[dn], 0, 0, 0);
        }

        // ---- write staged regs into the other buffer ----
        if (have_next) {
            char* KsN = lds + ((cur ^ 1) << 13);
            char* VtN = lds + 16384 + ((cur ^ 1) << 13);
            *(f16x8*)&KsN[row_a * 128 + ((u_a ^ (row_a & 7)) << 4)] = k8a;
            *(f16x8*)&KsN[row_b * 128 + ((u_b ^ (row_b & 7)) << 4)] = k8b;
            #pragma unroll
            for (int j = 0; j < 8; ++j) {
                int da = (u_a << 3) + j, db = (u_b << 3) + j;
                *(_Float16*)&VtN[da * 128 +
                    ((row_a << 1) ^ ((((da & 7) ^ (da >> 3)) & 7) << 4))] = v8a[j];
                *(_Float16*)&VtN[db * 128 +
                    ((row_b << 1) ^ ((((db & 7) ^ (db >> 3)) & 7) << 4))] = v8b[j];
            }
        }
        __syncthreads();
        cur ^= 1;
    }

    // ---- epilogue: normalize, write fp16 O[tok][h*64+d] ----
    const int b = bh >> 4, h = bh & 15;
    const float rl = 1.f / lreg;
    #pragma unroll
    for (int r = 0; r < 4; ++r) {
        float inv = __shfl(rl, (g << 2) + r); // 1/l for q row 4g+r
        int tok = (b << 11) + q0 + (w << 4) + (g << 2) + r;
        #pragma unroll
        for (int dn = 0; dn < 4; ++dn)
            O[(size_t)tok * EMB + (h << 6) + (dn << 4) + l15] =
                (_Float16)(acc_o[dn][r] * inv);
    }
}

// ---------------------------------------------------------------------------
extern "C" void kernel_launch(void* const* d_in, const int* in_sizes, int n_in,
                              void* d_out, int out_size, void* d_ws, size_t ws_size,
                              hipStream_t stream)
{
    const float* x  = (const float*)d_in[0];
    const float* Wq = (const float*)d_in[1];
    const float* Wk = (const float*)d_in[2];
    const float* Wv = (const float*)d_in[3];
    const float* Wo = (const float*)d_in[4];
    const float* bo = (const float*)d_in[5];
    float* out = (float*)d_out;

    const size_t ME = (size_t)MTOT * EMB;        // 4M elems
    const size_t WE = (size_t)EMB * EMB;         // 1M elems
    const size_t need = (ME + 3 * WE + WE + 3 * ME + ME) * sizeof(_Float16);
    if (ws_size < need) return;

    _Float16* xh  = (_Float16*)d_ws;
    _Float16* Wt  = xh + ME;
    _Float16* Wto = Wt + 3 * WE;
    _Float16* Qh  = Wto + WE;
    _Float16* Kh  = Qh + ME;
    _Float16* Vh  = Kh + ME;
    _Float16* Ow  = Vh + ME;

    cast_f32_f16<<<(int)(ME / 8 / 256), 256, 0, stream>>>(x, xh);
    dim3 tb(32, 8), tg(EMB / 32, EMB / 32);
    transpose_w<<<tg, tb, 0, stream>>>(Wq, Wt);
    transpose_w<<<tg, tb, 0, stream>>>(Wk, Wt + WE);
    transpose_w<<<tg, tb, 0, stream>>>(Wv, Wt + 2 * WE);
    transpose_w<<<tg, tb, 0, stream>>>(Wo, Wto);

    gemm_mfma<0><<<dim3(3 * EMB / 128, MTOT / 128), 256, 0, stream>>>(
        xh, Wt, Qh, Kh, Vh, nullptr, nullptr);

    attn_mfma<<<dim3(SEQ / 64, BATCH * NUM_HEADS), 256, 0, stream>>>(Qh, Kh, Vh, Ow);

    gemm_mfma<1><<<dim3(EMB / 128, MTOT / 128), 256, 0, stream>>>(
        Ow, Wto, nullptr, nullptr, nullptr, out, bo);
}

// Round 8
// 135.172 us; speedup vs baseline: 11.3824x; 1.2546x over previous
//
#include <hip/hip_runtime.h>

typedef __attribute__((ext_vector_type(8))) _Float16 f16x8;
typedef __attribute__((ext_vector_type(4))) _Float16 f16x4;
typedef __attribute__((ext_vector_type(2))) _Float16 f16x2;
typedef __attribute__((ext_vector_type(4))) float    f32x4;

#define NUM_HEADS 16
#define HEAD_D 64
#define EMB 1024
#define SEQ 2048
#define BATCH 2
#define MTOT (BATCH * SEQ) // 4096

// ---------------------------------------------------------------------------
// global -> LDS direct staging (16 B per lane). LDS dest is wave-uniform
// base + lane*16 (HW behavior); fallback reg-stages to the same address.
// ---------------------------------------------------------------------------
#if defined(__has_builtin)
#if __has_builtin(__builtin_amdgcn_global_load_lds)
#define HAVE_GLOAD_LDS 1
#endif
#endif

__device__ __forceinline__ void stage16(const void* g, void* ldsWaveBase, int lane)
{
#ifdef HAVE_GLOAD_LDS
    __builtin_amdgcn_global_load_lds(
        (const __attribute__((address_space(1))) void*)g,
        (__attribute__((address_space(3))) void*)ldsWaveBase, 16, 0, 0);
    (void)lane;
#else
    *(f16x8*)((char*)ldsWaveBase + lane * 16) = *(const f16x8*)g;
#endif
}

// ---------------------------------------------------------------------------
// cast fp32 -> fp16, 8 elems/thread
// ---------------------------------------------------------------------------
__global__ __launch_bounds__(256) void cast_f32_f16(
    const float* __restrict__ in, _Float16* __restrict__ out)
{
    int i = blockIdx.x * blockDim.x + threadIdx.x;
    float4 a = ((const float4*)in)[i * 2];
    float4 b = ((const float4*)in)[i * 2 + 1];
    f16x8 o;
    o[0] = (_Float16)a.x; o[1] = (_Float16)a.y;
    o[2] = (_Float16)a.z; o[3] = (_Float16)a.w;
    o[4] = (_Float16)b.x; o[5] = (_Float16)b.y;
    o[6] = (_Float16)b.z; o[7] = (_Float16)b.w;
    ((f16x8*)out)[i] = o;
}

// ---------------------------------------------------------------------------
// W [K=1024][N=1024] fp32 -> Wt [N][K] fp16 (tiled transpose, 32x32)
// ---------------------------------------------------------------------------
__global__ __launch_bounds__(256) void transpose_w(
    const float* __restrict__ W, _Float16* __restrict__ Wt)
{
    __shared__ float tile[32][33];
    const int tx = threadIdx.x, ty = threadIdx.y; // (32, 8)
    const int n0 = blockIdx.x * 32, k0 = blockIdx.y * 32;
    #pragma unroll
    for (int j = 0; j < 4; ++j)
        tile[ty + j * 8][tx] = W[(size_t)(k0 + ty + j * 8) * EMB + n0 + tx];
    __syncthreads();
    #pragma unroll
    for (int j = 0; j < 4; ++j)
        Wt[(size_t)(n0 + ty + j * 8) * EMB + k0 + tx] =
            (_Float16)tile[tx][ty + j * 8];
}

// ---------------------------------------------------------------------------
// fp16 MFMA GEMM: C[M,N] = A[M,K=1024] @ Bt[N,K]^T.
// 128x128 tile, BK=32, 4 waves (2x2), wave tile 64x64 = 4x4 16x16 frags.
// MODE 0: N=3072 fused QKV -> writes fp16 [B,H,T,D], alpha=0.125 on Q.
// MODE 1: N=1024 -> writes fp32 out + bias.
// ---------------------------------------------------------------------------
template <int MODE>
__global__ __launch_bounds__(256) void gemm_mfma(
    const _Float16* __restrict__ A, const _Float16* __restrict__ Bt,
    _Float16* __restrict__ Qh, _Float16* __restrict__ Kh,
    _Float16* __restrict__ Vh,
    float* __restrict__ outf, const float* __restrict__ bias)
{
    __shared__ __align__(16) _Float16 As[128 * 32]; // 8 KB, row-major [m][k]
    __shared__ __align__(16) _Float16 Bs[128 * 32]; // 8 KB, row-major [n][k]

    const int tid = threadIdx.x;
    const int w = tid >> 6, lane = tid & 63;
    const int l15 = lane & 15, g4 = lane >> 4;
    const int wm = w >> 1, wn = w & 1;
    const int row0 = blockIdx.y * 128, col0 = blockIdx.x * 128;

    f32x4 acc[4][4];
    #pragma unroll
    for (int mt = 0; mt < 4; ++mt)
        #pragma unroll
        for (int nt = 0; nt < 4; ++nt)
            acc[mt][nt] = (f32x4){0.f, 0.f, 0.f, 0.f};

    for (int k0 = 0; k0 < EMB; k0 += 32) {
        __syncthreads(); // previous compute done; safe to overwrite tiles
        #pragma unroll
        for (int i = 0; i < 2; ++i) {
            int c = (i << 8) + tid;       // 16B chunk id, 0..511
            int row = c >> 2, u = c & 3;  // row 0..127, 16B-unit in k
            stage16(&A[(size_t)(row0 + row) * EMB + k0 + (u << 3)],
                    (char*)As + (i << 12) + (w << 10), lane);
            stage16(&Bt[(size_t)(col0 + row) * EMB + k0 + (u << 3)],
                    (char*)Bs + (i << 12) + (w << 10), lane);
        }
        __syncthreads(); // staging visible (compiler drains vmcnt pre-barrier)

        f16x8 af[4], bf[4];
        #pragma unroll
        for (int mt = 0; mt < 4; ++mt)
            af[mt] = *(const f16x8*)((const char*)As +
                     ((wm << 6) + (mt << 4) + l15) * 64 + (g4 << 4));
        #pragma unroll
        for (int nt = 0; nt < 4; ++nt)
            bf[nt] = *(const f16x8*)((const char*)Bs +
                     ((wn << 6) + (nt << 4) + l15) * 64 + (g4 << 4));
        #pragma unroll
        for (int mt = 0; mt < 4; ++mt)
            #pragma unroll
            for (int nt = 0; nt < 4; ++nt)
                acc[mt][nt] = __builtin_amdgcn_mfma_f32_16x16x32_f16(
                    af[mt], bf[nt], acc[mt][nt], 0, 0, 0);
    }

    // Epilogue. C/D layout: col = lane&15, row = 4*(lane>>4) + reg.
    #pragma unroll
    for (int mt = 0; mt < 4; ++mt) {
        int m = row0 + (wm << 6) + (mt << 4) + (g4 << 2);
        #pragma unroll
        for (int nt = 0; nt < 4; ++nt) {
            int gcol = col0 + (wn << 6) + (nt << 4) + l15;
            if (MODE == 0) {
                int proj = gcol >> 10, pc = gcol & 1023;
                int h = pc >> 6, d = pc & 63;
                _Float16* dst = proj == 0 ? Qh : (proj == 1 ? Kh : Vh);
                float alpha = proj == 0 ? 0.125f : 1.0f;
                int b = m >> 11, t = m & 2047;
                #pragma unroll
                for (int r = 0; r < 4; ++r)
                    dst[(((size_t)(b * NUM_HEADS + h)) * SEQ + t + r) * HEAD_D + d] =
                        (_Float16)(acc[mt][nt][r] * alpha);
            } else {
                float bz = bias[gcol];
                #pragma unroll
                for (int r = 0; r < 4; ++r)
                    outf[(size_t)(m + r) * EMB + gcol] = acc[mt][nt][r] + bz;
            }
        }
    }
}

// ---------------------------------------------------------------------------
// One 64q x 64kv attention tile step: S^T = K Q^T (swapped MFMA, lane owns
// one q row), online softmax with defer-max (skip rescale while max lags
// <= 5.5 nats), P roundtrip through wave-private LDS, acc += P @ V.
// Address formulas identical to the R6/R7-verified kernel.
// ---------------------------------------------------------------------------
__device__ __forceinline__ void attn_tile(
    const char* __restrict__ KsC, const char* __restrict__ VtC,
    char* __restrict__ pwv,
    f16x8 qf0, f16x8 qf1, f32x4 (&acc)[4], float& m, float& l,
    bool diag, int qrel, int l15, int g)
{
    f32x4 st[4];
    #pragma unroll
    for (int nt = 0; nt < 4; ++nt) {
        int kvl = (nt << 4) + l15;
        f16x8 kf0 = *(const f16x8*)&KsC[kvl * 128 + (((g << 4)) ^ ((kvl & 7) << 4))];
        f16x8 kf1 = *(const f16x8*)&KsC[kvl * 128 + ((64 + (g << 4)) ^ ((kvl & 7) << 4))];
        f32x4 z = (f32x4){0.f, 0.f, 0.f, 0.f};
        z = __builtin_amdgcn_mfma_f32_16x16x32_f16(kf0, qf0, z, 0, 0, 0);
        z = __builtin_amdgcn_mfma_f32_16x16x32_f16(kf1, qf1, z, 0, 0, 0);
        st[nt] = z;
    }
    if (diag) {
        #pragma unroll
        for (int nt = 0; nt < 4; ++nt)
            #pragma unroll
            for (int r = 0; r < 4; ++r)
                if ((nt << 4) + (g << 2) + r > qrel) st[nt][r] = -1e30f;
    }

    float mx;
    {
        float a0 = fmaxf(fmaxf(st[0][0], st[0][1]), fmaxf(st[0][2], st[0][3]));
        float a1 = fmaxf(fmaxf(st[1][0], st[1][1]), fmaxf(st[1][2], st[1][3]));
        float a2 = fmaxf(fmaxf(st[2][0], st[2][1]), fmaxf(st[2][2], st[2][3]));
        float a3 = fmaxf(fmaxf(st[3][0], st[3][1]), fmaxf(st[3][2], st[3][3]));
        mx = fmaxf(fmaxf(a0, a1), fmaxf(a2, a3));
    }
    mx = fmaxf(mx, __shfl_xor(mx, 16));
    mx = fmaxf(mx, __shfl_xor(mx, 32));

    // defer-max: only rescale when the running max lags by > 5.5 nats
    // (P then bounded by e^5.5 ~ 245, safe in fp16; fp32 accum absorbs)
    if (!__all(mx - m <= 5.5f)) {
        float nm = fmaxf(m, mx);
        float sc = __expf(m - nm);
        m = nm;
        l *= sc;
        #pragma unroll
        for (int r = 0; r < 4; ++r) {
            float scr = __shfl(sc, (g << 2) + r); // q row 4g+r's factor
            acc[0][r] *= scr; acc[1][r] *= scr;
            acc[2][r] *= scr; acc[3][r] *= scr;
        }
    }

    float ps = 0.f;
    #pragma unroll
    for (int nt = 0; nt < 4; ++nt)
        #pragma unroll
        for (int r = 0; r < 4; ++r) {
            float p = __expf(st[nt][r] - m);
            st[nt][r] = p;
            ps += p;
        }
    ps += __shfl_xor(ps, 16);
    ps += __shfl_xor(ps, 32);
    l += ps;

    // P -> wave-private LDS as P[q][kv] (8x b32 writes), read back A-frags
    #pragma unroll
    for (int nt = 0; nt < 4; ++nt)
        #pragma unroll
        for (int rr = 0; rr < 2; ++rr) {
            int kvb = (nt << 4) + (g << 2) + (rr << 1);
            f16x2 pv;
            pv[0] = (_Float16)st[nt][rr * 2];
            pv[1] = (_Float16)st[nt][rr * 2 + 1];
            *(f16x2*)&pwv[l15 * 128 + ((kvb << 1) ^ ((l15 & 7) << 4))] = pv;
        }
    f16x8 pa0 = *(const f16x8*)&pwv[l15 * 128 + (((g << 4)) ^ ((l15 & 7) << 4))];
    f16x8 pa1 = *(const f16x8*)&pwv[l15 * 128 + ((64 + (g << 4)) ^ ((l15 & 7) << 4))];

    #pragma unroll
    for (int dn = 0; dn < 4; ++dn) {
        int d = (dn << 4) + l15;
        int swz = ((d & 7) ^ (d >> 3)) & 7;
        f16x8 vf0 = *(const f16x8*)&VtC[d * 128 + (((g << 4)) ^ (swz << 4))];
        f16x8 vf1 = *(const f16x8*)&VtC[d * 128 + ((64 + (g << 4)) ^ (swz << 4))];
        acc[dn] = __builtin_amdgcn_mfma_f32_16x16x32_f16(pa0, vf0, acc[dn], 0, 0, 0);
        acc[dn] = __builtin_amdgcn_mfma_f32_16x16x32_f16(pa1, vf1, acc[dn], 0, 0, 0);
    }
}

// ---------------------------------------------------------------------------
// Flash attention, causal, fp16 MFMA. R8: PAIRED q-tiles. Block handles
// q-tiles qtA = blockIdx.x and qtB = 31-qtA: total work is 33 tile-computes
// for EVERY block (perfect causal balance), K/V staged once for the pair,
// and phase-1 iterations carry two independent compute chains (2x ILP).
// Double-buffered K/V as in R7. Defer-max softmax (T13).
// ---------------------------------------------------------------------------
__global__ __launch_bounds__(256) void attn_mfma(
    const _Float16* __restrict__ Qh, const _Float16* __restrict__ Kh,
    const _Float16* __restrict__ Vh, _Float16* __restrict__ O)
{
    __shared__ char lds[48 * 1024];
    // Ks buf b: b*8192 | Vt buf b: 16384 + b*8192 | PwA: 32768 | PwB: 40960

    const int qtA = blockIdx.x;            // 0..15
    const int qtB = (SEQ / 64 - 1) - qtA;  // 31..16
    const int bh = blockIdx.y;
    const int q0A = qtA << 6, q0B = qtB << 6;
    const int tid = threadIdx.x;
    const int w = tid >> 6, lane = tid & 63;
    const int l15 = lane & 15, g = lane >> 4;

    const size_t headbase = (size_t)bh * SEQ * HEAD_D;

    // Q fragments for both tiles (lane -> q row l15; k = d at 8g / 32+8g)
    const int qrowA = q0A + (w << 4) + l15;
    const int qrowB = q0B + (w << 4) + l15;
    f16x8 qfA0 = *(const f16x8*)&Qh[headbase + (size_t)qrowA * HEAD_D + (g << 3)];
    f16x8 qfA1 = *(const f16x8*)&Qh[headbase + (size_t)qrowA * HEAD_D + 32 + (g << 3)];
    f16x8 qfB0 = *(const f16x8*)&Qh[headbase + (size_t)qrowB * HEAD_D + (g << 3)];
    f16x8 qfB1 = *(const f16x8*)&Qh[headbase + (size_t)qrowB * HEAD_D + 32 + (g << 3)];

    f32x4 accA[4], accB[4];
    #pragma unroll
    for (int dn = 0; dn < 4; ++dn) {
        accA[dn] = (f32x4){0.f, 0.f, 0.f, 0.f};
        accB[dn] = (f32x4){0.f, 0.f, 0.f, 0.f};
    }
    float mA = -1e30f, lA = 0.f, mB = -1e30f, lB = 0.f;

    const int c0 = tid, c1 = 256 + tid;
    const int row_a = c0 >> 3, u_a = c0 & 7;
    const int row_b = c1 >> 3, u_b = c1 & 7;

    // ---- prologue: stage tile 0 into buffer 0 ----
    {
        f16x8 k8a = *(const f16x8*)&Kh[headbase + (size_t)row_a * HEAD_D + (u_a << 3)];
        f16x8 v8a = *(const f16x8*)&Vh[headbase + (size_t)row_a * HEAD_D + (u_a << 3)];
        f16x8 k8b = *(const f16x8*)&Kh[headbase + (size_t)row_b * HEAD_D + (u_b << 3)];
        f16x8 v8b = *(const f16x8*)&Vh[headbase + (size_t)row_b * HEAD_D + (u_b << 3)];
        char* Ks0 = lds;
        char* Vt0 = lds + 16384;
        *(f16x8*)&Ks0[row_a * 128 + ((u_a ^ (row_a & 7)) << 4)] = k8a;
        *(f16x8*)&Ks0[row_b * 128 + ((u_b ^ (row_b & 7)) << 4)] = k8b;
        #pragma unroll
        for (int j = 0; j < 8; ++j) {
            int da = (u_a << 3) + j, db = (u_b << 3) + j;
            *(_Float16*)&Vt0[da * 128 +
                ((row_a << 1) ^ ((((da & 7) ^ (da >> 3)) & 7) << 4))] = v8a[j];
            *(_Float16*)&Vt0[db * 128 +
                ((row_b << 1) ^ ((((db & 7) ^ (db >> 3)) & 7) << 4))] = v8b[j];
        }
    }
    __syncthreads();

    char* pwvA = lds + 32768 + (w << 11);
    char* pwvB = lds + 40960 + (w << 11);

    int cur = 0;
    for (int kt = 0; kt <= qtB; ++kt) {
        const bool have_next = (kt < qtB);

        // issue next tile's global loads early (latency hides under compute)
        f16x8 k8a, v8a, k8b, v8b;
        if (have_next) {
            const size_t nb = headbase + (size_t)((kt + 1) << 6) * HEAD_D;
            k8a = *(const f16x8*)&Kh[nb + (size_t)row_a * HEAD_D + (u_a << 3)];
            v8a = *(const f16x8*)&Vh[nb + (size_t)row_a * HEAD_D + (u_a << 3)];
            k8b = *(const f16x8*)&Kh[nb + (size_t)row_b * HEAD_D + (u_b << 3)];
            v8b = *(const f16x8*)&Vh[nb + (size_t)row_b * HEAD_D + (u_b << 3)];
        }

        const char* KsC = lds + (cur << 13);
        const char* VtC = lds + 16384 + (cur << 13);
        const int qrel = (w << 4) + l15; // q - kv0 on any diagonal tile

        if (kt <= qtA) {
            // both tiles in one straight-line region -> 2 independent chains
            attn_tile(KsC, VtC, pwvA, qfA0, qfA1, accA, mA, lA,
                      kt == qtA, qrel, l15, g);
            attn_tile(KsC, VtC, pwvB, qfB0, qfB1, accB, mB, lB,
                      false, qrel, l15, g);
        } else {
            attn_tile(KsC, VtC, pwvB, qfB0, qfB1, accB, mB, lB,
                      kt == qtB, qrel, l15, g);
        }

        if (have_next) {
            char* KsN = lds + ((cur ^ 1) << 13);
            char* VtN = lds + 16384 + ((cur ^ 1) << 13);
            *(f16x8*)&KsN[row_a * 128 + ((u_a ^ (row_a & 7)) << 4)] = k8a;
            *(f16x8*)&KsN[row_b * 128 + ((u_b ^ (row_b & 7)) << 4)] = k8b;
            #pragma unroll
            for (int j = 0; j < 8; ++j) {
                int da = (u_a << 3) + j, db = (u_b << 3) + j;
                *(_Float16*)&VtN[da * 128 +
                    ((row_a << 1) ^ ((((da & 7) ^ (da >> 3)) & 7) << 4))] = v8a[j];
                *(_Float16*)&VtN[db * 128 +
                    ((row_b << 1) ^ ((((db & 7) ^ (db >> 3)) & 7) << 4))] = v8b[j];
            }
        }
        __syncthreads();
        cur ^= 1;
    }

    // ---- epilogue: normalize, write fp16 O[tok][h*64+d] for both tiles ----
    const int b = bh >> 4, h = bh & 15;
    const float rlA = 1.f / lA, rlB = 1.f / lB;
    #pragma unroll
    for (int r = 0; r < 4; ++r) {
        float invA = __shfl(rlA, (g << 2) + r);
        float invB = __shfl(rlB, (g << 2) + r);
        int tokA = (b << 11) + q0A + (w << 4) + (g << 2) + r;
        int tokB = (b << 11) + q0B + (w << 4) + (g << 2) + r;
        #pragma unroll
        for (int dn = 0; dn < 4; ++dn) {
            O[(size_t)tokA * EMB + (h << 6) + (dn << 4) + l15] =
                (_Float16)(accA[dn][r] * invA);
            O[(size_t)tokB * EMB + (h << 6) + (dn << 4) + l15] =
                (_Float16)(accB[dn][r] * invB);
        }
    }
}

// ---------------------------------------------------------------------------
extern "C" void kernel_launch(void* const* d_in, const int* in_sizes, int n_in,
                              void* d_out, int out_size, void* d_ws, size_t ws_size,
                              hipStream_t stream)
{
    const float* x  = (const float*)d_in[0];
    const float* Wq = (const float*)d_in[1];
    const float* Wk = (const float*)d_in[2];
    const float* Wv = (const float*)d_in[3];
    const float* Wo = (const float*)d_in[4];
    const float* bo = (const float*)d_in[5];
    float* out = (float*)d_out;

    const size_t ME = (size_t)MTOT * EMB;        // 4M elems
    const size_t WE = (size_t)EMB * EMB;         // 1M elems
    const size_t need = (ME + 3 * WE + WE + 3 * ME + ME) * sizeof(_Float16);
    if (ws_size < need) return;

    _Float16* xh  = (_Float16*)d_ws;
    _Float16* Wt  = xh + ME;
    _Float16* Wto = Wt + 3 * WE;
    _Float16* Qh  = Wto + WE;
    _Float16* Kh  = Qh + ME;
    _Float16* Vh  = Kh + ME;
    _Float16* Ow  = Vh + ME;

    cast_f32_f16<<<(int)(ME / 8 / 256), 256, 0, stream>>>(x, xh);
    dim3 tb(32, 8), tg(EMB / 32, EMB / 32);
    transpose_w<<<tg, tb, 0, stream>>>(Wq, Wt);
    transpose_w<<<tg, tb, 0, stream>>>(Wk, Wt + WE);
    transpose_w<<<tg, tb, 0, stream>>>(Wv, Wt + 2 * WE);
    transpose_w<<<tg, tb, 0, stream>>>(Wo, Wto);

    gemm_mfma<0><<<dim3(3 * EMB / 128, MTOT / 128), 256, 0, stream>>>(
        xh, Wt, Qh, Kh, Vh, nullptr, nullptr);

    // paired q-tiles: 16 pair-blocks x 32 (b,h)
    attn_mfma<<<dim3(SEQ / 128, BATCH * NUM_HEADS), 256, 0, stream>>>(Qh, Kh, Vh, Ow);

    gemm_mfma<1><<<dim3(EMB / 128, MTOT / 128), 256, 0, stream>>>(
        Ow, Wto, nullptr, nullptr, nullptr, out, bo);
}

// Round 10
// 133.435 us; speedup vs baseline: 11.5306x; 1.0130x over previous
//
#include <hip/hip_runtime.h>

typedef __attribute__((ext_vector_type(8))) _Float16 f16x8;
typedef __attribute__((ext_vector_type(4))) _Float16 f16x4;
typedef __attribute__((ext_vector_type(2))) _Float16 f16x2;
typedef __attribute__((ext_vector_type(2))) __fp16   fp16x2_raw;
typedef __attribute__((ext_vector_type(4))) float    f32x4;

#define NUM_HEADS 16
#define HEAD_D 64
#define EMB 1024
#define SEQ 2048
#define BATCH 2
#define MTOT (BATCH * SEQ) // 4096

// Q scale: 1/sqrt(64) * log2(e)  (softmax uses exp2)
#define QALPHA 0.18033688011112042f

__device__ __forceinline__ f16x2 cvt_pk_f16(float lo, float hi)
{
    fp16x2_raw r = __builtin_amdgcn_cvt_pkrtz(lo, hi);
    return __builtin_bit_cast(f16x2, r);
}

// ---------------------------------------------------------------------------
// global -> LDS direct staging (16 B per lane). LDS dest is wave-uniform
// base + lane*16 (HW behavior); fallback reg-stages to the same address.
// ---------------------------------------------------------------------------
#if defined(__has_builtin)
#if __has_builtin(__builtin_amdgcn_global_load_lds)
#define HAVE_GLOAD_LDS 1
#endif
#endif

__device__ __forceinline__ void stage16(const void* g, void* ldsWaveBase, int lane)
{
#ifdef HAVE_GLOAD_LDS
    __builtin_amdgcn_global_load_lds(
        (const __attribute__((address_space(1))) void*)g,
        (__attribute__((address_space(3))) void*)ldsWaveBase, 16, 0, 0);
    (void)lane;
#else
    *(f16x8*)((char*)ldsWaveBase + lane * 16) = *(const f16x8*)g;
#endif
}

// ---------------------------------------------------------------------------
// Fused prep: grid (32,32,5), 256 threads.
//  z=0..3 : transpose+cast W (z<3 -> Wt + z*WE, z=3 -> Wto)
//  z=4    : cast x -> xh (2 f16x8 chunks per thread)
// ---------------------------------------------------------------------------
__global__ __launch_bounds__(256) void prep_all(
    const float* __restrict__ x,
    const float* __restrict__ Wq, const float* __restrict__ Wk,
    const float* __restrict__ Wv, const float* __restrict__ Wo,
    _Float16* __restrict__ xh, _Float16* __restrict__ Wt,
    _Float16* __restrict__ Wto)
{
    const int z = blockIdx.z;
    if (z == 4) {
        int base = ((blockIdx.y * 32 + blockIdx.x) * 256 + threadIdx.x) * 2;
        #pragma unroll
        for (int t = 0; t < 2; ++t) {
            int i = base + t;
            float4 a = ((const float4*)x)[i * 2];
            float4 b = ((const float4*)x)[i * 2 + 1];
            f16x8 o;
            o[0] = (_Float16)a.x; o[1] = (_Float16)a.y;
            o[2] = (_Float16)a.z; o[3] = (_Float16)a.w;
            o[4] = (_Float16)b.x; o[5] = (_Float16)b.y;
            o[6] = (_Float16)b.z; o[7] = (_Float16)b.w;
            ((f16x8*)xh)[i] = o;
        }
        return;
    }
    const float* W = z == 0 ? Wq : (z == 1 ? Wk : (z == 2 ? Wv : Wo));
    _Float16* D = (z == 3) ? Wto : (Wt + (size_t)z * EMB * EMB);
    __shared__ float tile[32][33];
    const int tx = threadIdx.x & 31, ty = threadIdx.x >> 5; // (32, 8)
    const int n0 = blockIdx.x * 32, k0 = blockIdx.y * 32;
    #pragma unroll
    for (int j = 0; j < 4; ++j)
        tile[ty + j * 8][tx] = W[(size_t)(k0 + ty + j * 8) * EMB + n0 + tx];
    __syncthreads();
    #pragma unroll
    for (int j = 0; j < 4; ++j)
        D[(size_t)(n0 + ty + j * 8) * EMB + k0 + tx] =
            (_Float16)tile[tx][ty + j * 8];
}

// ---------------------------------------------------------------------------
// fp16 MFMA GEMM: C[M,N] = A[M,K=1024] @ Bt[N,K]^T.
// 128x128 tile, BK=32, 4 waves (2x2), wave tile 64x64 = 4x4 16x16 frags.
// MODE 0: N=3072 fused QKV -> writes fp16 [B,H,T,D], alpha=QALPHA on Q.
// MODE 1: N=1024 -> writes fp32 out + bias.
// ---------------------------------------------------------------------------
template <int MODE>
__global__ __launch_bounds__(256) void gemm_mfma(
    const _Float16* __restrict__ A, const _Float16* __restrict__ Bt,
    _Float16* __restrict__ Qh, _Float16* __restrict__ Kh,
    _Float16* __restrict__ Vh,
    float* __restrict__ outf, const float* __restrict__ bias)
{
    __shared__ __align__(16) _Float16 As[128 * 32]; // 8 KB, row-major [m][k]
    __shared__ __align__(16) _Float16 Bs[128 * 32]; // 8 KB, row-major [n][k]

    const int tid = threadIdx.x;
    const int w = tid >> 6, lane = tid & 63;
    const int l15 = lane & 15, g4 = lane >> 4;
    const int wm = w >> 1, wn = w & 1;
    const int row0 = blockIdx.y * 128, col0 = blockIdx.x * 128;

    f32x4 acc[4][4];
    #pragma unroll
    for (int mt = 0; mt < 4; ++mt)
        #pragma unroll
        for (int nt = 0; nt < 4; ++nt)
            acc[mt][nt] = (f32x4){0.f, 0.f, 0.f, 0.f};

    for (int k0 = 0; k0 < EMB; k0 += 32) {
        __syncthreads(); // previous compute done; safe to overwrite tiles
        #pragma unroll
        for (int i = 0; i < 2; ++i) {
            int c = (i << 8) + tid;       // 16B chunk id, 0..511
            int row = c >> 2, u = c & 3;  // row 0..127, 16B-unit in k
            stage16(&A[(size_t)(row0 + row) * EMB + k0 + (u << 3)],
                    (char*)As + (i << 12) + (w << 10), lane);
            stage16(&Bt[(size_t)(col0 + row) * EMB + k0 + (u << 3)],
                    (char*)Bs + (i << 12) + (w << 10), lane);
        }
        __syncthreads(); // staging visible (compiler drains vmcnt pre-barrier)

        f16x8 af[4], bf[4];
        #pragma unroll
        for (int mt = 0; mt < 4; ++mt)
            af[mt] = *(const f16x8*)((const char*)As +
                     ((wm << 6) + (mt << 4) + l15) * 64 + (g4 << 4));
        #pragma unroll
        for (int nt = 0; nt < 4; ++nt)
            bf[nt] = *(const f16x8*)((const char*)Bs +
                     ((wn << 6) + (nt << 4) + l15) * 64 + (g4 << 4));
        #pragma unroll
        for (int mt = 0; mt < 4; ++mt)
            #pragma unroll
            for (int nt = 0; nt < 4; ++nt)
                acc[mt][nt] = __builtin_amdgcn_mfma_f32_16x16x32_f16(
                    af[mt], bf[nt], acc[mt][nt], 0, 0, 0);
    }

    // Epilogue. C/D layout: col = lane&15, row = 4*(lane>>4) + reg.
    #pragma unroll
    for (int mt = 0; mt < 4; ++mt) {
        int m = row0 + (wm << 6) + (mt << 4) + (g4 << 2);
        #pragma unroll
        for (int nt = 0; nt < 4; ++nt) {
            int gcol = col0 + (wn << 6) + (nt << 4) + l15;
            if (MODE == 0) {
                int proj = gcol >> 10, pc = gcol & 1023;
                int h = pc >> 6, d = pc & 63;
                _Float16* dst = proj == 0 ? Qh : (proj == 1 ? Kh : Vh);
                float alpha = proj == 0 ? QALPHA : 1.0f;
                int b = m >> 11, t = m & 2047;
                #pragma unroll
                for (int r = 0; r < 4; ++r)
                    dst[(((size_t)(b * NUM_HEADS + h)) * SEQ + t + r) * HEAD_D + d] =
                        (_Float16)(acc[mt][nt][r] * alpha);
            } else {
                float bz = bias[gcol];
                #pragma unroll
                for (int r = 0; r < 4; ++r)
                    outf[(size_t)(m + r) * EMB + gcol] = acc[mt][nt][r] + bz;
            }
        }
    }
}

// ---------------------------------------------------------------------------
// One 64q x 64kv attention tile step: S^T = K Q^T (swapped MFMA, lane owns
// one q row), exp2-based online softmax with defer-max (skip rescale while
// max lags <= 8 in log2 units; P <= 256, fp16-safe), packed cvt_pkrtz for
// P->f16, P roundtrip through wave-private LDS, acc += P @ V.
// ---------------------------------------------------------------------------
__device__ __forceinline__ void attn_tile(
    const char* __restrict__ KsC, const char* __restrict__ VtC,
    char* __restrict__ pwv,
    f16x8 qf0, f16x8 qf1, f32x4 (&acc)[4], float& m, float& l,
    bool diag, int qrel, int l15, int g)
{
    f32x4 st[4];
    #pragma unroll
    for (int nt = 0; nt < 4; ++nt) {
        int kvl = (nt << 4) + l15;
        f16x8 kf0 = *(const f16x8*)&KsC[kvl * 128 + (((g << 4)) ^ ((kvl & 7) << 4))];
        f16x8 kf1 = *(const f16x8*)&KsC[kvl * 128 + ((64 + (g << 4)) ^ ((kvl & 7) << 4))];
        f32x4 z = (f32x4){0.f, 0.f, 0.f, 0.f};
        z = __builtin_amdgcn_mfma_f32_16x16x32_f16(kf0, qf0, z, 0, 0, 0);
        z = __builtin_amdgcn_mfma_f32_16x16x32_f16(kf1, qf1, z, 0, 0, 0);
        st[nt] = z;
    }
    if (diag) {
        #pragma unroll
        for (int nt = 0; nt < 4; ++nt)
            #pragma unroll
            for (int r = 0; r < 4; ++r)
                if ((nt << 4) + (g << 2) + r > qrel) st[nt][r] = -1e30f;
    }

    float mx;
    {
        float a0 = fmaxf(fmaxf(st[0][0], st[0][1]), fmaxf(st[0][2], st[0][3]));
        float a1 = fmaxf(fmaxf(st[1][0], st[1][1]), fmaxf(st[1][2], st[1][3]));
        float a2 = fmaxf(fmaxf(st[2][0], st[2][1]), fmaxf(st[2][2], st[2][3]));
        float a3 = fmaxf(fmaxf(st[3][0], st[3][1]), fmaxf(st[3][2], st[3][3]));
        mx = fmaxf(fmaxf(a0, a1), fmaxf(a2, a3));
    }
    mx = fmaxf(mx, __shfl_xor(mx, 16));
    mx = fmaxf(mx, __shfl_xor(mx, 32));

    // defer-max: only rescale when the running max lags by > 8 (log2 units)
    if (!__all(mx - m <= 8.0f)) {
        float nm = fmaxf(m, mx);
        float sc = exp2f(m - nm);
        m = nm;
        l *= sc;
        #pragma unroll
        for (int r = 0; r < 4; ++r) {
            float scr = __shfl(sc, (g << 2) + r); // q row 4g+r's factor
            acc[0][r] *= scr; acc[1][r] *= scr;
            acc[2][r] *= scr; acc[3][r] *= scr;
        }
    }

    float ps = 0.f;
    #pragma unroll
    for (int nt = 0; nt < 4; ++nt)
        #pragma unroll
        for (int r = 0; r < 4; ++r) {
            float p = exp2f(st[nt][r] - m);
            st[nt][r] = p;
            ps += p;
        }
    ps += __shfl_xor(ps, 16);
    ps += __shfl_xor(ps, 32);
    l += ps;

    // P -> wave-private LDS as P[q][kv] (8x packed b32 writes)
    #pragma unroll
    for (int nt = 0; nt < 4; ++nt)
        #pragma unroll
        for (int rr = 0; rr < 2; ++rr) {
            int kvb = (nt << 4) + (g << 2) + (rr << 1);
            f16x2 pv = cvt_pk_f16(st[nt][rr * 2], st[nt][rr * 2 + 1]);
            *(f16x2*)&pwv[l15 * 128 + ((kvb << 1) ^ ((l15 & 7) << 4))] = pv;
        }
    f16x8 pa0 = *(const f16x8*)&pwv[l15 * 128 + (((g << 4)) ^ ((l15 & 7) << 4))];
    f16x8 pa1 = *(const f16x8*)&pwv[l15 * 128 + ((64 + (g << 4)) ^ ((l15 & 7) << 4))];

    #pragma unroll
    for (int dn = 0; dn < 4; ++dn) {
        int d = (dn << 4) + l15;
        int swz = ((d & 7) ^ (d >> 3)) & 7;
        f16x8 vf0 = *(const f16x8*)&VtC[d * 128 + (((g << 4)) ^ (swz << 4))];
        f16x8 vf1 = *(const f16x8*)&VtC[d * 128 + ((64 + (g << 4)) ^ (swz << 4))];
        acc[dn] = __builtin_amdgcn_mfma_f32_16x16x32_f16(pa0, vf0, acc[dn], 0, 0, 0);
        acc[dn] = __builtin_amdgcn_mfma_f32_16x16x32_f16(pa1, vf1, acc[dn], 0, 0, 0);
    }
}

// ---------------------------------------------------------------------------
// Flash attention, causal, fp16 MFMA. Paired q-tiles (qtA, 31-qtA): 33
// tile-computes per block (perfect FLOP balance), K/V staged once per pair,
// dual independent chains in phase 1 (2x ILP). Double-buffered K/V.
// ---------------------------------------------------------------------------
__global__ __launch_bounds__(256) void attn_mfma(
    const _Float16* __restrict__ Qh, const _Float16* __restrict__ Kh,
    const _Float16* __restrict__ Vh, _Float16* __restrict__ O)
{
    __shared__ char lds[48 * 1024];
    // Ks buf b: b*8192 | Vt buf b: 16384 + b*8192 | PwA: 32768 | PwB: 40960

    const int qtA = blockIdx.x;            // 0..15
    const int qtB = (SEQ / 64 - 1) - qtA;  // 31..16
    const int bh = blockIdx.y;
    const int q0A = qtA << 6, q0B = qtB << 6;
    const int tid = threadIdx.x;
    const int w = tid >> 6, lane = tid & 63;
    const int l15 = lane & 15, g = lane >> 4;

    const size_t headbase = (size_t)bh * SEQ * HEAD_D;

    const int qrowA = q0A + (w << 4) + l15;
    const int qrowB = q0B + (w << 4) + l15;
    f16x8 qfA0 = *(const f16x8*)&Qh[headbase + (size_t)qrowA * HEAD_D + (g << 3)];
    f16x8 qfA1 = *(const f16x8*)&Qh[headbase + (size_t)qrowA * HEAD_D + 32 + (g << 3)];
    f16x8 qfB0 = *(const f16x8*)&Qh[headbase + (size_t)qrowB * HEAD_D + (g << 3)];
    f16x8 qfB1 = *(const f16x8*)&Qh[headbase + (size_t)qrowB * HEAD_D + 32 + (g << 3)];

    f32x4 accA[4], accB[4];
    #pragma unroll
    for (int dn = 0; dn < 4; ++dn) {
        accA[dn] = (f32x4){0.f, 0.f, 0.f, 0.f};
        accB[dn] = (f32x4){0.f, 0.f, 0.f, 0.f};
    }
    float mA = -1e30f, lA = 0.f, mB = -1e30f, lB = 0.f;

    const int c0 = tid, c1 = 256 + tid;
    const int row_a = c0 >> 3, u_a = c0 & 7;
    const int row_b = c1 >> 3, u_b = c1 & 7;

    // ---- prologue: stage tile 0 into buffer 0 ----
    {
        f16x8 k8a = *(const f16x8*)&Kh[headbase + (size_t)row_a * HEAD_D + (u_a << 3)];
        f16x8 v8a = *(const f16x8*)&Vh[headbase + (size_t)row_a * HEAD_D + (u_a << 3)];
        f16x8 k8b = *(const f16x8*)&Kh[headbase + (size_t)row_b * HEAD_D + (u_b << 3)];
        f16x8 v8b = *(const f16x8*)&Vh[headbase + (size_t)row_b * HEAD_D + (u_b << 3)];
        char* Ks0 = lds;
        char* Vt0 = lds + 16384;
        *(f16x8*)&Ks0[row_a * 128 + ((u_a ^ (row_a & 7)) << 4)] = k8a;
        *(f16x8*)&Ks0[row_b * 128 + ((u_b ^ (row_b & 7)) << 4)] = k8b;
        #pragma unroll
        for (int j = 0; j < 8; ++j) {
            int da = (u_a << 3) + j, db = (u_b << 3) + j;
            *(_Float16*)&Vt0[da * 128 +
                ((row_a << 1) ^ ((((da & 7) ^ (da >> 3)) & 7) << 4))] = v8a[j];
            *(_Float16*)&Vt0[db * 128 +
                ((row_b << 1) ^ ((((db & 7) ^ (db >> 3)) & 7) << 4))] = v8b[j];
        }
    }
    __syncthreads();

    char* pwvA = lds + 32768 + (w << 11);
    char* pwvB = lds + 40960 + (w << 11);

    int cur = 0;
    for (int kt = 0; kt <= qtB; ++kt) {
        const bool have_next = (kt < qtB);

        f16x8 k8a, v8a, k8b, v8b;
        if (have_next) {
            const size_t nb = headbase + (size_t)((kt + 1) << 6) * HEAD_D;
            k8a = *(const f16x8*)&Kh[nb + (size_t)row_a * HEAD_D + (u_a << 3)];
            v8a = *(const f16x8*)&Vh[nb + (size_t)row_a * HEAD_D + (u_a << 3)];
            k8b = *(const f16x8*)&Kh[nb + (size_t)row_b * HEAD_D + (u_b << 3)];
            v8b = *(const f16x8*)&Vh[nb + (size_t)row_b * HEAD_D + (u_b << 3)];
        }

        const char* KsC = lds + (cur << 13);
        const char* VtC = lds + 16384 + (cur << 13);
        const int qrel = (w << 4) + l15;

        if (kt <= qtA) {
            attn_tile(KsC, VtC, pwvA, qfA0, qfA1, accA, mA, lA,
                      kt == qtA, qrel, l15, g);
            attn_tile(KsC, VtC, pwvB, qfB0, qfB1, accB, mB, lB,
                      false, qrel, l15, g);
        } else {
            attn_tile(KsC, VtC, pwvB, qfB0, qfB1, accB, mB, lB,
                      kt == qtB, qrel, l15, g);
        }

        if (have_next) {
            char* KsN = lds + ((cur ^ 1) << 13);
            char* VtN = lds + 16384 + ((cur ^ 1) << 13);
            *(f16x8*)&KsN[row_a * 128 + ((u_a ^ (row_a & 7)) << 4)] = k8a;
            *(f16x8*)&KsN[row_b * 128 + ((u_b ^ (row_b & 7)) << 4)] = k8b;
            #pragma unroll
            for (int j = 0; j < 8; ++j) {
                int da = (u_a << 3) + j, db = (u_b << 3) + j;
                *(_Float16*)&VtN[da * 128 +
                    ((row_a << 1) ^ ((((da & 7) ^ (da >> 3)) & 7) << 4))] = v8a[j];
                *(_Float16*)&VtN[db * 128 +
                    ((row_b << 1) ^ ((((db & 7) ^ (db >> 3)) & 7) << 4))] = v8b[j];
            }
        }
        __syncthreads();
        cur ^= 1;
    }

    // ---- epilogue: normalize, write fp16 O[tok][h*64+d] for both tiles ----
    const int b = bh >> 4, h = bh & 15;
    const float rlA = 1.f / lA, rlB = 1.f / lB;
    #pragma unroll
    for (int r = 0; r < 4; ++r) {
        float invA = __shfl(rlA, (g << 2) + r);
        float invB = __shfl(rlB, (g << 2) + r);
        int tokA = (b << 11) + q0A + (w << 4) + (g << 2) + r;
        int tokB = (b << 11) + q0B + (w << 4) + (g << 2) + r;
        #pragma unroll
        for (int dn = 0; dn < 4; ++dn) {
            O[(size_t)tokA * EMB + (h << 6) + (dn << 4) + l15] =
                (_Float16)(accA[dn][r] * invA);
            O[(size_t)tokB * EMB + (h << 6) + (dn << 4) + l15] =
                (_Float16)(accB[dn][r] * invB);
        }
    }
}

// ---------------------------------------------------------------------------
extern "C" void kernel_launch(void* const* d_in, const int* in_sizes, int n_in,
                              void* d_out, int out_size, void* d_ws, size_t ws_size,
                              hipStream_t stream)
{
    const float* x  = (const float*)d_in[0];
    const float* Wq = (const float*)d_in[1];
    const float* Wk = (const float*)d_in[2];
    const float* Wv = (const float*)d_in[3];
    const float* Wo = (const float*)d_in[4];
    const float* bo = (const float*)d_in[5];
    float* out = (float*)d_out;

    const size_t ME = (size_t)MTOT * EMB;        // 4M elems
    const size_t WE = (size_t)EMB * EMB;         // 1M elems
    const size_t need = (ME + 3 * WE + WE + 3 * ME + ME) * sizeof(_Float16);
    if (ws_size < need) return;

    _Float16* xh  = (_Float16*)d_ws;
    _Float16* Wt  = xh + ME;
    _Float16* Wto = Wt + 3 * WE;
    _Float16* Qh  = Wto + WE;
    _Float16* Kh  = Qh + ME;
    _Float16* Vh  = Kh + ME;
    _Float16* Ow  = Vh + ME;

    // fused prep: 4 weight transposes + x cast in one dispatch
    prep_all<<<dim3(EMB / 32, EMB / 32, 5), 256, 0, stream>>>(
        x, Wq, Wk, Wv, Wo, xh, Wt, Wto);

    gemm_mfma<0><<<dim3(3 * EMB / 128, MTOT / 128), 256, 0, stream>>>(
        xh, Wt, Qh, Kh, Vh, nullptr, nullptr);

    attn_mfma<<<dim3(SEQ / 128, BATCH * NUM_HEADS), 256, 0, stream>>>(Qh, Kh, Vh, Ow);

    gemm_mfma<1><<<dim3(EMB / 128, MTOT / 128), 256, 0, stream>>>(
        Ow, Wto, nullptr, nullptr, nullptr, out, bo);
}

// Round 11
// 128.266 us; speedup vs baseline: 11.9953x; 1.0403x over previous
//
#include <hip/hip_runtime.h>

typedef __attribute__((ext_vector_type(8))) _Float16 f16x8;
typedef __attribute__((ext_vector_type(4))) _Float16 f16x4;
typedef __attribute__((ext_vector_type(2))) _Float16 f16x2;
typedef __attribute__((ext_vector_type(2))) __fp16   fp16x2_raw;
typedef __attribute__((ext_vector_type(4))) float    f32x4;

#define NUM_HEADS 16
#define HEAD_D 64
#define EMB 1024
#define SEQ 2048
#define BATCH 2
#define MTOT (BATCH * SEQ) // 4096

// Q scale: 1/sqrt(64) * log2(e)  (softmax runs in exp2 domain)
#define QALPHA 0.18033688011112042f

__device__ __forceinline__ f16x2 cvt_pk_f16(float lo, float hi)
{
    fp16x2_raw r = __builtin_amdgcn_cvt_pkrtz(lo, hi);
    return __builtin_bit_cast(f16x2, r);
}

// Raw v_exp_f32 (2^x). Guarded: fall back to fast __expf if builtin absent.
#if defined(__has_builtin)
#if __has_builtin(__builtin_amdgcn_exp2f)
#define HAVE_EXP2 1
#endif
#endif
__device__ __forceinline__ float fast_exp2(float x)
{
#ifdef HAVE_EXP2
    return __builtin_amdgcn_exp2f(x);
#else
    return __expf(x * 0.6931471805599453f);
#endif
}

// ---------------------------------------------------------------------------
// global -> LDS direct staging (16 B per lane). LDS dest is wave-uniform
// base + lane*16 (HW behavior); fallback reg-stages to the same address.
// ---------------------------------------------------------------------------
#if defined(__has_builtin)
#if __has_builtin(__builtin_amdgcn_global_load_lds)
#define HAVE_GLOAD_LDS 1
#endif
#endif

__device__ __forceinline__ void stage16(const void* g, void* ldsWaveBase, int lane)
{
#ifdef HAVE_GLOAD_LDS
    __builtin_amdgcn_global_load_lds(
        (const __attribute__((address_space(1))) void*)g,
        (__attribute__((address_space(3))) void*)ldsWaveBase, 16, 0, 0);
    (void)lane;
#else
    *(f16x8*)((char*)ldsWaveBase + lane * 16) = *(const f16x8*)g;
#endif
}

// ---------------------------------------------------------------------------
// Fused prep: grid (32,32,5), 256 threads.
//  z=0..3 : transpose+cast W (z<3 -> Wt + z*WE, z=3 -> Wto)
//  z=4    : cast x -> xh (2 f16x8 chunks per thread)
// ---------------------------------------------------------------------------
__global__ __launch_bounds__(256) void prep_all(
    const float* __restrict__ x,
    const float* __restrict__ Wq, const float* __restrict__ Wk,
    const float* __restrict__ Wv, const float* __restrict__ Wo,
    _Float16* __restrict__ xh, _Float16* __restrict__ Wt,
    _Float16* __restrict__ Wto)
{
    const int z = blockIdx.z;
    if (z == 4) {
        int base = ((blockIdx.y * 32 + blockIdx.x) * 256 + threadIdx.x) * 2;
        #pragma unroll
        for (int t = 0; t < 2; ++t) {
            int i = base + t;
            float4 a = ((const float4*)x)[i * 2];
            float4 b = ((const float4*)x)[i * 2 + 1];
            f16x8 o;
            o[0] = (_Float16)a.x; o[1] = (_Float16)a.y;
            o[2] = (_Float16)a.z; o[3] = (_Float16)a.w;
            o[4] = (_Float16)b.x; o[5] = (_Float16)b.y;
            o[6] = (_Float16)b.z; o[7] = (_Float16)b.w;
            ((f16x8*)xh)[i] = o;
        }
        return;
    }
    const float* W = z == 0 ? Wq : (z == 1 ? Wk : (z == 2 ? Wv : Wo));
    _Float16* D = (z == 3) ? Wto : (Wt + (size_t)z * EMB * EMB);
    __shared__ float tile[32][33];
    const int tx = threadIdx.x & 31, ty = threadIdx.x >> 5; // (32, 8)
    const int n0 = blockIdx.x * 32, k0 = blockIdx.y * 32;
    #pragma unroll
    for (int j = 0; j < 4; ++j)
        tile[ty + j * 8][tx] = W[(size_t)(k0 + ty + j * 8) * EMB + n0 + tx];
    __syncthreads();
    #pragma unroll
    for (int j = 0; j < 4; ++j)
        D[(size_t)(n0 + ty + j * 8) * EMB + k0 + tx] =
            (_Float16)tile[tx][ty + j * 8];
}

// ---------------------------------------------------------------------------
// fp16 MFMA GEMM: C[M,N] = A[M,K=1024] @ Bt[N,K]^T.
// 128x128 tile, BK=32, 4 waves (2x2), wave tile 64x64 = 4x4 16x16 frags.
// MODE 0: N=3072 fused QKV -> writes fp16 [B,H,T,D], alpha=QALPHA on Q.
// MODE 1: N=1024 -> writes fp32 out + bias.
// ---------------------------------------------------------------------------
template <int MODE>
__global__ __launch_bounds__(256) void gemm_mfma(
    const _Float16* __restrict__ A, const _Float16* __restrict__ Bt,
    _Float16* __restrict__ Qh, _Float16* __restrict__ Kh,
    _Float16* __restrict__ Vh,
    float* __restrict__ outf, const float* __restrict__ bias)
{
    __shared__ __align__(16) _Float16 As[128 * 32]; // 8 KB, row-major [m][k]
    __shared__ __align__(16) _Float16 Bs[128 * 32]; // 8 KB, row-major [n][k]

    const int tid = threadIdx.x;
    const int w = tid >> 6, lane = tid & 63;
    const int l15 = lane & 15, g4 = lane >> 4;
    const int wm = w >> 1, wn = w & 1;
    const int row0 = blockIdx.y * 128, col0 = blockIdx.x * 128;

    f32x4 acc[4][4];
    #pragma unroll
    for (int mt = 0; mt < 4; ++mt)
        #pragma unroll
        for (int nt = 0; nt < 4; ++nt)
            acc[mt][nt] = (f32x4){0.f, 0.f, 0.f, 0.f};

    for (int k0 = 0; k0 < EMB; k0 += 32) {
        __syncthreads(); // previous compute done; safe to overwrite tiles
        #pragma unroll
        for (int i = 0; i < 2; ++i) {
            int c = (i << 8) + tid;       // 16B chunk id, 0..511
            int row = c >> 2, u = c & 3;  // row 0..127, 16B-unit in k
            stage16(&A[(size_t)(row0 + row) * EMB + k0 + (u << 3)],
                    (char*)As + (i << 12) + (w << 10), lane);
            stage16(&Bt[(size_t)(col0 + row) * EMB + k0 + (u << 3)],
                    (char*)Bs + (i << 12) + (w << 10), lane);
        }
        __syncthreads(); // staging visible (compiler drains vmcnt pre-barrier)

        f16x8 af[4], bf[4];
        #pragma unroll
        for (int mt = 0; mt < 4; ++mt)
            af[mt] = *(const f16x8*)((const char*)As +
                     ((wm << 6) + (mt << 4) + l15) * 64 + (g4 << 4));
        #pragma unroll
        for (int nt = 0; nt < 4; ++nt)
            bf[nt] = *(const f16x8*)((const char*)Bs +
                     ((wn << 6) + (nt << 4) + l15) * 64 + (g4 << 4));
        #pragma unroll
        for (int mt = 0; mt < 4; ++mt)
            #pragma unroll
            for (int nt = 0; nt < 4; ++nt)
                acc[mt][nt] = __builtin_amdgcn_mfma_f32_16x16x32_f16(
                    af[mt], bf[nt], acc[mt][nt], 0, 0, 0);
    }

    // Epilogue. C/D layout: col = lane&15, row = 4*(lane>>4) + reg.
    #pragma unroll
    for (int mt = 0; mt < 4; ++mt) {
        int m = row0 + (wm << 6) + (mt << 4) + (g4 << 2);
        #pragma unroll
        for (int nt = 0; nt < 4; ++nt) {
            int gcol = col0 + (wn << 6) + (nt << 4) + l15;
            if (MODE == 0) {
                int proj = gcol >> 10, pc = gcol & 1023;
                int h = pc >> 6, d = pc & 63;
                _Float16* dst = proj == 0 ? Qh : (proj == 1 ? Kh : Vh);
                float alpha = proj == 0 ? QALPHA : 1.0f;
                int b = m >> 11, t = m & 2047;
                #pragma unroll
                for (int r = 0; r < 4; ++r)
                    dst[(((size_t)(b * NUM_HEADS + h)) * SEQ + t + r) * HEAD_D + d] =
                        (_Float16)(acc[mt][nt][r] * alpha);
            } else {
                float bz = bias[gcol];
                #pragma unroll
                for (int r = 0; r < 4; ++r)
                    outf[(size_t)(m + r) * EMB + gcol] = acc[mt][nt][r] + bz;
            }
        }
    }
}

// ---------------------------------------------------------------------------
// One 64q x 64kv attention tile step: S^T = K Q^T (swapped MFMA, lane owns
// one q row), exp2-domain online softmax (raw v_exp_f32) with defer-max
// (skip rescale while max lags <= 8 log2 units; P <= 256, fp16-safe),
// packed cvt_pkrtz P->f16, P roundtrip through wave-private LDS, acc += P@V.
// ---------------------------------------------------------------------------
__device__ __forceinline__ void attn_tile(
    const char* __restrict__ KsC, const char* __restrict__ VtC,
    char* __restrict__ pwv,
    f16x8 qf0, f16x8 qf1, f32x4 (&acc)[4], float& m, float& l,
    bool diag, int qrel, int l15, int g)
{
    f32x4 st[4];
    #pragma unroll
    for (int nt = 0; nt < 4; ++nt) {
        int kvl = (nt << 4) + l15;
        f16x8 kf0 = *(const f16x8*)&KsC[kvl * 128 + (((g << 4)) ^ ((kvl & 7) << 4))];
        f16x8 kf1 = *(const f16x8*)&KsC[kvl * 128 + ((64 + (g << 4)) ^ ((kvl & 7) << 4))];
        f32x4 z = (f32x4){0.f, 0.f, 0.f, 0.f};
        z = __builtin_amdgcn_mfma_f32_16x16x32_f16(kf0, qf0, z, 0, 0, 0);
        z = __builtin_amdgcn_mfma_f32_16x16x32_f16(kf1, qf1, z, 0, 0, 0);
        st[nt] = z;
    }
    if (diag) {
        #pragma unroll
        for (int nt = 0; nt < 4; ++nt)
            #pragma unroll
            for (int r = 0; r < 4; ++r)
                if ((nt << 4) + (g << 2) + r > qrel) st[nt][r] = -1e30f;
    }

    float mx;
    {
        float a0 = fmaxf(fmaxf(st[0][0], st[0][1]), fmaxf(st[0][2], st[0][3]));
        float a1 = fmaxf(fmaxf(st[1][0], st[1][1]), fmaxf(st[1][2], st[1][3]));
        float a2 = fmaxf(fmaxf(st[2][0], st[2][1]), fmaxf(st[2][2], st[2][3]));
        float a3 = fmaxf(fmaxf(st[3][0], st[3][1]), fmaxf(st[3][2], st[3][3]));
        mx = fmaxf(fmaxf(a0, a1), fmaxf(a2, a3));
    }
    mx = fmaxf(mx, __shfl_xor(mx, 16));
    mx = fmaxf(mx, __shfl_xor(mx, 32));

    // defer-max: only rescale when the running max lags by > 8 (log2 units)
    if (!__all(mx - m <= 8.0f)) {
        float nm = fmaxf(m, mx);
        float sc = fast_exp2(m - nm);
        m = nm;
        l *= sc;
        #pragma unroll
        for (int r = 0; r < 4; ++r) {
            float scr = __shfl(sc, (g << 2) + r); // q row 4g+r's factor
            acc[0][r] *= scr; acc[1][r] *= scr;
            acc[2][r] *= scr; acc[3][r] *= scr;
        }
    }

    float ps = 0.f;
    #pragma unroll
    for (int nt = 0; nt < 4; ++nt)
        #pragma unroll
        for (int r = 0; r < 4; ++r) {
            float p = fast_exp2(st[nt][r] - m);
            st[nt][r] = p;
            ps += p;
        }
    ps += __shfl_xor(ps, 16);
    ps += __shfl_xor(ps, 32);
    l += ps;

    // P -> wave-private LDS as P[q][kv] (8x packed b32 writes)
    #pragma unroll
    for (int nt = 0; nt < 4; ++nt)
        #pragma unroll
        for (int rr = 0; rr < 2; ++rr) {
            int kvb = (nt << 4) + (g << 2) + (rr << 1);
            f16x2 pv = cvt_pk_f16(st[nt][rr * 2], st[nt][rr * 2 + 1]);
            *(f16x2*)&pwv[l15 * 128 + ((kvb << 1) ^ ((l15 & 7) << 4))] = pv;
        }
    f16x8 pa0 = *(const f16x8*)&pwv[l15 * 128 + (((g << 4)) ^ ((l15 & 7) << 4))];
    f16x8 pa1 = *(const f16x8*)&pwv[l15 * 128 + ((64 + (g << 4)) ^ ((l15 & 7) << 4))];

    #pragma unroll
    for (int dn = 0; dn < 4; ++dn) {
        int d = (dn << 4) + l15;
        int swz = ((d & 7) ^ (d >> 3)) & 7;
        f16x8 vf0 = *(const f16x8*)&VtC[d * 128 + (((g << 4)) ^ (swz << 4))];
        f16x8 vf1 = *(const f16x8*)&VtC[d * 128 + ((64 + (g << 4)) ^ (swz << 4))];
        acc[dn] = __builtin_amdgcn_mfma_f32_16x16x32_f16(pa0, vf0, acc[dn], 0, 0, 0);
        acc[dn] = __builtin_amdgcn_mfma_f32_16x16x32_f16(pa1, vf1, acc[dn], 0, 0, 0);
    }
}

// ---------------------------------------------------------------------------
// Flash attention, causal, fp16 MFMA. Paired q-tiles (qtA, 31-qtA): 33
// tile-computes per block (perfect FLOP balance), K/V staged once per pair,
// dual independent chains in phase 1 (2x ILP). Double-buffered K/V.
// ---------------------------------------------------------------------------
__global__ __launch_bounds__(256) void attn_mfma(
    const _Float16* __restrict__ Qh, const _Float16* __restrict__ Kh,
    const _Float16* __restrict__ Vh, _Float16* __restrict__ O)
{
    __shared__ char lds[48 * 1024];
    // Ks buf b: b*8192 | Vt buf b: 16384 + b*8192 | PwA: 32768 | PwB: 40960

    const int qtA = blockIdx.x;            // 0..15
    const int qtB = (SEQ / 64 - 1) - qtA;  // 31..16
    const int bh = blockIdx.y;
    const int q0A = qtA << 6, q0B = qtB << 6;
    const int tid = threadIdx.x;
    const int w = tid >> 6, lane = tid & 63;
    const int l15 = lane & 15, g = lane >> 4;

    const size_t headbase = (size_t)bh * SEQ * HEAD_D;

    const int qrowA = q0A + (w << 4) + l15;
    const int qrowB = q0B + (w << 4) + l15;
    f16x8 qfA0 = *(const f16x8*)&Qh[headbase + (size_t)qrowA * HEAD_D + (g << 3)];
    f16x8 qfA1 = *(const f16x8*)&Qh[headbase + (size_t)qrowA * HEAD_D + 32 + (g << 3)];
    f16x8 qfB0 = *(const f16x8*)&Qh[headbase + (size_t)qrowB * HEAD_D + (g << 3)];
    f16x8 qfB1 = *(const f16x8*)&Qh[headbase + (size_t)qrowB * HEAD_D + 32 + (g << 3)];

    f32x4 accA[4], accB[4];
    #pragma unroll
    for (int dn = 0; dn < 4; ++dn) {
        accA[dn] = (f32x4){0.f, 0.f, 0.f, 0.f};
        accB[dn] = (f32x4){0.f, 0.f, 0.f, 0.f};
    }
    float mA = -1e30f, lA = 0.f, mB = -1e30f, lB = 0.f;

    const int c0 = tid, c1 = 256 + tid;
    const int row_a = c0 >> 3, u_a = c0 & 7;
    const int row_b = c1 >> 3, u_b = c1 & 7;

    // ---- prologue: stage tile 0 into buffer 0 ----
    {
        f16x8 k8a = *(const f16x8*)&Kh[headbase + (size_t)row_a * HEAD_D + (u_a << 3)];
        f16x8 v8a = *(const f16x8*)&Vh[headbase + (size_t)row_a * HEAD_D + (u_a << 3)];
        f16x8 k8b = *(const f16x8*)&Kh[headbase + (size_t)row_b * HEAD_D + (u_b << 3)];
        f16x8 v8b = *(const f16x8*)&Vh[headbase + (size_t)row_b * HEAD_D + (u_b << 3)];
        char* Ks0 = lds;
        char* Vt0 = lds + 16384;
        *(f16x8*)&Ks0[row_a * 128 + ((u_a ^ (row_a & 7)) << 4)] = k8a;
        *(f16x8*)&Ks0[row_b * 128 + ((u_b ^ (row_b & 7)) << 4)] = k8b;
        #pragma unroll
        for (int j = 0; j < 8; ++j) {
            int da = (u_a << 3) + j, db = (u_b << 3) + j;
            *(_Float16*)&Vt0[da * 128 +
                ((row_a << 1) ^ ((((da & 7) ^ (da >> 3)) & 7) << 4))] = v8a[j];
            *(_Float16*)&Vt0[db * 128 +
                ((row_b << 1) ^ ((((db & 7) ^ (db >> 3)) & 7) << 4))] = v8b[j];
        }
    }
    __syncthreads();

    char* pwvA = lds + 32768 + (w << 11);
    char* pwvB = lds + 40960 + (w << 11);

    int cur = 0;
    for (int kt = 0; kt <= qtB; ++kt) {
        const bool have_next = (kt < qtB);

        f16x8 k8a, v8a, k8b, v8b;
        if (have_next) {
            const size_t nb = headbase + (size_t)((kt + 1) << 6) * HEAD_D;
            k8a = *(const f16x8*)&Kh[nb + (size_t)row_a * HEAD_D + (u_a << 3)];
            v8a = *(const f16x8*)&Vh[nb + (size_t)row_a * HEAD_D + (u_a << 3)];
            k8b = *(const f16x8*)&Kh[nb + (size_t)row_b * HEAD_D + (u_b << 3)];
            v8b = *(const f16x8*)&Vh[nb + (size_t)row_b * HEAD_D + (u_b << 3)];
        }

        const char* KsC = lds + (cur << 13);
        const char* VtC = lds + 16384 + (cur << 13);
        const int qrel = (w << 4) + l15;

        if (kt <= qtA) {
            attn_tile(KsC, VtC, pwvA, qfA0, qfA1, accA, mA, lA,
                      kt == qtA, qrel, l15, g);
            attn_tile(KsC, VtC, pwvB, qfB0, qfB1, accB, mB, lB,
                      false, qrel, l15, g);
        } else {
            attn_tile(KsC, VtC, pwvB, qfB0, qfB1, accB, mB, lB,
                      kt == qtB, qrel, l15, g);
        }

        if (have_next) {
            char* KsN = lds + ((cur ^ 1) << 13);
            char* VtN = lds + 16384 + ((cur ^ 1) << 13);
            *(f16x8*)&KsN[row_a * 128 + ((u_a ^ (row_a & 7)) << 4)] = k8a;
            *(f16x8*)&KsN[row_b * 128 + ((u_b ^ (row_b & 7)) << 4)] = k8b;
            #pragma unroll
            for (int j = 0; j < 8; ++j) {
                int da = (u_a << 3) + j, db = (u_b << 3) + j;
                *(_Float16*)&VtN[da * 128 +
                    ((row_a << 1) ^ ((((da & 7) ^ (da >> 3)) & 7) << 4))] = v8a[j];
                *(_Float16*)&VtN[db * 128 +
                    ((row_b << 1) ^ ((((db & 7) ^ (db >> 3)) & 7) << 4))] = v8b[j];
            }
        }
        __syncthreads();
        cur ^= 1;
    }

    // ---- epilogue: normalize, write fp16 O[tok][h*64+d] for both tiles ----
    const int b = bh >> 4, h = bh & 15;
    const float rlA = 1.f / lA, rlB = 1.f / lB;
    #pragma unroll
    for (int r = 0; r < 4; ++r) {
        float invA = __shfl(rlA, (g << 2) + r);
        float invB = __shfl(rlB, (g << 2) + r);
        int tokA = (b << 11) + q0A + (w << 4) + (g << 2) + r;
        int tokB = (b << 11) + q0B + (w << 4) + (g << 2) + r;
        #pragma unroll
        for (int dn = 0; dn < 4; ++dn) {
            O[(size_t)tokA * EMB + (h << 6) + (dn << 4) + l15] =
                (_Float16)(accA[dn][r] * invA);
            O[(size_t)tokB * EMB + (h << 6) + (dn << 4) + l15] =
                (_Float16)(accB[dn][r] * invB);
        }
    }
}

// ---------------------------------------------------------------------------
extern "C" void kernel_launch(void* const* d_in, const int* in_sizes, int n_in,
                              void* d_out, int out_size, void* d_ws, size_t ws_size,
                              hipStream_t stream)
{
    const float* x  = (const float*)d_in[0];
    const float* Wq = (const float*)d_in[1];
    const float* Wk = (const float*)d_in[2];
    const float* Wv = (const float*)d_in[3];
    const float* Wo = (const float*)d_in[4];
    const float* bo = (const float*)d_in[5];
    float* out = (float*)d_out;

    const size_t ME = (size_t)MTOT * EMB;        // 4M elems
    const size_t WE = (size_t)EMB * EMB;         // 1M elems
    const size_t need = (ME + 3 * WE + WE + 3 * ME + ME) * sizeof(_Float16);
    if (ws_size < need) return;

    _Float16* xh  = (_Float16*)d_ws;
    _Float16* Wt  = xh + ME;
    _Float16* Wto = Wt + 3 * WE;
    _Float16* Qh  = Wto + WE;
    _Float16* Kh  = Qh + ME;
    _Float16* Vh  = Kh + ME;
    _Float16* Ow  = Vh + ME;

    // fused prep: 4 weight transposes + x cast in one dispatch
    prep_all<<<dim3(EMB / 32, EMB / 32, 5), 256, 0, stream>>>(
        x, Wq, Wk, Wv, Wo, xh, Wt, Wto);

    gemm_mfma<0><<<dim3(3 * EMB / 128, MTOT / 128), 256, 0, stream>>>(
        xh, Wt, Qh, Kh, Vh, nullptr, nullptr);

    attn_mfma<<<dim3(SEQ / 128, BATCH * NUM_HEADS), 256, 0, stream>>>(Qh, Kh, Vh, Ow);

    gemm_mfma<1><<<dim3(EMB / 128, MTOT / 128), 256, 0, stream>>>(
        Ow, Wto, nullptr, nullptr, nullptr, out, bo);
}

// Round 12
// 125.023 us; speedup vs baseline: 12.3064x; 1.0259x over previous
//
#include <hip/hip_runtime.h>

typedef __attribute__((ext_vector_type(8))) _Float16 f16x8;
typedef __attribute__((ext_vector_type(2))) _Float16 f16x2;
typedef __attribute__((ext_vector_type(2))) __fp16   fp16x2_raw;
typedef __attribute__((ext_vector_type(4))) float    f32x4;

#define NUM_HEADS 16
#define HEAD_D 64
#define EMB 1024
#define SEQ 2048
#define BATCH 2
#define MTOT (BATCH * SEQ) // 4096

// Q scale: 1/sqrt(64) * log2(e)  (softmax runs in exp2 domain)
#define QALPHA 0.18033688011112042f

__device__ __forceinline__ f16x2 cvt_pk_f16(float lo, float hi)
{
    fp16x2_raw r = __builtin_amdgcn_cvt_pkrtz(lo, hi);
    return __builtin_bit_cast(f16x2, r);
}

// Raw v_exp_f32 (2^x). Guarded: fall back to fast __expf if builtin absent.
#if defined(__has_builtin)
#if __has_builtin(__builtin_amdgcn_exp2f)
#define HAVE_EXP2 1
#endif
#endif
__device__ __forceinline__ float fast_exp2(float x)
{
#ifdef HAVE_EXP2
    return __builtin_amdgcn_exp2f(x);
#else
    return __expf(x * 0.6931471805599453f);
#endif
}

// ---------------------------------------------------------------------------
// global -> LDS direct staging (16 B per lane). LDS dest is wave-uniform
// base + lane*16 (HW behavior); fallback reg-stages to the same address.
// ---------------------------------------------------------------------------
#if defined(__has_builtin)
#if __has_builtin(__builtin_amdgcn_global_load_lds)
#define HAVE_GLOAD_LDS 1
#endif
#endif

__device__ __forceinline__ void stage16(const void* g, void* ldsWaveBase, int lane)
{
#ifdef HAVE_GLOAD_LDS
    __builtin_amdgcn_global_load_lds(
        (const __attribute__((address_space(1))) void*)g,
        (__attribute__((address_space(3))) void*)ldsWaveBase, 16, 0, 0);
    (void)lane;
#else
    *(f16x8*)((char*)ldsWaveBase + lane * 16) = *(const f16x8*)g;
#endif
}

// ---------------------------------------------------------------------------
// Fused prep: grid (32,32,5), 256 threads.
//  z=0..3 : transpose+cast W (z<3 -> Wt + z*WE, z=3 -> Wto)
//  z=4    : cast x -> xh (2 f16x8 chunks per thread)
// ---------------------------------------------------------------------------
__global__ __launch_bounds__(256) void prep_all(
    const float* __restrict__ x,
    const float* __restrict__ Wq, const float* __restrict__ Wk,
    const float* __restrict__ Wv, const float* __restrict__ Wo,
    _Float16* __restrict__ xh, _Float16* __restrict__ Wt,
    _Float16* __restrict__ Wto)
{
    const int z = blockIdx.z;
    if (z == 4) {
        int base = ((blockIdx.y * 32 + blockIdx.x) * 256 + threadIdx.x) * 2;
        #pragma unroll
        for (int t = 0; t < 2; ++t) {
            int i = base + t;
            float4 a = ((const float4*)x)[i * 2];
            float4 b = ((const float4*)x)[i * 2 + 1];
            f16x8 o;
            o[0] = (_Float16)a.x; o[1] = (_Float16)a.y;
            o[2] = (_Float16)a.z; o[3] = (_Float16)a.w;
            o[4] = (_Float16)b.x; o[5] = (_Float16)b.y;
            o[6] = (_Float16)b.z; o[7] = (_Float16)b.w;
            ((f16x8*)xh)[i] = o;
        }
        return;
    }
    const float* W = z == 0 ? Wq : (z == 1 ? Wk : (z == 2 ? Wv : Wo));
    _Float16* D = (z == 3) ? Wto : (Wt + (size_t)z * EMB * EMB);
    __shared__ float tile[32][33];
    const int tx = threadIdx.x & 31, ty = threadIdx.x >> 5; // (32, 8)
    const int n0 = blockIdx.x * 32, k0 = blockIdx.y * 32;
    #pragma unroll
    for (int j = 0; j < 4; ++j)
        tile[ty + j * 8][tx] = W[(size_t)(k0 + ty + j * 8) * EMB + n0 + tx];
    __syncthreads();
    #pragma unroll
    for (int j = 0; j < 4; ++j)
        D[(size_t)(n0 + ty + j * 8) * EMB + k0 + tx] =
            (_Float16)tile[tx][ty + j * 8];
}

// ---------------------------------------------------------------------------
// V [B,H,T,D] -> V^T [B,H,D,T] (per-head 64x64 tiled transpose)
// ---------------------------------------------------------------------------
__global__ __launch_bounds__(256) void transpose_v(
    const _Float16* __restrict__ Vh, _Float16* __restrict__ VhT)
{
    __shared__ _Float16 tile[64][72]; // 144 B rows: 16B-aligned vector reads
    const int t0 = blockIdx.x << 6, bh = blockIdx.y;
    const size_t hb  = (size_t)bh * SEQ * HEAD_D;
    const size_t hb2 = (size_t)bh * HEAD_D * SEQ;
    const int tid = threadIdx.x;
    #pragma unroll
    for (int i = 0; i < 2; ++i) {
        int c = (i << 8) + tid, row = c >> 3, u = c & 7; // row = t-rel
        f16x8 v = *(const f16x8*)&Vh[hb + (size_t)(t0 + row) * HEAD_D + (u << 3)];
        #pragma unroll
        for (int j = 0; j < 8; ++j)
            tile[(u << 3) + j][row] = v[j];
    }
    __syncthreads();
    #pragma unroll
    for (int i = 0; i < 2; ++i) {
        int c = (i << 8) + tid, row = c >> 3, u = c & 7; // row = d
        *(f16x8*)&VhT[hb2 + (size_t)row * SEQ + t0 + (u << 3)] =
            *(const f16x8*)&tile[row][u << 3];
    }
}

// ---------------------------------------------------------------------------
// fp16 MFMA GEMM: C[M,N] = A[M,K=1024] @ Bt[N,K]^T.
// 128x128 tile, BK=32, 4 waves (2x2), wave tile 64x64 = 4x4 16x16 frags.
// MODE 0: N=3072 fused QKV -> writes fp16 [B,H,T,D], alpha=QALPHA on Q.
// MODE 1: N=1024 -> writes fp32 out + bias.
// ---------------------------------------------------------------------------
template <int MODE>
__global__ __launch_bounds__(256) void gemm_mfma(
    const _Float16* __restrict__ A, const _Float16* __restrict__ Bt,
    _Float16* __restrict__ Qh, _Float16* __restrict__ Kh,
    _Float16* __restrict__ Vh,
    float* __restrict__ outf, const float* __restrict__ bias)
{
    __shared__ __align__(16) _Float16 As[128 * 32]; // 8 KB, row-major [m][k]
    __shared__ __align__(16) _Float16 Bs[128 * 32]; // 8 KB, row-major [n][k]

    const int tid = threadIdx.x;
    const int w = tid >> 6, lane = tid & 63;
    const int l15 = lane & 15, g4 = lane >> 4;
    const int wm = w >> 1, wn = w & 1;
    const int row0 = blockIdx.y * 128, col0 = blockIdx.x * 128;

    f32x4 acc[4][4];
    #pragma unroll
    for (int mt = 0; mt < 4; ++mt)
        #pragma unroll
        for (int nt = 0; nt < 4; ++nt)
            acc[mt][nt] = (f32x4){0.f, 0.f, 0.f, 0.f};

    for (int k0 = 0; k0 < EMB; k0 += 32) {
        __syncthreads(); // previous compute done; safe to overwrite tiles
        #pragma unroll
        for (int i = 0; i < 2; ++i) {
            int c = (i << 8) + tid;       // 16B chunk id, 0..511
            int row = c >> 2, u = c & 3;  // row 0..127, 16B-unit in k
            stage16(&A[(size_t)(row0 + row) * EMB + k0 + (u << 3)],
                    (char*)As + (i << 12) + (w << 10), lane);
            stage16(&Bt[(size_t)(col0 + row) * EMB + k0 + (u << 3)],
                    (char*)Bs + (i << 12) + (w << 10), lane);
        }
        __syncthreads(); // staging visible (compiler drains vmcnt pre-barrier)

        f16x8 af[4], bf[4];
        #pragma unroll
        for (int mt = 0; mt < 4; ++mt)
            af[mt] = *(const f16x8*)((const char*)As +
                     ((wm << 6) + (mt << 4) + l15) * 64 + (g4 << 4));
        #pragma unroll
        for (int nt = 0; nt < 4; ++nt)
            bf[nt] = *(const f16x8*)((const char*)Bs +
                     ((wn << 6) + (nt << 4) + l15) * 64 + (g4 << 4));
        #pragma unroll
        for (int mt = 0; mt < 4; ++mt)
            #pragma unroll
            for (int nt = 0; nt < 4; ++nt)
                acc[mt][nt] = __builtin_amdgcn_mfma_f32_16x16x32_f16(
                    af[mt], bf[nt], acc[mt][nt], 0, 0, 0);
    }

    // Epilogue. C/D layout: col = lane&15, row = 4*(lane>>4) + reg.
    #pragma unroll
    for (int mt = 0; mt < 4; ++mt) {
        int m = row0 + (wm << 6) + (mt << 4) + (g4 << 2);
        #pragma unroll
        for (int nt = 0; nt < 4; ++nt) {
            int gcol = col0 + (wn << 6) + (nt << 4) + l15;
            if (MODE == 0) {
                int proj = gcol >> 10, pc = gcol & 1023;
                int h = pc >> 6, d = pc & 63;
                _Float16* dst = proj == 0 ? Qh : (proj == 1 ? Kh : Vh);
                float alpha = proj == 0 ? QALPHA : 1.0f;
                int b = m >> 11, t = m & 2047;
                #pragma unroll
                for (int r = 0; r < 4; ++r)
                    dst[(((size_t)(b * NUM_HEADS + h)) * SEQ + t + r) * HEAD_D + d] =
                        (_Float16)(acc[mt][nt][r] * alpha);
            } else {
                float bz = bias[gcol];
                #pragma unroll
                for (int r = 0; r < 4; ++r)
                    outf[(size_t)(m + r) * EMB + gcol] = acc[mt][nt][r] + bz;
            }
        }
    }
}

// ---------------------------------------------------------------------------
// Stage one 64-kv K tile + V^T tile into LDS via global_load_lds with
// pre-swizzled global source (LDS dest linear; chunk (row,u) holds global
// (row, u^(row&7)) -> read formulas identical to the verified K-frag path).
// ---------------------------------------------------------------------------
__device__ __forceinline__ void stage_kv_tile(
    const _Float16* __restrict__ KhB, const _Float16* __restrict__ VtB,
    int kv0, char* __restrict__ KsBuf, char* __restrict__ VtBuf,
    int w, int lane)
{
    #pragma unroll
    for (int i = 0; i < 2; ++i) {
        int c = (i << 8) + (w << 6) + lane;
        int row = c >> 3, u = c & 7;
        int us = u ^ (row & 7);
        stage16(&KhB[(size_t)(kv0 + row) * HEAD_D + (us << 3)],
                KsBuf + (i << 12) + (w << 10), lane);
        stage16(&VtB[(size_t)row * SEQ + kv0 + (us << 3)],
                VtBuf + (i << 12) + (w << 10), lane);
    }
}

// ---------------------------------------------------------------------------
// One 64q x 64kv attention tile step: S^T = K Q^T (swapped MFMA, lane owns
// one q row), exp2-domain online softmax (raw v_exp_f32) with defer-max,
// packed cvt_pkrtz P->f16, P roundtrip through wave-private LDS, acc += P@V.
// V^T is staged like K (pre-transposed in global), so the B-frag read is the
// K-frag formula.
// ---------------------------------------------------------------------------
__device__ __forceinline__ void attn_tile(
    const char* __restrict__ KsC, const char* __restrict__ VtC,
    char* __restrict__ pwv,
    f16x8 qf0, f16x8 qf1, f32x4 (&acc)[4], float& m, float& l,
    bool diag, int qrel, int l15, int g)
{
    f32x4 st[4];
    #pragma unroll
    for (int nt = 0; nt < 4; ++nt) {
        int kvl = (nt << 4) + l15;
        f16x8 kf0 = *(const f16x8*)&KsC[kvl * 128 + (((g << 4)) ^ ((kvl & 7) << 4))];
        f16x8 kf1 = *(const f16x8*)&KsC[kvl * 128 + ((64 + (g << 4)) ^ ((kvl & 7) << 4))];
        f32x4 z = (f32x4){0.f, 0.f, 0.f, 0.f};
        z = __builtin_amdgcn_mfma_f32_16x16x32_f16(kf0, qf0, z, 0, 0, 0);
        z = __builtin_amdgcn_mfma_f32_16x16x32_f16(kf1, qf1, z, 0, 0, 0);
        st[nt] = z;
    }
    if (diag) {
        #pragma unroll
        for (int nt = 0; nt < 4; ++nt)
            #pragma unroll
            for (int r = 0; r < 4; ++r)
                if ((nt << 4) + (g << 2) + r > qrel) st[nt][r] = -1e30f;
    }

    float mx;
    {
        float a0 = fmaxf(fmaxf(st[0][0], st[0][1]), fmaxf(st[0][2], st[0][3]));
        float a1 = fmaxf(fmaxf(st[1][0], st[1][1]), fmaxf(st[1][2], st[1][3]));
        float a2 = fmaxf(fmaxf(st[2][0], st[2][1]), fmaxf(st[2][2], st[2][3]));
        float a3 = fmaxf(fmaxf(st[3][0], st[3][1]), fmaxf(st[3][2], st[3][3]));
        mx = fmaxf(fmaxf(a0, a1), fmaxf(a2, a3));
    }
    mx = fmaxf(mx, __shfl_xor(mx, 16));
    mx = fmaxf(mx, __shfl_xor(mx, 32));

    // defer-max: only rescale when the running max lags by > 8 (log2 units)
    if (!__all(mx - m <= 8.0f)) {
        float nm = fmaxf(m, mx);
        float sc = fast_exp2(m - nm);
        m = nm;
        l *= sc;
        #pragma unroll
        for (int r = 0; r < 4; ++r) {
            float scr = __shfl(sc, (g << 2) + r); // q row 4g+r's factor
            acc[0][r] *= scr; acc[1][r] *= scr;
            acc[2][r] *= scr; acc[3][r] *= scr;
        }
    }

    float ps = 0.f;
    #pragma unroll
    for (int nt = 0; nt < 4; ++nt)
        #pragma unroll
        for (int r = 0; r < 4; ++r) {
            float p = fast_exp2(st[nt][r] - m);
            st[nt][r] = p;
            ps += p;
        }
    ps += __shfl_xor(ps, 16);
    ps += __shfl_xor(ps, 32);
    l += ps;

    // P -> wave-private LDS as P[q][kv] (8x packed b32 writes)
    #pragma unroll
    for (int nt = 0; nt < 4; ++nt)
        #pragma unroll
        for (int rr = 0; rr < 2; ++rr) {
            int kvb = (nt << 4) + (g << 2) + (rr << 1);
            f16x2 pv = cvt_pk_f16(st[nt][rr * 2], st[nt][rr * 2 + 1]);
            *(f16x2*)&pwv[l15 * 128 + ((kvb << 1) ^ ((l15 & 7) << 4))] = pv;
        }
    f16x8 pa0 = *(const f16x8*)&pwv[l15 * 128 + (((g << 4)) ^ ((l15 & 7) << 4))];
    f16x8 pa1 = *(const f16x8*)&pwv[l15 * 128 + ((64 + (g << 4)) ^ ((l15 & 7) << 4))];

    #pragma unroll
    for (int dn = 0; dn < 4; ++dn) {
        int d = (dn << 4) + l15;
        f16x8 vf0 = *(const f16x8*)&VtC[d * 128 + (((g << 4)) ^ ((d & 7) << 4))];
        f16x8 vf1 = *(const f16x8*)&VtC[d * 128 + ((64 + (g << 4)) ^ ((d & 7) << 4))];
        acc[dn] = __builtin_amdgcn_mfma_f32_16x16x32_f16(pa0, vf0, acc[dn], 0, 0, 0);
        acc[dn] = __builtin_amdgcn_mfma_f32_16x16x32_f16(pa1, vf1, acc[dn], 0, 0, 0);
    }
}

// ---------------------------------------------------------------------------
// Flash attention, causal, fp16 MFMA. Paired q-tiles (qtA, 31-qtA): 33
// tile-computes per block (perfect FLOP balance), K/V^T staged once per pair
// via global_load_lds double-buffer (issue into dead buffer -> compute ->
// barrier drain). Dual independent chains in phase 1 (2x ILP).
// ---------------------------------------------------------------------------
__global__ __launch_bounds__(256) void attn_mfma(
    const _Float16* __restrict__ Qh, const _Float16* __restrict__ Kh,
    const _Float16* __restrict__ VhT, _Float16* __restrict__ O)
{
    __shared__ char lds[48 * 1024];
    // Ks buf b: b*8192 | Vt buf b: 16384 + b*8192 | PwA: 32768 | PwB: 40960

    const int qtA = blockIdx.x;            // 0..15
    const int qtB = (SEQ / 64 - 1) - qtA;  // 31..16
    const int bh = blockIdx.y;
    const int q0A = qtA << 6, q0B = qtB << 6;
    const int tid = threadIdx.x;
    const int w = tid >> 6, lane = tid & 63;
    const int l15 = lane & 15, g = lane >> 4;

    const _Float16* KhB = Kh  + (size_t)bh * SEQ * HEAD_D;
    const _Float16* VtB = VhT + (size_t)bh * HEAD_D * SEQ;
    const size_t headbase = (size_t)bh * SEQ * HEAD_D;

    const int qrowA = q0A + (w << 4) + l15;
    const int qrowB = q0B + (w << 4) + l15;
    f16x8 qfA0 = *(const f16x8*)&Qh[headbase + (size_t)qrowA * HEAD_D + (g << 3)];
    f16x8 qfA1 = *(const f16x8*)&Qh[headbase + (size_t)qrowA * HEAD_D + 32 + (g << 3)];
    f16x8 qfB0 = *(const f16x8*)&Qh[headbase + (size_t)qrowB * HEAD_D + (g << 3)];
    f16x8 qfB1 = *(const f16x8*)&Qh[headbase + (size_t)qrowB * HEAD_D + 32 + (g << 3)];

    f32x4 accA[4], accB[4];
    #pragma unroll
    for (int dn = 0; dn < 4; ++dn) {
        accA[dn] = (f32x4){0.f, 0.f, 0.f, 0.f};
        accB[dn] = (f32x4){0.f, 0.f, 0.f, 0.f};
    }
    float mA = -1e30f, lA = 0.f, mB = -1e30f, lB = 0.f;

    // ---- prologue: stage tile 0 into buffer 0 ----
    stage_kv_tile(KhB, VtB, 0, lds, lds + 16384, w, lane);
    __syncthreads(); // vmcnt drained before barrier release

    char* pwvA = lds + 32768 + (w << 11);
    char* pwvB = lds + 40960 + (w << 11);

    int cur = 0;
    for (int kt = 0; kt <= qtB; ++kt) {
        // issue next tile's glds into the dead buffer (latency hides)
        if (kt < qtB)
            stage_kv_tile(KhB, VtB, (kt + 1) << 6,
                          lds + ((cur ^ 1) << 13),
                          lds + 16384 + ((cur ^ 1) << 13), w, lane);

        const char* KsC = lds + (cur << 13);
        const char* VtC = lds + 16384 + (cur << 13);
        const int qrel = (w << 4) + l15;

        if (kt <= qtA) {
            attn_tile(KsC, VtC, pwvA, qfA0, qfA1, accA, mA, lA,
                      kt == qtA, qrel, l15, g);
            attn_tile(KsC, VtC, pwvB, qfB0, qfB1, accB, mB, lB,
                      false, qrel, l15, g);
        } else {
            attn_tile(KsC, VtC, pwvB, qfB0, qfB1, accB, mB, lB,
                      kt == qtB, qrel, l15, g);
        }

        __syncthreads(); // drains vmcnt: next tile resident before flip
        cur ^= 1;
    }

    // ---- epilogue: normalize, write fp16 O[tok][h*64+d] for both tiles ----
    const int b = bh >> 4, h = bh & 15;
    const float rlA = 1.f / lA, rlB = 1.f / lB;
    #pragma unroll
    for (int r = 0; r < 4; ++r) {
        float invA = __shfl(rlA, (g << 2) + r);
        float invB = __shfl(rlB, (g << 2) + r);
        int tokA = (b << 11) + q0A + (w << 4) + (g << 2) + r;
        int tokB = (b << 11) + q0B + (w << 4) + (g << 2) + r;
        #pragma unroll
        for (int dn = 0; dn < 4; ++dn) {
            O[(size_t)tokA * EMB + (h << 6) + (dn << 4) + l15] =
                (_Float16)(accA[dn][r] * invA);
            O[(size_t)tokB * EMB + (h << 6) + (dn << 4) + l15] =
                (_Float16)(accB[dn][r] * invB);
        }
    }
}

// ---------------------------------------------------------------------------
extern "C" void kernel_launch(void* const* d_in, const int* in_sizes, int n_in,
                              void* d_out, int out_size, void* d_ws, size_t ws_size,
                              hipStream_t stream)
{
    const float* x  = (const float*)d_in[0];
    const float* Wq = (const float*)d_in[1];
    const float* Wk = (const float*)d_in[2];
    const float* Wv = (const float*)d_in[3];
    const float* Wo = (const float*)d_in[4];
    const float* bo = (const float*)d_in[5];
    float* out = (float*)d_out;

    const size_t ME = (size_t)MTOT * EMB;        // 4M elems
    const size_t WE = (size_t)EMB * EMB;         // 1M elems
    // xh + Wt(3) + Wto + Qh + Kh + Vh + Ow + VhT = 6*ME + 4*WE elems fp16
    const size_t need = (6 * ME + 4 * WE) * sizeof(_Float16);
    if (ws_size < need) return;

    _Float16* xh  = (_Float16*)d_ws;
    _Float16* Wt  = xh + ME;
    _Float16* Wto = Wt + 3 * WE;
    _Float16* Qh  = Wto + WE;
    _Float16* Kh  = Qh + ME;
    _Float16* Vh  = Kh + ME;
    _Float16* Ow  = Vh + ME;
    _Float16* VhT = Ow + ME;

    // fused prep: 4 weight transposes + x cast in one dispatch
    prep_all<<<dim3(EMB / 32, EMB / 32, 5), 256, 0, stream>>>(
        x, Wq, Wk, Wv, Wo, xh, Wt, Wto);

    gemm_mfma<0><<<dim3(3 * EMB / 128, MTOT / 128), 256, 0, stream>>>(
        xh, Wt, Qh, Kh, Vh, nullptr, nullptr);

    // V -> V^T in global (enables K-identical vectorized V staging in attn)
    transpose_v<<<dim3(SEQ / 64, BATCH * NUM_HEADS), 256, 0, stream>>>(Vh, VhT);

    attn_mfma<<<dim3(SEQ / 128, BATCH * NUM_HEADS), 256, 0, stream>>>(Qh, Kh, VhT, Ow);

    gemm_mfma<1><<<dim3(EMB / 128, MTOT / 128), 256, 0, stream>>>(
        Ow, Wto, nullptr, nullptr, nullptr, out, bo);
}

// Round 13
// 122.634 us; speedup vs baseline: 12.5462x; 1.0195x over previous
//
#include <hip/hip_runtime.h>

typedef __attribute__((ext_vector_type(8))) _Float16 f16x8;
typedef __attribute__((ext_vector_type(4))) _Float16 f16x4;
typedef __attribute__((ext_vector_type(2))) _Float16 f16x2;
typedef __attribute__((ext_vector_type(2))) __fp16   fp16x2_raw;
typedef __attribute__((ext_vector_type(4))) float    f32x4;

#define NUM_HEADS 16
#define HEAD_D 64
#define EMB 1024
#define SEQ 2048
#define BATCH 2
#define MTOT (BATCH * SEQ) // 4096

// Q scale: 1/sqrt(64) * log2(e)  (softmax runs in exp2 domain)
#define QALPHA 0.18033688011112042f

__device__ __forceinline__ f16x2 cvt_pk_f16(float lo, float hi)
{
    fp16x2_raw r = __builtin_amdgcn_cvt_pkrtz(lo, hi);
    return __builtin_bit_cast(f16x2, r);
}

// Raw v_exp_f32 (2^x). Guarded: fall back to fast __expf if builtin absent.
#if defined(__has_builtin)
#if __has_builtin(__builtin_amdgcn_exp2f)
#define HAVE_EXP2 1
#endif
#endif
__device__ __forceinline__ float fast_exp2(float x)
{
#ifdef HAVE_EXP2
    return __builtin_amdgcn_exp2f(x);
#else
    return __expf(x * 0.6931471805599453f);
#endif
}

// ---------------------------------------------------------------------------
// global -> LDS direct staging (16 B per lane). LDS dest is wave-uniform
// base + lane*16 (HW behavior); fallback reg-stages to the same address.
// ---------------------------------------------------------------------------
#if defined(__has_builtin)
#if __has_builtin(__builtin_amdgcn_global_load_lds)
#define HAVE_GLOAD_LDS 1
#endif
#endif

__device__ __forceinline__ void stage16(const void* g, void* ldsWaveBase, int lane)
{
#ifdef HAVE_GLOAD_LDS
    __builtin_amdgcn_global_load_lds(
        (const __attribute__((address_space(1))) void*)g,
        (__attribute__((address_space(3))) void*)ldsWaveBase, 16, 0, 0);
    (void)lane;
#else
    *(f16x8*)((char*)ldsWaveBase + lane * 16) = *(const f16x8*)g;
#endif
}

// ---------------------------------------------------------------------------
// Fused prep: grid (32,32,5), 256 threads.
//  z=0..3 : transpose+cast W (z<3 -> Wt + z*WE, z=3 -> Wto)
//  z=4    : cast x -> xh (2 f16x8 chunks per thread)
// ---------------------------------------------------------------------------
__global__ __launch_bounds__(256) void prep_all(
    const float* __restrict__ x,
    const float* __restrict__ Wq, const float* __restrict__ Wk,
    const float* __restrict__ Wv, const float* __restrict__ Wo,
    _Float16* __restrict__ xh, _Float16* __restrict__ Wt,
    _Float16* __restrict__ Wto)
{
    const int z = blockIdx.z;
    if (z == 4) {
        int base = ((blockIdx.y * 32 + blockIdx.x) * 256 + threadIdx.x) * 2;
        #pragma unroll
        for (int t = 0; t < 2; ++t) {
            int i = base + t;
            float4 a = ((const float4*)x)[i * 2];
            float4 b = ((const float4*)x)[i * 2 + 1];
            f16x8 o;
            o[0] = (_Float16)a.x; o[1] = (_Float16)a.y;
            o[2] = (_Float16)a.z; o[3] = (_Float16)a.w;
            o[4] = (_Float16)b.x; o[5] = (_Float16)b.y;
            o[6] = (_Float16)b.z; o[7] = (_Float16)b.w;
            ((f16x8*)xh)[i] = o;
        }
        return;
    }
    const float* W = z == 0 ? Wq : (z == 1 ? Wk : (z == 2 ? Wv : Wo));
    _Float16* D = (z == 3) ? Wto : (Wt + (size_t)z * EMB * EMB);
    __shared__ float tile[32][33];
    const int tx = threadIdx.x & 31, ty = threadIdx.x >> 5; // (32, 8)
    const int n0 = blockIdx.x * 32, k0 = blockIdx.y * 32;
    #pragma unroll
    for (int j = 0; j < 4; ++j)
        tile[ty + j * 8][tx] = W[(size_t)(k0 + ty + j * 8) * EMB + n0 + tx];
    __syncthreads();
    #pragma unroll
    for (int j = 0; j < 4; ++j)
        D[(size_t)(n0 + ty + j * 8) * EMB + k0 + tx] =
            (_Float16)tile[tx][ty + j * 8];
}

// ---------------------------------------------------------------------------
// fp16 MFMA GEMM: C[M,N] = A[M,K=1024] @ Bt[N,K]^T.
// 128x128 tile, BK=32, 4 waves (2x2), wave tile 64x64 = 4x4 16x16 frags.
// MODE 0: N=3072 fused QKV -> Q,K as fp16 [B,H,T,D]; V written TRANSPOSED
//         as V^T [B,H,D,T] (4 consecutive t per lane = one 8B store).
// MODE 1: N=1024 -> writes fp32 out + bias.
// ---------------------------------------------------------------------------
template <int MODE>
__global__ __launch_bounds__(256) void gemm_mfma(
    const _Float16* __restrict__ A, const _Float16* __restrict__ Bt,
    _Float16* __restrict__ Qh, _Float16* __restrict__ Kh,
    _Float16* __restrict__ VhT,
    float* __restrict__ outf, const float* __restrict__ bias)
{
    __shared__ __align__(16) _Float16 As[128 * 32]; // 8 KB, row-major [m][k]
    __shared__ __align__(16) _Float16 Bs[128 * 32]; // 8 KB, row-major [n][k]

    const int tid = threadIdx.x;
    const int w = tid >> 6, lane = tid & 63;
    const int l15 = lane & 15, g4 = lane >> 4;
    const int wm = w >> 1, wn = w & 1;
    const int row0 = blockIdx.y * 128, col0 = blockIdx.x * 128;

    f32x4 acc[4][4];
    #pragma unroll
    for (int mt = 0; mt < 4; ++mt)
        #pragma unroll
        for (int nt = 0; nt < 4; ++nt)
            acc[mt][nt] = (f32x4){0.f, 0.f, 0.f, 0.f};

    for (int k0 = 0; k0 < EMB; k0 += 32) {
        __syncthreads(); // previous compute done; safe to overwrite tiles
        #pragma unroll
        for (int i = 0; i < 2; ++i) {
            int c = (i << 8) + tid;       // 16B chunk id, 0..511
            int row = c >> 2, u = c & 3;  // row 0..127, 16B-unit in k
            stage16(&A[(size_t)(row0 + row) * EMB + k0 + (u << 3)],
                    (char*)As + (i << 12) + (w << 10), lane);
            stage16(&Bt[(size_t)(col0 + row) * EMB + k0 + (u << 3)],
                    (char*)Bs + (i << 12) + (w << 10), lane);
        }
        __syncthreads(); // staging visible (compiler drains vmcnt pre-barrier)

        f16x8 af[4], bf[4];
        #pragma unroll
        for (int mt = 0; mt < 4; ++mt)
            af[mt] = *(const f16x8*)((const char*)As +
                     ((wm << 6) + (mt << 4) + l15) * 64 + (g4 << 4));
        #pragma unroll
        for (int nt = 0; nt < 4; ++nt)
            bf[nt] = *(const f16x8*)((const char*)Bs +
                     ((wn << 6) + (nt << 4) + l15) * 64 + (g4 << 4));
        #pragma unroll
        for (int mt = 0; mt < 4; ++mt)
            #pragma unroll
            for (int nt = 0; nt < 4; ++nt)
                acc[mt][nt] = __builtin_amdgcn_mfma_f32_16x16x32_f16(
                    af[mt], bf[nt], acc[mt][nt], 0, 0, 0);
    }

    // Epilogue. C/D layout: col = lane&15, row = 4*(lane>>4) + reg.
    #pragma unroll
    for (int mt = 0; mt < 4; ++mt) {
        int m = row0 + (wm << 6) + (mt << 4) + (g4 << 2);
        #pragma unroll
        for (int nt = 0; nt < 4; ++nt) {
            int gcol = col0 + (wn << 6) + (nt << 4) + l15;
            if (MODE == 0) {
                int proj = gcol >> 10, pc = gcol & 1023;
                int h = pc >> 6, d = pc & 63;
                int b = m >> 11, t = m & 2047;
                int bh = b * NUM_HEADS + h;
                if (proj == 2) {
                    // V^T [bh][d][t..t+3]: one 8B contiguous store
                    f16x4 v4;
                    v4[0] = (_Float16)acc[mt][nt][0];
                    v4[1] = (_Float16)acc[mt][nt][1];
                    v4[2] = (_Float16)acc[mt][nt][2];
                    v4[3] = (_Float16)acc[mt][nt][3];
                    *(f16x4*)&VhT[((size_t)bh * HEAD_D + d) * SEQ + t] = v4;
                } else {
                    _Float16* dst = proj == 0 ? Qh : Kh;
                    float alpha = proj == 0 ? QALPHA : 1.0f;
                    #pragma unroll
                    for (int r = 0; r < 4; ++r)
                        dst[((size_t)bh * SEQ + t + r) * HEAD_D + d] =
                            (_Float16)(acc[mt][nt][r] * alpha);
                }
            } else {
                float bz = bias[gcol];
                #pragma unroll
                for (int r = 0; r < 4; ++r)
                    outf[(size_t)(m + r) * EMB + gcol] = acc[mt][nt][r] + bz;
            }
        }
    }
}

// ---------------------------------------------------------------------------
// Stage one 64-kv K tile + V^T tile into LDS via global_load_lds with
// pre-swizzled global source (LDS dest linear; chunk (row,u) holds global
// (row, u^(row&7)) -> read formulas identical to the verified K-frag path).
// ---------------------------------------------------------------------------
__device__ __forceinline__ void stage_kv_tile(
    const _Float16* __restrict__ KhB, const _Float16* __restrict__ VtB,
    int kv0, char* __restrict__ KsBuf, char* __restrict__ VtBuf,
    int w, int lane)
{
    #pragma unroll
    for (int i = 0; i < 2; ++i) {
        int c = (i << 8) + (w << 6) + lane;
        int row = c >> 3, u = c & 7;
        int us = u ^ (row & 7);
        stage16(&KhB[(size_t)(kv0 + row) * HEAD_D + (us << 3)],
                KsBuf + (i << 12) + (w << 10), lane);
        stage16(&VtB[(size_t)row * SEQ + kv0 + (us << 3)],
                VtBuf + (i << 12) + (w << 10), lane);
    }
}

// ---------------------------------------------------------------------------
// One 64q x 64kv attention tile step: S^T = K Q^T (swapped MFMA, lane owns
// one q row), exp2-domain online softmax (raw v_exp_f32) with defer-max,
// packed cvt_pkrtz P->f16, P roundtrip through wave-private LDS, acc += P@V.
// T5: s_setprio(1) around the MFMA clusters.
// ---------------------------------------------------------------------------
__device__ __forceinline__ void attn_tile(
    const char* __restrict__ KsC, const char* __restrict__ VtC,
    char* __restrict__ pwv,
    f16x8 qf0, f16x8 qf1, f32x4 (&acc)[4], float& m, float& l,
    bool diag, int qrel, int l15, int g)
{
    f32x4 st[4];
    __builtin_amdgcn_s_setprio(1);
    #pragma unroll
    for (int nt = 0; nt < 4; ++nt) {
        int kvl = (nt << 4) + l15;
        f16x8 kf0 = *(const f16x8*)&KsC[kvl * 128 + (((g << 4)) ^ ((kvl & 7) << 4))];
        f16x8 kf1 = *(const f16x8*)&KsC[kvl * 128 + ((64 + (g << 4)) ^ ((kvl & 7) << 4))];
        f32x4 z = (f32x4){0.f, 0.f, 0.f, 0.f};
        z = __builtin_amdgcn_mfma_f32_16x16x32_f16(kf0, qf0, z, 0, 0, 0);
        z = __builtin_amdgcn_mfma_f32_16x16x32_f16(kf1, qf1, z, 0, 0, 0);
        st[nt] = z;
    }
    __builtin_amdgcn_s_setprio(0);
    if (diag) {
        #pragma unroll
        for (int nt = 0; nt < 4; ++nt)
            #pragma unroll
            for (int r = 0; r < 4; ++r)
                if ((nt << 4) + (g << 2) + r > qrel) st[nt][r] = -1e30f;
    }

    float mx;
    {
        float a0 = fmaxf(fmaxf(st[0][0], st[0][1]), fmaxf(st[0][2], st[0][3]));
        float a1 = fmaxf(fmaxf(st[1][0], st[1][1]), fmaxf(st[1][2], st[1][3]));
        float a2 = fmaxf(fmaxf(st[2][0], st[2][1]), fmaxf(st[2][2], st[2][3]));
        float a3 = fmaxf(fmaxf(st[3][0], st[3][1]), fmaxf(st[3][2], st[3][3]));
        mx = fmaxf(fmaxf(a0, a1), fmaxf(a2, a3));
    }
    mx = fmaxf(mx, __shfl_xor(mx, 16));
    mx = fmaxf(mx, __shfl_xor(mx, 32));

    // defer-max: only rescale when the running max lags by > 8 (log2 units)
    if (!__all(mx - m <= 8.0f)) {
        float nm = fmaxf(m, mx);
        float sc = fast_exp2(m - nm);
        m = nm;
        l *= sc;
        #pragma unroll
        for (int r = 0; r < 4; ++r) {
            float scr = __shfl(sc, (g << 2) + r); // q row 4g+r's factor
            acc[0][r] *= scr; acc[1][r] *= scr;
            acc[2][r] *= scr; acc[3][r] *= scr;
        }
    }

    float ps = 0.f;
    #pragma unroll
    for (int nt = 0; nt < 4; ++nt)
        #pragma unroll
        for (int r = 0; r < 4; ++r) {
            float p = fast_exp2(st[nt][r] - m);
            st[nt][r] = p;
            ps += p;
        }
    ps += __shfl_xor(ps, 16);
    ps += __shfl_xor(ps, 32);
    l += ps;

    // P -> wave-private LDS as P[q][kv] (8x packed b32 writes)
    #pragma unroll
    for (int nt = 0; nt < 4; ++nt)
        #pragma unroll
        for (int rr = 0; rr < 2; ++rr) {
            int kvb = (nt << 4) + (g << 2) + (rr << 1);
            f16x2 pv = cvt_pk_f16(st[nt][rr * 2], st[nt][rr * 2 + 1]);
            *(f16x2*)&pwv[l15 * 128 + ((kvb << 1) ^ ((l15 & 7) << 4))] = pv;
        }
    f16x8 pa0 = *(const f16x8*)&pwv[l15 * 128 + (((g << 4)) ^ ((l15 & 7) << 4))];
    f16x8 pa1 = *(const f16x8*)&pwv[l15 * 128 + ((64 + (g << 4)) ^ ((l15 & 7) << 4))];

    __builtin_amdgcn_s_setprio(1);
    #pragma unroll
    for (int dn = 0; dn < 4; ++dn) {
        int d = (dn << 4) + l15;
        f16x8 vf0 = *(const f16x8*)&VtC[d * 128 + (((g << 4)) ^ ((d & 7) << 4))];
        f16x8 vf1 = *(const f16x8*)&VtC[d * 128 + ((64 + (g << 4)) ^ ((d & 7) << 4))];
        acc[dn] = __builtin_amdgcn_mfma_f32_16x16x32_f16(pa0, vf0, acc[dn], 0, 0, 0);
        acc[dn] = __builtin_amdgcn_mfma_f32_16x16x32_f16(pa1, vf1, acc[dn], 0, 0, 0);
    }
    __builtin_amdgcn_s_setprio(0);
}

// ---------------------------------------------------------------------------
// Flash attention, causal, fp16 MFMA. Paired q-tiles (qtA, 31-qtA): 33
// tile-computes per block (perfect FLOP balance), K/V^T staged once per pair
// via global_load_lds double-buffer (issue into dead buffer -> compute ->
// barrier drain). Dual independent chains in phase 1 (2x ILP).
// ---------------------------------------------------------------------------
__global__ __launch_bounds__(256) void attn_mfma(
    const _Float16* __restrict__ Qh, const _Float16* __restrict__ Kh,
    const _Float16* __restrict__ VhT, _Float16* __restrict__ O)
{
    __shared__ char lds[48 * 1024];
    // Ks buf b: b*8192 | Vt buf b: 16384 + b*8192 | PwA: 32768 | PwB: 40960

    const int qtA = blockIdx.x;            // 0..15
    const int qtB = (SEQ / 64 - 1) - qtA;  // 31..16
    const int bh = blockIdx.y;
    const int q0A = qtA << 6, q0B = qtB << 6;
    const int tid = threadIdx.x;
    const int w = tid >> 6, lane = tid & 63;
    const int l15 = lane & 15, g = lane >> 4;

    const _Float16* KhB = Kh  + (size_t)bh * SEQ * HEAD_D;
    const _Float16* VtB = VhT + (size_t)bh * HEAD_D * SEQ;
    const size_t headbase = (size_t)bh * SEQ * HEAD_D;

    const int qrowA = q0A + (w << 4) + l15;
    const int qrowB = q0B + (w << 4) + l15;
    f16x8 qfA0 = *(const f16x8*)&Qh[headbase + (size_t)qrowA * HEAD_D + (g << 3)];
    f16x8 qfA1 = *(const f16x8*)&Qh[headbase + (size_t)qrowA * HEAD_D + 32 + (g << 3)];
    f16x8 qfB0 = *(const f16x8*)&Qh[headbase + (size_t)qrowB * HEAD_D + (g << 3)];
    f16x8 qfB1 = *(const f16x8*)&Qh[headbase + (size_t)qrowB * HEAD_D + 32 + (g << 3)];

    f32x4 accA[4], accB[4];
    #pragma unroll
    for (int dn = 0; dn < 4; ++dn) {
        accA[dn] = (f32x4){0.f, 0.f, 0.f, 0.f};
        accB[dn] = (f32x4){0.f, 0.f, 0.f, 0.f};
    }
    float mA = -1e30f, lA = 0.f, mB = -1e30f, lB = 0.f;

    // ---- prologue: stage tile 0 into buffer 0 ----
    stage_kv_tile(KhB, VtB, 0, lds, lds + 16384, w, lane);
    __syncthreads(); // vmcnt drained before barrier release

    char* pwvA = lds + 32768 + (w << 11);
    char* pwvB = lds + 40960 + (w << 11);

    int cur = 0;
    for (int kt = 0; kt <= qtB; ++kt) {
        // issue next tile's glds into the dead buffer (latency hides)
        if (kt < qtB)
            stage_kv_tile(KhB, VtB, (kt + 1) << 6,
                          lds + ((cur ^ 1) << 13),
                          lds + 16384 + ((cur ^ 1) << 13), w, lane);

        const char* KsC = lds + (cur << 13);
        const char* VtC = lds + 16384 + (cur << 13);
        const int qrel = (w << 4) + l15;

        if (kt <= qtA) {
            attn_tile(KsC, VtC, pwvA, qfA0, qfA1, accA, mA, lA,
                      kt == qtA, qrel, l15, g);
            attn_tile(KsC, VtC, pwvB, qfB0, qfB1, accB, mB, lB,
                      false, qrel, l15, g);
        } else {
            attn_tile(KsC, VtC, pwvB, qfB0, qfB1, accB, mB, lB,
                      kt == qtB, qrel, l15, g);
        }

        __syncthreads(); // drains vmcnt: next tile resident before flip
        cur ^= 1;
    }

    // ---- epilogue: normalize, write fp16 O[tok][h*64+d] for both tiles ----
    const int b = bh >> 4, h = bh & 15;
    const float rlA = 1.f / lA, rlB = 1.f / lB;
    #pragma unroll
    for (int r = 0; r < 4; ++r) {
        float invA = __shfl(rlA, (g << 2) + r);
        float invB = __shfl(rlB, (g << 2) + r);
        int tokA = (b << 11) + q0A + (w << 4) + (g << 2) + r;
        int tokB = (b << 11) + q0B + (w << 4) + (g << 2) + r;
        #pragma unroll
        for (int dn = 0; dn < 4; ++dn) {
            O[(size_t)tokA * EMB + (h << 6) + (dn << 4) + l15] =
                (_Float16)(accA[dn][r] * invA);
            O[(size_t)tokB * EMB + (h << 6) + (dn << 4) + l15] =
                (_Float16)(accB[dn][r] * invB);
        }
    }
}

// ---------------------------------------------------------------------------
extern "C" void kernel_launch(void* const* d_in, const int* in_sizes, int n_in,
                              void* d_out, int out_size, void* d_ws, size_t ws_size,
                              hipStream_t stream)
{
    const float* x  = (const float*)d_in[0];
    const float* Wq = (const float*)d_in[1];
    const float* Wk = (const float*)d_in[2];
    const float* Wv = (const float*)d_in[3];
    const float* Wo = (const float*)d_in[4];
    const float* bo = (const float*)d_in[5];
    float* out = (float*)d_out;

    const size_t ME = (size_t)MTOT * EMB;        // 4M elems
    const size_t WE = (size_t)EMB * EMB;         // 1M elems
    // xh + Wt(3) + Wto + Qh + Kh + VhT + Ow = 5*ME + 4*WE elems fp16
    const size_t need = (5 * ME + 4 * WE) * sizeof(_Float16);
    if (ws_size < need) return;

    _Float16* xh  = (_Float16*)d_ws;
    _Float16* Wt  = xh + ME;
    _Float16* Wto = Wt + 3 * WE;
    _Float16* Qh  = Wto + WE;
    _Float16* Kh  = Qh + ME;
    _Float16* VhT = Kh + ME;   // V stored transposed [B,H,D,T] by the GEMM
    _Float16* Ow  = VhT + ME;

    // fused prep: 4 weight transposes + x cast in one dispatch
    prep_all<<<dim3(EMB / 32, EMB / 32, 5), 256, 0, stream>>>(
        x, Wq, Wk, Wv, Wo, xh, Wt, Wto);

    gemm_mfma<0><<<dim3(3 * EMB / 128, MTOT / 128), 256, 0, stream>>>(
        xh, Wt, Qh, Kh, VhT, nullptr, nullptr);

    attn_mfma<<<dim3(SEQ / 128, BATCH * NUM_HEADS), 256, 0, stream>>>(Qh, Kh, VhT, Ow);

    gemm_mfma<1><<<dim3(EMB / 128, MTOT / 128), 256, 0, stream>>>(
        Ow, Wto, nullptr, nullptr, nullptr, out, bo);
}

// Round 14
// 119.528 us; speedup vs baseline: 12.8723x; 1.0260x over previous
//
#include <hip/hip_runtime.h>

typedef __attribute__((ext_vector_type(8))) _Float16 f16x8;
typedef __attribute__((ext_vector_type(4))) _Float16 f16x4;
typedef __attribute__((ext_vector_type(2))) _Float16 f16x2;
typedef __attribute__((ext_vector_type(2))) __fp16   fp16x2_raw;
typedef __attribute__((ext_vector_type(4))) float    f32x4;

#define NUM_HEADS 16
#define HEAD_D 64
#define EMB 1024
#define SEQ 2048
#define BATCH 2
#define MTOT (BATCH * SEQ) // 4096

// Q scale: 1/sqrt(64) * log2(e)  (softmax runs in exp2 domain)
#define QALPHA 0.18033688011112042f

__device__ __forceinline__ f16x2 cvt_pk_f16(float lo, float hi)
{
    fp16x2_raw r = __builtin_amdgcn_cvt_pkrtz(lo, hi);
    return __builtin_bit_cast(f16x2, r);
}

// Raw v_exp_f32 (2^x). Guarded: fall back to fast __expf if builtin absent.
#if defined(__has_builtin)
#if __has_builtin(__builtin_amdgcn_exp2f)
#define HAVE_EXP2 1
#endif
#endif
__device__ __forceinline__ float fast_exp2(float x)
{
#ifdef HAVE_EXP2
    return __builtin_amdgcn_exp2f(x);
#else
    return __expf(x * 0.6931471805599453f);
#endif
}

// ---------------------------------------------------------------------------
// global -> LDS direct staging (16 B per lane). LDS dest is wave-uniform
// base + lane*16 (HW behavior); fallback reg-stages to the same address.
// ---------------------------------------------------------------------------
#if defined(__has_builtin)
#if __has_builtin(__builtin_amdgcn_global_load_lds)
#define HAVE_GLOAD_LDS 1
#endif
#endif

__device__ __forceinline__ void stage16(const void* g, void* ldsWaveBase, int lane)
{
#ifdef HAVE_GLOAD_LDS
    __builtin_amdgcn_global_load_lds(
        (const __attribute__((address_space(1))) void*)g,
        (__attribute__((address_space(3))) void*)ldsWaveBase, 16, 0, 0);
    (void)lane;
#else
    *(f16x8*)((char*)ldsWaveBase + lane * 16) = *(const f16x8*)g;
#endif
}

// ---------------------------------------------------------------------------
// Fused prep: grid (32,32,5), 256 threads.
//  z=0..3 : transpose+cast W (z<3 -> Wt + z*WE, z=3 -> Wto)
//  z=4    : cast x -> xh (2 f16x8 chunks per thread)
// ---------------------------------------------------------------------------
__global__ __launch_bounds__(256) void prep_all(
    const float* __restrict__ x,
    const float* __restrict__ Wq, const float* __restrict__ Wk,
    const float* __restrict__ Wv, const float* __restrict__ Wo,
    _Float16* __restrict__ xh, _Float16* __restrict__ Wt,
    _Float16* __restrict__ Wto)
{
    const int z = blockIdx.z;
    if (z == 4) {
        int base = ((blockIdx.y * 32 + blockIdx.x) * 256 + threadIdx.x) * 2;
        #pragma unroll
        for (int t = 0; t < 2; ++t) {
            int i = base + t;
            float4 a = ((const float4*)x)[i * 2];
            float4 b = ((const float4*)x)[i * 2 + 1];
            f16x8 o;
            o[0] = (_Float16)a.x; o[1] = (_Float16)a.y;
            o[2] = (_Float16)a.z; o[3] = (_Float16)a.w;
            o[4] = (_Float16)b.x; o[5] = (_Float16)b.y;
            o[6] = (_Float16)b.z; o[7] = (_Float16)b.w;
            ((f16x8*)xh)[i] = o;
        }
        return;
    }
    const float* W = z == 0 ? Wq : (z == 1 ? Wk : (z == 2 ? Wv : Wo));
    _Float16* D = (z == 3) ? Wto : (Wt + (size_t)z * EMB * EMB);
    __shared__ float tile[32][33];
    const int tx = threadIdx.x & 31, ty = threadIdx.x >> 5; // (32, 8)
    const int n0 = blockIdx.x * 32, k0 = blockIdx.y * 32;
    #pragma unroll
    for (int j = 0; j < 4; ++j)
        tile[ty + j * 8][tx] = W[(size_t)(k0 + ty + j * 8) * EMB + n0 + tx];
    __syncthreads();
    #pragma unroll
    for (int j = 0; j < 4; ++j)
        D[(size_t)(n0 + ty + j * 8) * EMB + k0 + tx] =
            (_Float16)tile[tx][ty + j * 8];
}

// ---------------------------------------------------------------------------
// Fused QKV GEMM: [4096, 3072] = xh @ Wt^T. 128x128 tile, BK=32, 4 waves.
// XCD swizzle: col-major tile order, contiguous x-band per XCD -> each XCD's
// B working set = 3 panels (768 KB, L2-resident).
// Q,K written [B,H,T,D] (Q scaled by QALPHA); V written transposed [B,H,D,T].
// ---------------------------------------------------------------------------
__global__ __launch_bounds__(256) void gemm_qkv(
    const _Float16* __restrict__ A, const _Float16* __restrict__ Bt,
    _Float16* __restrict__ Qh, _Float16* __restrict__ Kh,
    _Float16* __restrict__ VhT)
{
    __shared__ __align__(16) _Float16 As[128 * 32]; // 8 KB
    __shared__ __align__(16) _Float16 Bs[128 * 32]; // 8 KB

    const int tid = threadIdx.x;
    const int w = tid >> 6, lane = tid & 63;
    const int l15 = lane & 15, g4 = lane >> 4;
    const int wm = w >> 1, wn = w & 1;

    // XCD-aware bijective remap (nwg = 768, 768 % 8 == 0)
    const int wg = blockIdx.y * gridDim.x + blockIdx.x;
    const int t  = (wg & 7) * 96 + (wg >> 3);
    const int bx = t >> 5, by = t & 31;     // col-major tile order
    const int row0 = by * 128, col0 = bx * 128;

    f32x4 acc[4][4];
    #pragma unroll
    for (int mt = 0; mt < 4; ++mt)
        #pragma unroll
        for (int nt = 0; nt < 4; ++nt)
            acc[mt][nt] = (f32x4){0.f, 0.f, 0.f, 0.f};

    for (int k0 = 0; k0 < EMB; k0 += 32) {
        __syncthreads();
        #pragma unroll
        for (int i = 0; i < 2; ++i) {
            int c = (i << 8) + tid;
            int row = c >> 2, u = c & 3;
            stage16(&A[(size_t)(row0 + row) * EMB + k0 + (u << 3)],
                    (char*)As + (i << 12) + (w << 10), lane);
            stage16(&Bt[(size_t)(col0 + row) * EMB + k0 + (u << 3)],
                    (char*)Bs + (i << 12) + (w << 10), lane);
        }
        __syncthreads();

        f16x8 af[4], bf[4];
        #pragma unroll
        for (int mt = 0; mt < 4; ++mt)
            af[mt] = *(const f16x8*)((const char*)As +
                     ((wm << 6) + (mt << 4) + l15) * 64 + (g4 << 4));
        #pragma unroll
        for (int nt = 0; nt < 4; ++nt)
            bf[nt] = *(const f16x8*)((const char*)Bs +
                     ((wn << 6) + (nt << 4) + l15) * 64 + (g4 << 4));
        #pragma unroll
        for (int mt = 0; mt < 4; ++mt)
            #pragma unroll
            for (int nt = 0; nt < 4; ++nt)
                acc[mt][nt] = __builtin_amdgcn_mfma_f32_16x16x32_f16(
                    af[mt], bf[nt], acc[mt][nt], 0, 0, 0);
    }

    // Epilogue. C/D: col = lane&15, row = 4*(lane>>4) + reg.
    #pragma unroll
    for (int mt = 0; mt < 4; ++mt) {
        int m = row0 + (wm << 6) + (mt << 4) + (g4 << 2);
        #pragma unroll
        for (int nt = 0; nt < 4; ++nt) {
            int gcol = col0 + (wn << 6) + (nt << 4) + l15;
            int proj = gcol >> 10, pc = gcol & 1023;
            int h = pc >> 6, d = pc & 63;
            int b = m >> 11, tt = m & 2047;
            int bh = b * NUM_HEADS + h;
            if (proj == 2) {
                f16x4 v4;
                v4[0] = (_Float16)acc[mt][nt][0];
                v4[1] = (_Float16)acc[mt][nt][1];
                v4[2] = (_Float16)acc[mt][nt][2];
                v4[3] = (_Float16)acc[mt][nt][3];
                *(f16x4*)&VhT[((size_t)bh * HEAD_D + d) * SEQ + tt] = v4;
            } else {
                _Float16* dst = proj == 0 ? Qh : Kh;
                float alpha = proj == 0 ? QALPHA : 1.0f;
                #pragma unroll
                for (int r = 0; r < 4; ++r)
                    dst[((size_t)bh * SEQ + tt + r) * HEAD_D + d] =
                        (_Float16)(acc[mt][nt][r] * alpha);
            }
        }
    }
}

// ---------------------------------------------------------------------------
// Output projection GEMM: [4096, 1024] fp32 + bias. 128x64 tile (BN=64 ->
// 512 blocks = 2/CU for latency overlap), BK=32, 4 waves (2x2), wave tile
// 64x32. XCD swizzle as above (nwg = 512).
// ---------------------------------------------------------------------------
__global__ __launch_bounds__(256) void gemm_out(
    const _Float16* __restrict__ A, const _Float16* __restrict__ Bt,
    float* __restrict__ outf, const float* __restrict__ bias)
{
    __shared__ __align__(16) _Float16 As[128 * 32]; // 8 KB
    __shared__ __align__(16) _Float16 Bs[64 * 32];  // 4 KB

    const int tid = threadIdx.x;
    const int w = tid >> 6, lane = tid & 63;
    const int l15 = lane & 15, g4 = lane >> 4;
    const int wm = w >> 1, wn = w & 1;

    const int wg = blockIdx.y * gridDim.x + blockIdx.x;
    const int t  = (wg & 7) * 64 + (wg >> 3);
    const int bx = t >> 5, by = t & 31;
    const int row0 = by * 128, col0 = bx * 64;

    f32x4 acc[4][2];
    #pragma unroll
    for (int mt = 0; mt < 4; ++mt)
        #pragma unroll
        for (int nt = 0; nt < 2; ++nt)
            acc[mt][nt] = (f32x4){0.f, 0.f, 0.f, 0.f};

    for (int k0 = 0; k0 < EMB; k0 += 32) {
        __syncthreads();
        #pragma unroll
        for (int i = 0; i < 2; ++i) {
            int c = (i << 8) + tid;
            int row = c >> 2, u = c & 3;
            stage16(&A[(size_t)(row0 + row) * EMB + k0 + (u << 3)],
                    (char*)As + (i << 12) + (w << 10), lane);
        }
        {
            int row = tid >> 2, u = tid & 3; // 256 chunks: 64 rows x 4 units
            stage16(&Bt[(size_t)(col0 + row) * EMB + k0 + (u << 3)],
                    (char*)Bs + (w << 10), lane);
        }
        __syncthreads();

        f16x8 af[4], bf[2];
        #pragma unroll
        for (int mt = 0; mt < 4; ++mt)
            af[mt] = *(const f16x8*)((const char*)As +
                     ((wm << 6) + (mt << 4) + l15) * 64 + (g4 << 4));
        #pragma unroll
        for (int nt = 0; nt < 2; ++nt)
            bf[nt] = *(const f16x8*)((const char*)Bs +
                     ((wn << 5) + (nt << 4) + l15) * 64 + (g4 << 4));
        #pragma unroll
        for (int mt = 0; mt < 4; ++mt)
            #pragma unroll
            for (int nt = 0; nt < 2; ++nt)
                acc[mt][nt] = __builtin_amdgcn_mfma_f32_16x16x32_f16(
                    af[mt], bf[nt], acc[mt][nt], 0, 0, 0);
    }

    #pragma unroll
    for (int mt = 0; mt < 4; ++mt) {
        int m = row0 + (wm << 6) + (mt << 4) + (g4 << 2);
        #pragma unroll
        for (int nt = 0; nt < 2; ++nt) {
            int gcol = col0 + (wn << 5) + (nt << 4) + l15;
            float bz = bias[gcol];
            #pragma unroll
            for (int r = 0; r < 4; ++r)
                outf[(size_t)(m + r) * EMB + gcol] = acc[mt][nt][r] + bz;
        }
    }
}

// ---------------------------------------------------------------------------
// Stage one 64-kv K tile + V^T tile into LDS via global_load_lds with
// pre-swizzled global source (LDS dest linear; chunk (row,u) holds global
// (row, u^(row&7)) -> read formulas identical to the verified K-frag path).
// ---------------------------------------------------------------------------
__device__ __forceinline__ void stage_kv_tile(
    const _Float16* __restrict__ KhB, const _Float16* __restrict__ VtB,
    int kv0, char* __restrict__ KsBuf, char* __restrict__ VtBuf,
    int w, int lane)
{
    #pragma unroll
    for (int i = 0; i < 2; ++i) {
        int c = (i << 8) + (w << 6) + lane;
        int row = c >> 3, u = c & 7;
        int us = u ^ (row & 7);
        stage16(&KhB[(size_t)(kv0 + row) * HEAD_D + (us << 3)],
                KsBuf + (i << 12) + (w << 10), lane);
        stage16(&VtB[(size_t)row * SEQ + kv0 + (us << 3)],
                VtBuf + (i << 12) + (w << 10), lane);
    }
}

// ---------------------------------------------------------------------------
// One 64q x 64kv attention tile step: S^T = K Q^T (swapped MFMA, lane owns
// one q row), exp2-domain online softmax (raw v_exp_f32) with defer-max,
// packed cvt_pkrtz P->f16, P roundtrip through wave-private LDS, acc += P@V.
// (setprio removed: measured null in R13.)
// ---------------------------------------------------------------------------
__device__ __forceinline__ void attn_tile(
    const char* __restrict__ KsC, const char* __restrict__ VtC,
    char* __restrict__ pwv,
    f16x8 qf0, f16x8 qf1, f32x4 (&acc)[4], float& m, float& l,
    bool diag, int qrel, int l15, int g)
{
    f32x4 st[4];
    #pragma unroll
    for (int nt = 0; nt < 4; ++nt) {
        int kvl = (nt << 4) + l15;
        f16x8 kf0 = *(const f16x8*)&KsC[kvl * 128 + (((g << 4)) ^ ((kvl & 7) << 4))];
        f16x8 kf1 = *(const f16x8*)&KsC[kvl * 128 + ((64 + (g << 4)) ^ ((kvl & 7) << 4))];
        f32x4 z = (f32x4){0.f, 0.f, 0.f, 0.f};
        z = __builtin_amdgcn_mfma_f32_16x16x32_f16(kf0, qf0, z, 0, 0, 0);
        z = __builtin_amdgcn_mfma_f32_16x16x32_f16(kf1, qf1, z, 0, 0, 0);
        st[nt] = z;
    }
    if (diag) {
        #pragma unroll
        for (int nt = 0; nt < 4; ++nt)
            #pragma unroll
            for (int r = 0; r < 4; ++r)
                if ((nt << 4) + (g << 2) + r > qrel) st[nt][r] = -1e30f;
    }

    float mx;
    {
        float a0 = fmaxf(fmaxf(st[0][0], st[0][1]), fmaxf(st[0][2], st[0][3]));
        float a1 = fmaxf(fmaxf(st[1][0], st[1][1]), fmaxf(st[1][2], st[1][3]));
        float a2 = fmaxf(fmaxf(st[2][0], st[2][1]), fmaxf(st[2][2], st[2][3]));
        float a3 = fmaxf(fmaxf(st[3][0], st[3][1]), fmaxf(st[3][2], st[3][3]));
        mx = fmaxf(fmaxf(a0, a1), fmaxf(a2, a3));
    }
    mx = fmaxf(mx, __shfl_xor(mx, 16));
    mx = fmaxf(mx, __shfl_xor(mx, 32));

    // defer-max: only rescale when the running max lags by > 8 (log2 units)
    if (!__all(mx - m <= 8.0f)) {
        float nm = fmaxf(m, mx);
        float sc = fast_exp2(m - nm);
        m = nm;
        l *= sc;
        #pragma unroll
        for (int r = 0; r < 4; ++r) {
            float scr = __shfl(sc, (g << 2) + r); // q row 4g+r's factor
            acc[0][r] *= scr; acc[1][r] *= scr;
            acc[2][r] *= scr; acc[3][r] *= scr;
        }
    }

    float ps = 0.f;
    #pragma unroll
    for (int nt = 0; nt < 4; ++nt)
        #pragma unroll
        for (int r = 0; r < 4; ++r) {
            float p = fast_exp2(st[nt][r] - m);
            st[nt][r] = p;
            ps += p;
        }
    ps += __shfl_xor(ps, 16);
    ps += __shfl_xor(ps, 32);
    l += ps;

    // P -> wave-private LDS as P[q][kv] (8x packed b32 writes)
    #pragma unroll
    for (int nt = 0; nt < 4; ++nt)
        #pragma unroll
        for (int rr = 0; rr < 2; ++rr) {
            int kvb = (nt << 4) + (g << 2) + (rr << 1);
            f16x2 pv = cvt_pk_f16(st[nt][rr * 2], st[nt][rr * 2 + 1]);
            *(f16x2*)&pwv[l15 * 128 + ((kvb << 1) ^ ((l15 & 7) << 4))] = pv;
        }
    f16x8 pa0 = *(const f16x8*)&pwv[l15 * 128 + (((g << 4)) ^ ((l15 & 7) << 4))];
    f16x8 pa1 = *(const f16x8*)&pwv[l15 * 128 + ((64 + (g << 4)) ^ ((l15 & 7) << 4))];

    #pragma unroll
    for (int dn = 0; dn < 4; ++dn) {
        int d = (dn << 4) + l15;
        f16x8 vf0 = *(const f16x8*)&VtC[d * 128 + (((g << 4)) ^ ((d & 7) << 4))];
        f16x8 vf1 = *(const f16x8*)&VtC[d * 128 + ((64 + (g << 4)) ^ ((d & 7) << 4))];
        acc[dn] = __builtin_amdgcn_mfma_f32_16x16x32_f16(pa0, vf0, acc[dn], 0, 0, 0);
        acc[dn] = __builtin_amdgcn_mfma_f32_16x16x32_f16(pa1, vf1, acc[dn], 0, 0, 0);
    }
}

// ---------------------------------------------------------------------------
// Flash attention, causal, fp16 MFMA. Paired q-tiles (qtA, 31-qtA): 33
// tile-computes per block (perfect FLOP balance), K/V^T staged once per pair
// via global_load_lds double-buffer (issue into dead buffer -> compute ->
// barrier drain). Dual independent chains in phase 1 (2x ILP).
// ---------------------------------------------------------------------------
__global__ __launch_bounds__(256) void attn_mfma(
    const _Float16* __restrict__ Qh, const _Float16* __restrict__ Kh,
    const _Float16* __restrict__ VhT, _Float16* __restrict__ O)
{
    __shared__ char lds[48 * 1024];
    // Ks buf b: b*8192 | Vt buf b: 16384 + b*8192 | PwA: 32768 | PwB: 40960

    const int qtA = blockIdx.x;            // 0..15
    const int qtB = (SEQ / 64 - 1) - qtA;  // 31..16
    const int bh = blockIdx.y;
    const int q0A = qtA << 6, q0B = qtB << 6;
    const int tid = threadIdx.x;
    const int w = tid >> 6, lane = tid & 63;
    const int l15 = lane & 15, g = lane >> 4;

    const _Float16* KhB = Kh  + (size_t)bh * SEQ * HEAD_D;
    const _Float16* VtB = VhT + (size_t)bh * HEAD_D * SEQ;
    const size_t headbase = (size_t)bh * SEQ * HEAD_D;

    const int qrowA = q0A + (w << 4) + l15;
    const int qrowB = q0B + (w << 4) + l15;
    f16x8 qfA0 = *(const f16x8*)&Qh[headbase + (size_t)qrowA * HEAD_D + (g << 3)];
    f16x8 qfA1 = *(const f16x8*)&Qh[headbase + (size_t)qrowA * HEAD_D + 32 + (g << 3)];
    f16x8 qfB0 = *(const f16x8*)&Qh[headbase + (size_t)qrowB * HEAD_D + (g << 3)];
    f16x8 qfB1 = *(const f16x8*)&Qh[headbase + (size_t)qrowB * HEAD_D + 32 + (g << 3)];

    f32x4 accA[4], accB[4];
    #pragma unroll
    for (int dn = 0; dn < 4; ++dn) {
        accA[dn] = (f32x4){0.f, 0.f, 0.f, 0.f};
        accB[dn] = (f32x4){0.f, 0.f, 0.f, 0.f};
    }
    float mA = -1e30f, lA = 0.f, mB = -1e30f, lB = 0.f;

    // ---- prologue: stage tile 0 into buffer 0 ----
    stage_kv_tile(KhB, VtB, 0, lds, lds + 16384, w, lane);
    __syncthreads(); // vmcnt drained before barrier release

    char* pwvA = lds + 32768 + (w << 11);
    char* pwvB = lds + 40960 + (w << 11);

    int cur = 0;
    for (int kt = 0; kt <= qtB; ++kt) {
        // issue next tile's glds into the dead buffer (latency hides)
        if (kt < qtB)
            stage_kv_tile(KhB, VtB, (kt + 1) << 6,
                          lds + ((cur ^ 1) << 13),
                          lds + 16384 + ((cur ^ 1) << 13), w, lane);

        const char* KsC = lds + (cur << 13);
        const char* VtC = lds + 16384 + (cur << 13);
        const int qrel = (w << 4) + l15;

        if (kt <= qtA) {
            attn_tile(KsC, VtC, pwvA, qfA0, qfA1, accA, mA, lA,
                      kt == qtA, qrel, l15, g);
            attn_tile(KsC, VtC, pwvB, qfB0, qfB1, accB, mB, lB,
                      false, qrel, l15, g);
        } else {
            attn_tile(KsC, VtC, pwvB, qfB0, qfB1, accB, mB, lB,
                      kt == qtB, qrel, l15, g);
        }

        __syncthreads(); // drains vmcnt: next tile resident before flip
        cur ^= 1;
    }

    // ---- epilogue: normalize, write fp16 O[tok][h*64+d] for both tiles ----
    const int b = bh >> 4, h = bh & 15;
    const float rlA = 1.f / lA, rlB = 1.f / lB;
    #pragma unroll
    for (int r = 0; r < 4; ++r) {
        float invA = __shfl(rlA, (g << 2) + r);
        float invB = __shfl(rlB, (g << 2) + r);
        int tokA = (b << 11) + q0A + (w << 4) + (g << 2) + r;
        int tokB = (b << 11) + q0B + (w << 4) + (g << 2) + r;
        #pragma unroll
        for (int dn = 0; dn < 4; ++dn) {
            O[(size_t)tokA * EMB + (h << 6) + (dn << 4) + l15] =
                (_Float16)(accA[dn][r] * invA);
            O[(size_t)tokB * EMB + (h << 6) + (dn << 4) + l15] =
                (_Float16)(accB[dn][r] * invB);
        }
    }
}

// ---------------------------------------------------------------------------
extern "C" void kernel_launch(void* const* d_in, const int* in_sizes, int n_in,
                              void* d_out, int out_size, void* d_ws, size_t ws_size,
                              hipStream_t stream)
{
    const float* x  = (const float*)d_in[0];
    const float* Wq = (const float*)d_in[1];
    const float* Wk = (const float*)d_in[2];
    const float* Wv = (const float*)d_in[3];
    const float* Wo = (const float*)d_in[4];
    const float* bo = (const float*)d_in[5];
    float* out = (float*)d_out;

    const size_t ME = (size_t)MTOT * EMB;        // 4M elems
    const size_t WE = (size_t)EMB * EMB;         // 1M elems
    // xh + Wt(3) + Wto + Qh + Kh + VhT + Ow = 5*ME + 4*WE elems fp16
    const size_t need = (5 * ME + 4 * WE) * sizeof(_Float16);
    if (ws_size < need) return;

    _Float16* xh  = (_Float16*)d_ws;
    _Float16* Wt  = xh + ME;
    _Float16* Wto = Wt + 3 * WE;
    _Float16* Qh  = Wto + WE;
    _Float16* Kh  = Qh + ME;
    _Float16* VhT = Kh + ME;   // V stored transposed [B,H,D,T] by the GEMM
    _Float16* Ow  = VhT + ME;

    // fused prep: 4 weight transposes + x cast in one dispatch
    prep_all<<<dim3(EMB / 32, EMB / 32, 5), 256, 0, stream>>>(
        x, Wq, Wk, Wv, Wo, xh, Wt, Wto);

    gemm_qkv<<<dim3(3 * EMB / 128, MTOT / 128), 256, 0, stream>>>(
        xh, Wt, Qh, Kh, VhT);

    attn_mfma<<<dim3(SEQ / 128, BATCH * NUM_HEADS), 256, 0, stream>>>(Qh, Kh, VhT, Ow);

    gemm_out<<<dim3(EMB / 64, MTOT / 128), 256, 0, stream>>>(
        Ow, Wto, out, bo);
}

// Round 15
// 116.661 us; speedup vs baseline: 13.1886x; 1.0246x over previous
//
#include <hip/hip_runtime.h>

typedef __attribute__((ext_vector_type(8))) _Float16 f16x8;
typedef __attribute__((ext_vector_type(4))) _Float16 f16x4;
typedef __attribute__((ext_vector_type(2))) _Float16 f16x2;
typedef __attribute__((ext_vector_type(2))) __fp16   fp16x2_raw;
typedef __attribute__((ext_vector_type(4))) float    f32x4;

#define NUM_HEADS 16
#define HEAD_D 64
#define EMB 1024
#define SEQ 2048
#define BATCH 2
#define MTOT (BATCH * SEQ) // 4096

// Q scale: 1/sqrt(64) * log2(e)  (softmax runs in exp2 domain)
#define QALPHA 0.18033688011112042f

__device__ __forceinline__ f16x2 cvt_pk_f16(float lo, float hi)
{
    fp16x2_raw r = __builtin_amdgcn_cvt_pkrtz(lo, hi);
    return __builtin_bit_cast(f16x2, r);
}

// Raw v_exp_f32 (2^x). Guarded: fall back to fast __expf if builtin absent.
#if defined(__has_builtin)
#if __has_builtin(__builtin_amdgcn_exp2f)
#define HAVE_EXP2 1
#endif
#endif
__device__ __forceinline__ float fast_exp2(float x)
{
#ifdef HAVE_EXP2
    return __builtin_amdgcn_exp2f(x);
#else
    return __expf(x * 0.6931471805599453f);
#endif
}

// ---------------------------------------------------------------------------
// global -> LDS direct staging (16 B per lane). LDS dest is wave-uniform
// base + lane*16 (HW behavior); fallback reg-stages to the same address.
// ---------------------------------------------------------------------------
#if defined(__has_builtin)
#if __has_builtin(__builtin_amdgcn_global_load_lds)
#define HAVE_GLOAD_LDS 1
#endif
#endif

__device__ __forceinline__ void stage16(const void* g, void* ldsWaveBase, int lane)
{
#ifdef HAVE_GLOAD_LDS
    __builtin_amdgcn_global_load_lds(
        (const __attribute__((address_space(1))) void*)g,
        (__attribute__((address_space(3))) void*)ldsWaveBase, 16, 0, 0);
    (void)lane;
#else
    *(f16x8*)((char*)ldsWaveBase + lane * 16) = *(const f16x8*)g;
#endif
}

// ---------------------------------------------------------------------------
// Fused prep: grid (32,32,5), 256 threads.
//  z=0..3 : transpose+cast W (z<3 -> Wt + z*WE, z=3 -> Wto)
//  z=4    : cast x -> xh (2 f16x8 chunks per thread)
// ---------------------------------------------------------------------------
__global__ __launch_bounds__(256) void prep_all(
    const float* __restrict__ x,
    const float* __restrict__ Wq, const float* __restrict__ Wk,
    const float* __restrict__ Wv, const float* __restrict__ Wo,
    _Float16* __restrict__ xh, _Float16* __restrict__ Wt,
    _Float16* __restrict__ Wto)
{
    const int z = blockIdx.z;
    if (z == 4) {
        int base = ((blockIdx.y * 32 + blockIdx.x) * 256 + threadIdx.x) * 2;
        #pragma unroll
        for (int t = 0; t < 2; ++t) {
            int i = base + t;
            float4 a = ((const float4*)x)[i * 2];
            float4 b = ((const float4*)x)[i * 2 + 1];
            f16x8 o;
            o[0] = (_Float16)a.x; o[1] = (_Float16)a.y;
            o[2] = (_Float16)a.z; o[3] = (_Float16)a.w;
            o[4] = (_Float16)b.x; o[5] = (_Float16)b.y;
            o[6] = (_Float16)b.z; o[7] = (_Float16)b.w;
            ((f16x8*)xh)[i] = o;
        }
        return;
    }
    const float* W = z == 0 ? Wq : (z == 1 ? Wk : (z == 2 ? Wv : Wo));
    _Float16* D = (z == 3) ? Wto : (Wt + (size_t)z * EMB * EMB);
    __shared__ float tile[32][33];
    const int tx = threadIdx.x & 31, ty = threadIdx.x >> 5; // (32, 8)
    const int n0 = blockIdx.x * 32, k0 = blockIdx.y * 32;
    #pragma unroll
    for (int j = 0; j < 4; ++j)
        tile[ty + j * 8][tx] = W[(size_t)(k0 + ty + j * 8) * EMB + n0 + tx];
    __syncthreads();
    #pragma unroll
    for (int j = 0; j < 4; ++j)
        D[(size_t)(n0 + ty + j * 8) * EMB + k0 + tx] =
            (_Float16)tile[tx][ty + j * 8];
}

// ---------------------------------------------------------------------------
// Fused QKV GEMM: [4096, 3072] = xh @ Wt^T. 128x128 tile, BK=32, 4 waves.
// XCD swizzle: col-major tile order, contiguous x-band per XCD.
// Q,K written [B,H,T,D] (Q scaled by QALPHA); V written transposed [B,H,D,T].
// ---------------------------------------------------------------------------
__global__ __launch_bounds__(256) void gemm_qkv(
    const _Float16* __restrict__ A, const _Float16* __restrict__ Bt,
    _Float16* __restrict__ Qh, _Float16* __restrict__ Kh,
    _Float16* __restrict__ VhT)
{
    __shared__ __align__(16) _Float16 As[128 * 32]; // 8 KB
    __shared__ __align__(16) _Float16 Bs[128 * 32]; // 8 KB

    const int tid = threadIdx.x;
    const int w = tid >> 6, lane = tid & 63;
    const int l15 = lane & 15, g4 = lane >> 4;
    const int wm = w >> 1, wn = w & 1;

    // XCD-aware bijective remap (nwg = 768, 768 % 8 == 0)
    const int wg = blockIdx.y * gridDim.x + blockIdx.x;
    const int t  = (wg & 7) * 96 + (wg >> 3);
    const int bx = t >> 5, by = t & 31;     // col-major tile order
    const int row0 = by * 128, col0 = bx * 128;

    f32x4 acc[4][4];
    #pragma unroll
    for (int mt = 0; mt < 4; ++mt)
        #pragma unroll
        for (int nt = 0; nt < 4; ++nt)
            acc[mt][nt] = (f32x4){0.f, 0.f, 0.f, 0.f};

    for (int k0 = 0; k0 < EMB; k0 += 32) {
        __syncthreads();
        #pragma unroll
        for (int i = 0; i < 2; ++i) {
            int c = (i << 8) + tid;
            int row = c >> 2, u = c & 3;
            stage16(&A[(size_t)(row0 + row) * EMB + k0 + (u << 3)],
                    (char*)As + (i << 12) + (w << 10), lane);
            stage16(&Bt[(size_t)(col0 + row) * EMB + k0 + (u << 3)],
                    (char*)Bs + (i << 12) + (w << 10), lane);
        }
        __syncthreads();

        f16x8 af[4], bf[4];
        #pragma unroll
        for (int mt = 0; mt < 4; ++mt)
            af[mt] = *(const f16x8*)((const char*)As +
                     ((wm << 6) + (mt << 4) + l15) * 64 + (g4 << 4));
        #pragma unroll
        for (int nt = 0; nt < 4; ++nt)
            bf[nt] = *(const f16x8*)((const char*)Bs +
                     ((wn << 6) + (nt << 4) + l15) * 64 + (g4 << 4));
        #pragma unroll
        for (int mt = 0; mt < 4; ++mt)
            #pragma unroll
            for (int nt = 0; nt < 4; ++nt)
                acc[mt][nt] = __builtin_amdgcn_mfma_f32_16x16x32_f16(
                    af[mt], bf[nt], acc[mt][nt], 0, 0, 0);
    }

    // Epilogue. C/D: col = lane&15, row = 4*(lane>>4) + reg.
    #pragma unroll
    for (int mt = 0; mt < 4; ++mt) {
        int m = row0 + (wm << 6) + (mt << 4) + (g4 << 2);
        #pragma unroll
        for (int nt = 0; nt < 4; ++nt) {
            int gcol = col0 + (wn << 6) + (nt << 4) + l15;
            int proj = gcol >> 10, pc = gcol & 1023;
            int h = pc >> 6, d = pc & 63;
            int b = m >> 11, tt = m & 2047;
            int bh = b * NUM_HEADS + h;
            if (proj == 2) {
                f16x4 v4;
                v4[0] = (_Float16)acc[mt][nt][0];
                v4[1] = (_Float16)acc[mt][nt][1];
                v4[2] = (_Float16)acc[mt][nt][2];
                v4[3] = (_Float16)acc[mt][nt][3];
                *(f16x4*)&VhT[((size_t)bh * HEAD_D + d) * SEQ + tt] = v4;
            } else {
                _Float16* dst = proj == 0 ? Qh : Kh;
                float alpha = proj == 0 ? QALPHA : 1.0f;
                #pragma unroll
                for (int r = 0; r < 4; ++r)
                    dst[((size_t)bh * SEQ + tt + r) * HEAD_D + d] =
                        (_Float16)(acc[mt][nt][r] * alpha);
            }
        }
    }
}

// ---------------------------------------------------------------------------
// Output projection GEMM: [4096, 1024] fp32 + bias. 128x64 tile (512 blocks
// = 2/CU), BK=32, 4 waves, wave tile 64x32. XCD swizzle (nwg = 512).
// ---------------------------------------------------------------------------
__global__ __launch_bounds__(256) void gemm_out(
    const _Float16* __restrict__ A, const _Float16* __restrict__ Bt,
    float* __restrict__ outf, const float* __restrict__ bias)
{
    __shared__ __align__(16) _Float16 As[128 * 32]; // 8 KB
    __shared__ __align__(16) _Float16 Bs[64 * 32];  // 4 KB

    const int tid = threadIdx.x;
    const int w = tid >> 6, lane = tid & 63;
    const int l15 = lane & 15, g4 = lane >> 4;
    const int wm = w >> 1, wn = w & 1;

    const int wg = blockIdx.y * gridDim.x + blockIdx.x;
    const int t  = (wg & 7) * 64 + (wg >> 3);
    const int bx = t >> 5, by = t & 31;
    const int row0 = by * 128, col0 = bx * 64;

    f32x4 acc[4][2];
    #pragma unroll
    for (int mt = 0; mt < 4; ++mt)
        #pragma unroll
        for (int nt = 0; nt < 2; ++nt)
            acc[mt][nt] = (f32x4){0.f, 0.f, 0.f, 0.f};

    for (int k0 = 0; k0 < EMB; k0 += 32) {
        __syncthreads();
        #pragma unroll
        for (int i = 0; i < 2; ++i) {
            int c = (i << 8) + tid;
            int row = c >> 2, u = c & 3;
            stage16(&A[(size_t)(row0 + row) * EMB + k0 + (u << 3)],
                    (char*)As + (i << 12) + (w << 10), lane);
        }
        {
            int row = tid >> 2, u = tid & 3; // 256 chunks: 64 rows x 4 units
            stage16(&Bt[(size_t)(col0 + row) * EMB + k0 + (u << 3)],
                    (char*)Bs + (w << 10), lane);
        }
        __syncthreads();

        f16x8 af[4], bf[2];
        #pragma unroll
        for (int mt = 0; mt < 4; ++mt)
            af[mt] = *(const f16x8*)((const char*)As +
                     ((wm << 6) + (mt << 4) + l15) * 64 + (g4 << 4));
        #pragma unroll
        for (int nt = 0; nt < 2; ++nt)
            bf[nt] = *(const f16x8*)((const char*)Bs +
                     ((wn << 5) + (nt << 4) + l15) * 64 + (g4 << 4));
        #pragma unroll
        for (int mt = 0; mt < 4; ++mt)
            #pragma unroll
            for (int nt = 0; nt < 2; ++nt)
                acc[mt][nt] = __builtin_amdgcn_mfma_f32_16x16x32_f16(
                    af[mt], bf[nt], acc[mt][nt], 0, 0, 0);
    }

    #pragma unroll
    for (int mt = 0; mt < 4; ++mt) {
        int m = row0 + (wm << 6) + (mt << 4) + (g4 << 2);
        #pragma unroll
        for (int nt = 0; nt < 2; ++nt) {
            int gcol = col0 + (wn << 5) + (nt << 4) + l15;
            float bz = bias[gcol];
            #pragma unroll
            for (int r = 0; r < 4; ++r)
                outf[(size_t)(m + r) * EMB + gcol] = acc[mt][nt][r] + bz;
        }
    }
}

// ---------------------------------------------------------------------------
// Stage one 64-kv K tile + V^T tile into LDS via global_load_lds with
// pre-swizzled global source (LDS dest linear; chunk (row,u) holds global
// (row, u^(row&7)) -> read formulas identical to the verified K-frag path).
// ---------------------------------------------------------------------------
__device__ __forceinline__ void stage_kv_tile(
    const _Float16* __restrict__ KhB, const _Float16* __restrict__ VtB,
    int kv0, char* __restrict__ KsBuf, char* __restrict__ VtBuf,
    int w, int lane)
{
    #pragma unroll
    for (int i = 0; i < 2; ++i) {
        int c = (i << 8) + (w << 6) + lane;
        int row = c >> 3, u = c & 7;
        int us = u ^ (row & 7);
        stage16(&KhB[(size_t)(kv0 + row) * HEAD_D + (us << 3)],
                KsBuf + (i << 12) + (w << 10), lane);
        stage16(&VtB[(size_t)row * SEQ + kv0 + (us << 3)],
                VtBuf + (i << 12) + (w << 10), lane);
    }
}

// ---------------------------------------------------------------------------
// One 64q x 64kv attention tile step: S^T = K Q^T (swapped MFMA, lane owns
// one q row), exp2-domain online softmax. R15 shuffle-free steady state:
//  - defer-max check via __all() ballot on PER-LANE partial max (free
//    cross-lane reduction); true row max (2 shuffles) only inside the rare
//    rescale branch (wave-uniform).
//  - l kept as per-lane partial (each g-lane sums its own 16 P values);
//    cross-lane sum deferred to the kernel epilogue.
// ---------------------------------------------------------------------------
__device__ __forceinline__ void attn_tile(
    const char* __restrict__ KsC, const char* __restrict__ VtC,
    char* __restrict__ pwv,
    f16x8 qf0, f16x8 qf1, f32x4 (&acc)[4], float& m, float& l,
    bool diag, int qrel, int l15, int g)
{
    f32x4 st[4];
    #pragma unroll
    for (int nt = 0; nt < 4; ++nt) {
        int kvl = (nt << 4) + l15;
        f16x8 kf0 = *(const f16x8*)&KsC[kvl * 128 + (((g << 4)) ^ ((kvl & 7) << 4))];
        f16x8 kf1 = *(const f16x8*)&KsC[kvl * 128 + ((64 + (g << 4)) ^ ((kvl & 7) << 4))];
        f32x4 z = (f32x4){0.f, 0.f, 0.f, 0.f};
        z = __builtin_amdgcn_mfma_f32_16x16x32_f16(kf0, qf0, z, 0, 0, 0);
        z = __builtin_amdgcn_mfma_f32_16x16x32_f16(kf1, qf1, z, 0, 0, 0);
        st[nt] = z;
    }
    if (diag) {
        #pragma unroll
        for (int nt = 0; nt < 4; ++nt)
            #pragma unroll
            for (int r = 0; r < 4; ++r)
                if ((nt << 4) + (g << 2) + r > qrel) st[nt][r] = -1e30f;
    }

    // per-lane partial max over this lane's 16 S values (no shuffles)
    float mx;
    {
        float a0 = fmaxf(fmaxf(st[0][0], st[0][1]), fmaxf(st[0][2], st[0][3]));
        float a1 = fmaxf(fmaxf(st[1][0], st[1][1]), fmaxf(st[1][2], st[1][3]));
        float a2 = fmaxf(fmaxf(st[2][0], st[2][1]), fmaxf(st[2][2], st[2][3]));
        float a3 = fmaxf(fmaxf(st[3][0], st[3][1]), fmaxf(st[3][2], st[3][3]));
        mx = fmaxf(fmaxf(a0, a1), fmaxf(a2, a3));
    }

    // defer-max: ballot IS the cross-lane reduction. Rescale (rare) computes
    // the true row max; m stays row-uniform because it is only ever updated
    // from the shuffled row max.
    if (!__all(mx - m <= 8.0f)) {
        float mxr = fmaxf(mx, __shfl_xor(mx, 16));
        mxr = fmaxf(mxr, __shfl_xor(mxr, 32));
        float nm = fmaxf(m, mxr);
        float sc = fast_exp2(m - nm);   // row-uniform
        m = nm;
        l *= sc;                        // per-lane partial scales uniformly
        #pragma unroll
        for (int r = 0; r < 4; ++r) {
            float scr = __shfl(sc, (g << 2) + r); // q row 4g+r's factor
            acc[0][r] *= scr; acc[1][r] *= scr;
            acc[2][r] *= scr; acc[3][r] *= scr;
        }
    }

    // P = 2^(S-m); l accumulates per-lane partial (summed at epilogue)
    float ps = 0.f;
    #pragma unroll
    for (int nt = 0; nt < 4; ++nt)
        #pragma unroll
        for (int r = 0; r < 4; ++r) {
            float p = fast_exp2(st[nt][r] - m);
            st[nt][r] = p;
            ps += p;
        }
    l += ps;

    // P -> wave-private LDS as P[q][kv] (8x packed b32 writes)
    #pragma unroll
    for (int nt = 0; nt < 4; ++nt)
        #pragma unroll
        for (int rr = 0; rr < 2; ++rr) {
            int kvb = (nt << 4) + (g << 2) + (rr << 1);
            f16x2 pv = cvt_pk_f16(st[nt][rr * 2], st[nt][rr * 2 + 1]);
            *(f16x2*)&pwv[l15 * 128 + ((kvb << 1) ^ ((l15 & 7) << 4))] = pv;
        }
    f16x8 pa0 = *(const f16x8*)&pwv[l15 * 128 + (((g << 4)) ^ ((l15 & 7) << 4))];
    f16x8 pa1 = *(const f16x8*)&pwv[l15 * 128 + ((64 + (g << 4)) ^ ((l15 & 7) << 4))];

    #pragma unroll
    for (int dn = 0; dn < 4; ++dn) {
        int d = (dn << 4) + l15;
        f16x8 vf0 = *(const f16x8*)&VtC[d * 128 + (((g << 4)) ^ ((d & 7) << 4))];
        f16x8 vf1 = *(const f16x8*)&VtC[d * 128 + ((64 + (g << 4)) ^ ((d & 7) << 4))];
        acc[dn] = __builtin_amdgcn_mfma_f32_16x16x32_f16(pa0, vf0, acc[dn], 0, 0, 0);
        acc[dn] = __builtin_amdgcn_mfma_f32_16x16x32_f16(pa1, vf1, acc[dn], 0, 0, 0);
    }
}

// ---------------------------------------------------------------------------
// Flash attention, causal, fp16 MFMA. Paired q-tiles (qtA, 31-qtA): 33
// tile-computes per block (perfect FLOP balance), K/V^T staged once per pair
// via global_load_lds double-buffer. Dual independent chains in phase 1.
// ---------------------------------------------------------------------------
__global__ __launch_bounds__(256) void attn_mfma(
    const _Float16* __restrict__ Qh, const _Float16* __restrict__ Kh,
    const _Float16* __restrict__ VhT, _Float16* __restrict__ O)
{
    __shared__ char lds[48 * 1024];
    // Ks buf b: b*8192 | Vt buf b: 16384 + b*8192 | PwA: 32768 | PwB: 40960

    const int qtA = blockIdx.x;            // 0..15
    const int qtB = (SEQ / 64 - 1) - qtA;  // 31..16
    const int bh = blockIdx.y;
    const int q0A = qtA << 6, q0B = qtB << 6;
    const int tid = threadIdx.x;
    const int w = tid >> 6, lane = tid & 63;
    const int l15 = lane & 15, g = lane >> 4;

    const _Float16* KhB = Kh  + (size_t)bh * SEQ * HEAD_D;
    const _Float16* VtB = VhT + (size_t)bh * HEAD_D * SEQ;
    const size_t headbase = (size_t)bh * SEQ * HEAD_D;

    const int qrowA = q0A + (w << 4) + l15;
    const int qrowB = q0B + (w << 4) + l15;
    f16x8 qfA0 = *(const f16x8*)&Qh[headbase + (size_t)qrowA * HEAD_D + (g << 3)];
    f16x8 qfA1 = *(const f16x8*)&Qh[headbase + (size_t)qrowA * HEAD_D + 32 + (g << 3)];
    f16x8 qfB0 = *(const f16x8*)&Qh[headbase + (size_t)qrowB * HEAD_D + (g << 3)];
    f16x8 qfB1 = *(const f16x8*)&Qh[headbase + (size_t)qrowB * HEAD_D + 32 + (g << 3)];

    f32x4 accA[4], accB[4];
    #pragma unroll
    for (int dn = 0; dn < 4; ++dn) {
        accA[dn] = (f32x4){0.f, 0.f, 0.f, 0.f};
        accB[dn] = (f32x4){0.f, 0.f, 0.f, 0.f};
    }
    float mA = -1e30f, lA = 0.f, mB = -1e30f, lB = 0.f;

    // ---- prologue: stage tile 0 into buffer 0 ----
    stage_kv_tile(KhB, VtB, 0, lds, lds + 16384, w, lane);
    __syncthreads(); // vmcnt drained before barrier release

    char* pwvA = lds + 32768 + (w << 11);
    char* pwvB = lds + 40960 + (w << 11);

    int cur = 0;
    for (int kt = 0; kt <= qtB; ++kt) {
        // issue next tile's glds into the dead buffer (latency hides)
        if (kt < qtB)
            stage_kv_tile(KhB, VtB, (kt + 1) << 6,
                          lds + ((cur ^ 1) << 13),
                          lds + 16384 + ((cur ^ 1) << 13), w, lane);

        const char* KsC = lds + (cur << 13);
        const char* VtC = lds + 16384 + (cur << 13);
        const int qrel = (w << 4) + l15;

        if (kt <= qtA) {
            attn_tile(KsC, VtC, pwvA, qfA0, qfA1, accA, mA, lA,
                      kt == qtA, qrel, l15, g);
            attn_tile(KsC, VtC, pwvB, qfB0, qfB1, accB, mB, lB,
                      false, qrel, l15, g);
        } else {
            attn_tile(KsC, VtC, pwvB, qfB0, qfB1, accB, mB, lB,
                      kt == qtB, qrel, l15, g);
        }

        __syncthreads(); // drains vmcnt: next tile resident before flip
        cur ^= 1;
    }

    // ---- epilogue: cross-lane l reduction (deferred), normalize, store ----
    lA += __shfl_xor(lA, 16); lA += __shfl_xor(lA, 32);
    lB += __shfl_xor(lB, 16); lB += __shfl_xor(lB, 32);
    const int b = bh >> 4, h = bh & 15;
    const float rlA = 1.f / lA, rlB = 1.f / lB;
    #pragma unroll
    for (int r = 0; r < 4; ++r) {
        float invA = __shfl(rlA, (g << 2) + r);
        float invB = __shfl(rlB, (g << 2) + r);
        int tokA = (b << 11) + q0A + (w << 4) + (g << 2) + r;
        int tokB = (b << 11) + q0B + (w << 4) + (g << 2) + r;
        #pragma unroll
        for (int dn = 0; dn < 4; ++dn) {
            O[(size_t)tokA * EMB + (h << 6) + (dn << 4) + l15] =
                (_Float16)(accA[dn][r] * invA);
            O[(size_t)tokB * EMB + (h << 6) + (dn << 4) + l15] =
                (_Float16)(accB[dn][r] * invB);
        }
    }
}

// ---------------------------------------------------------------------------
extern "C" void kernel_launch(void* const* d_in, const int* in_sizes, int n_in,
                              void* d_out, int out_size, void* d_ws, size_t ws_size,
                              hipStream_t stream)
{
    const float* x  = (const float*)d_in[0];
    const float* Wq = (const float*)d_in[1];
    const float* Wk = (const float*)d_in[2];
    const float* Wv = (const float*)d_in[3];
    const float* Wo = (const float*)d_in[4];
    const float* bo = (const float*)d_in[5];
    float* out = (float*)d_out;

    const size_t ME = (size_t)MTOT * EMB;        // 4M elems
    const size_t WE = (size_t)EMB * EMB;         // 1M elems
    // xh + Wt(3) + Wto + Qh + Kh + VhT + Ow = 5*ME + 4*WE elems fp16
    const size_t need = (5 * ME + 4 * WE) * sizeof(_Float16);
    if (ws_size < need) return;

    _Float16* xh  = (_Float16*)d_ws;
    _Float16* Wt  = xh + ME;
    _Float16* Wto = Wt + 3 * WE;
    _Float16* Qh  = Wto + WE;
    _Float16* Kh  = Qh + ME;
    _Float16* VhT = Kh + ME;   // V stored transposed [B,H,D,T] by the GEMM
    _Float16* Ow  = VhT + ME;

    // fused prep: 4 weight transposes + x cast in one dispatch
    prep_all<<<dim3(EMB / 32, EMB / 32, 5), 256, 0, stream>>>(
        x, Wq, Wk, Wv, Wo, xh, Wt, Wto);

    gemm_qkv<<<dim3(3 * EMB / 128, MTOT / 128), 256, 0, stream>>>(
        xh, Wt, Qh, Kh, VhT);

    attn_mfma<<<dim3(SEQ / 128, BATCH * NUM_HEADS), 256, 0, stream>>>(Qh, Kh, VhT, Ow);

    gemm_out<<<dim3(EMB / 64, MTOT / 128), 256, 0, stream>>>(
        Ow, Wto, out, bo);
}

// Round 16
// 112.596 us; speedup vs baseline: 13.6647x; 1.0361x over previous
//
#include <hip/hip_runtime.h>

typedef __attribute__((ext_vector_type(8))) _Float16 f16x8;
typedef __attribute__((ext_vector_type(4))) _Float16 f16x4;
typedef __attribute__((ext_vector_type(2))) _Float16 f16x2;
typedef __attribute__((ext_vector_type(2))) __fp16   fp16x2_raw;
typedef __attribute__((ext_vector_type(4))) float    f32x4;

#define NUM_HEADS 16
#define HEAD_D 64
#define EMB 1024
#define SEQ 2048
#define BATCH 2
#define MTOT (BATCH * SEQ) // 4096

// Q scale: 1/sqrt(64) * log2(e)  (softmax runs in exp2 domain)
#define QALPHA 0.18033688011112042f

__device__ __forceinline__ f16x2 cvt_pk_f16(float lo, float hi)
{
    fp16x2_raw r = __builtin_amdgcn_cvt_pkrtz(lo, hi);
    return __builtin_bit_cast(f16x2, r);
}

// Raw v_exp_f32 (2^x). Guarded: fall back to fast __expf if builtin absent.
#if defined(__has_builtin)
#if __has_builtin(__builtin_amdgcn_exp2f)
#define HAVE_EXP2 1
#endif
#endif
__device__ __forceinline__ float fast_exp2(float x)
{
#ifdef HAVE_EXP2
    return __builtin_amdgcn_exp2f(x);
#else
    return __expf(x * 0.6931471805599453f);
#endif
}

// ---------------------------------------------------------------------------
// global -> LDS direct staging (16 B per lane). LDS dest is wave-uniform
// base + lane*16 (HW behavior); fallback reg-stages to the same address.
// ---------------------------------------------------------------------------
#if defined(__has_builtin)
#if __has_builtin(__builtin_amdgcn_global_load_lds)
#define HAVE_GLOAD_LDS 1
#endif
#endif

__device__ __forceinline__ void stage16(const void* g, void* ldsWaveBase, int lane)
{
#ifdef HAVE_GLOAD_LDS
    __builtin_amdgcn_global_load_lds(
        (const __attribute__((address_space(1))) void*)g,
        (__attribute__((address_space(3))) void*)ldsWaveBase, 16, 0, 0);
    (void)lane;
#else
    *(f16x8*)((char*)ldsWaveBase + lane * 16) = *(const f16x8*)g;
#endif
}

// ---------------------------------------------------------------------------
// Fused prep: grid (32,32,5), 256 threads.
//  z=0..3 : transpose+cast W (z<3 -> Wt + z*WE, z=3 -> Wto)
//  z=4    : cast x -> xh (2 f16x8 chunks per thread)
// ---------------------------------------------------------------------------
__global__ __launch_bounds__(256) void prep_all(
    const float* __restrict__ x,
    const float* __restrict__ Wq, const float* __restrict__ Wk,
    const float* __restrict__ Wv, const float* __restrict__ Wo,
    _Float16* __restrict__ xh, _Float16* __restrict__ Wt,
    _Float16* __restrict__ Wto)
{
    const int z = blockIdx.z;
    if (z == 4) {
        int base = ((blockIdx.y * 32 + blockIdx.x) * 256 + threadIdx.x) * 2;
        #pragma unroll
        for (int t = 0; t < 2; ++t) {
            int i = base + t;
            float4 a = ((const float4*)x)[i * 2];
            float4 b = ((const float4*)x)[i * 2 + 1];
            f16x8 o;
            o[0] = (_Float16)a.x; o[1] = (_Float16)a.y;
            o[2] = (_Float16)a.z; o[3] = (_Float16)a.w;
            o[4] = (_Float16)b.x; o[5] = (_Float16)b.y;
            o[6] = (_Float16)b.z; o[7] = (_Float16)b.w;
            ((f16x8*)xh)[i] = o;
        }
        return;
    }
    const float* W = z == 0 ? Wq : (z == 1 ? Wk : (z == 2 ? Wv : Wo));
    _Float16* D = (z == 3) ? Wto : (Wt + (size_t)z * EMB * EMB);
    __shared__ float tile[32][33];
    const int tx = threadIdx.x & 31, ty = threadIdx.x >> 5; // (32, 8)
    const int n0 = blockIdx.x * 32, k0 = blockIdx.y * 32;
    #pragma unroll
    for (int j = 0; j < 4; ++j)
        tile[ty + j * 8][tx] = W[(size_t)(k0 + ty + j * 8) * EMB + n0 + tx];
    __syncthreads();
    #pragma unroll
    for (int j = 0; j < 4; ++j)
        D[(size_t)(n0 + ty + j * 8) * EMB + k0 + tx] =
            (_Float16)tile[tx][ty + j * 8];
}

// ---------------------------------------------------------------------------
// Fused QKV GEMM: [4096, 3072] = xh @ Wt^T. 128x128 tile, BK=32, 4 waves.
// XCD swizzle: col-major tile order, contiguous x-band per XCD.
// Q,K written [B,H,T,D] (Q scaled by QALPHA); V written transposed [B,H,D,T].
// ---------------------------------------------------------------------------
__global__ __launch_bounds__(256) void gemm_qkv(
    const _Float16* __restrict__ A, const _Float16* __restrict__ Bt,
    _Float16* __restrict__ Qh, _Float16* __restrict__ Kh,
    _Float16* __restrict__ VhT)
{
    __shared__ __align__(16) _Float16 As[128 * 32]; // 8 KB
    __shared__ __align__(16) _Float16 Bs[128 * 32]; // 8 KB

    const int tid = threadIdx.x;
    const int w = tid >> 6, lane = tid & 63;
    const int l15 = lane & 15, g4 = lane >> 4;
    const int wm = w >> 1, wn = w & 1;

    // XCD-aware bijective remap (nwg = 768, 768 % 8 == 0)
    const int wg = blockIdx.y * gridDim.x + blockIdx.x;
    const int t  = (wg & 7) * 96 + (wg >> 3);
    const int bx = t >> 5, by = t & 31;     // col-major tile order
    const int row0 = by * 128, col0 = bx * 128;

    f32x4 acc[4][4];
    #pragma unroll
    for (int mt = 0; mt < 4; ++mt)
        #pragma unroll
        for (int nt = 0; nt < 4; ++nt)
            acc[mt][nt] = (f32x4){0.f, 0.f, 0.f, 0.f};

    for (int k0 = 0; k0 < EMB; k0 += 32) {
        __syncthreads();
        #pragma unroll
        for (int i = 0; i < 2; ++i) {
            int c = (i << 8) + tid;
            int row = c >> 2, u = c & 3;
            stage16(&A[(size_t)(row0 + row) * EMB + k0 + (u << 3)],
                    (char*)As + (i << 12) + (w << 10), lane);
            stage16(&Bt[(size_t)(col0 + row) * EMB + k0 + (u << 3)],
                    (char*)Bs + (i << 12) + (w << 10), lane);
        }
        __syncthreads();

        f16x8 af[4], bf[4];
        #pragma unroll
        for (int mt = 0; mt < 4; ++mt)
            af[mt] = *(const f16x8*)((const char*)As +
                     ((wm << 6) + (mt << 4) + l15) * 64 + (g4 << 4));
        #pragma unroll
        for (int nt = 0; nt < 4; ++nt)
            bf[nt] = *(const f16x8*)((const char*)Bs +
                     ((wn << 6) + (nt << 4) + l15) * 64 + (g4 << 4));
        #pragma unroll
        for (int mt = 0; mt < 4; ++mt)
            #pragma unroll
            for (int nt = 0; nt < 4; ++nt)
                acc[mt][nt] = __builtin_amdgcn_mfma_f32_16x16x32_f16(
                    af[mt], bf[nt], acc[mt][nt], 0, 0, 0);
    }

    // Epilogue. C/D: col = lane&15, row = 4*(lane>>4) + reg.
    #pragma unroll
    for (int mt = 0; mt < 4; ++mt) {
        int m = row0 + (wm << 6) + (mt << 4) + (g4 << 2);
        #pragma unroll
        for (int nt = 0; nt < 4; ++nt) {
            int gcol = col0 + (wn << 6) + (nt << 4) + l15;
            int proj = gcol >> 10, pc = gcol & 1023;
            int h = pc >> 6, d = pc & 63;
            int b = m >> 11, tt = m & 2047;
            int bh = b * NUM_HEADS + h;
            if (proj == 2) {
                f16x4 v4;
                v4[0] = (_Float16)acc[mt][nt][0];
                v4[1] = (_Float16)acc[mt][nt][1];
                v4[2] = (_Float16)acc[mt][nt][2];
                v4[3] = (_Float16)acc[mt][nt][3];
                *(f16x4*)&VhT[((size_t)bh * HEAD_D + d) * SEQ + tt] = v4;
            } else {
                _Float16* dst = proj == 0 ? Qh : Kh;
                float alpha = proj == 0 ? QALPHA : 1.0f;
                #pragma unroll
                for (int r = 0; r < 4; ++r)
                    dst[((size_t)bh * SEQ + tt + r) * HEAD_D + d] =
                        (_Float16)(acc[mt][nt][r] * alpha);
            }
        }
    }
}

// ---------------------------------------------------------------------------
// Output projection GEMM: [4096, 1024] fp32 + bias. 128x64 tile (512 blocks
// = 2/CU), BK=32, 4 waves, wave tile 64x32. XCD swizzle (nwg = 512).
// ---------------------------------------------------------------------------
__global__ __launch_bounds__(256) void gemm_out(
    const _Float16* __restrict__ A, const _Float16* __restrict__ Bt,
    float* __restrict__ outf, const float* __restrict__ bias)
{
    __shared__ __align__(16) _Float16 As[128 * 32]; // 8 KB
    __shared__ __align__(16) _Float16 Bs[64 * 32];  // 4 KB

    const int tid = threadIdx.x;
    const int w = tid >> 6, lane = tid & 63;
    const int l15 = lane & 15, g4 = lane >> 4;
    const int wm = w >> 1, wn = w & 1;

    const int wg = blockIdx.y * gridDim.x + blockIdx.x;
    const int t  = (wg & 7) * 64 + (wg >> 3);
    const int bx = t >> 5, by = t & 31;
    const int row0 = by * 128, col0 = bx * 64;

    f32x4 acc[4][2];
    #pragma unroll
    for (int mt = 0; mt < 4; ++mt)
        #pragma unroll
        for (int nt = 0; nt < 2; ++nt)
            acc[mt][nt] = (f32x4){0.f, 0.f, 0.f, 0.f};

    for (int k0 = 0; k0 < EMB; k0 += 32) {
        __syncthreads();
        #pragma unroll
        for (int i = 0; i < 2; ++i) {
            int c = (i << 8) + tid;
            int row = c >> 2, u = c & 3;
            stage16(&A[(size_t)(row0 + row) * EMB + k0 + (u << 3)],
                    (char*)As + (i << 12) + (w << 10), lane);
        }
        {
            int row = tid >> 2, u = tid & 3; // 256 chunks: 64 rows x 4 units
            stage16(&Bt[(size_t)(col0 + row) * EMB + k0 + (u << 3)],
                    (char*)Bs + (w << 10), lane);
        }
        __syncthreads();

        f16x8 af[4], bf[2];
        #pragma unroll
        for (int mt = 0; mt < 4; ++mt)
            af[mt] = *(const f16x8*)((const char*)As +
                     ((wm << 6) + (mt << 4) + l15) * 64 + (g4 << 4));
        #pragma unroll
        for (int nt = 0; nt < 2; ++nt)
            bf[nt] = *(const f16x8*)((const char*)Bs +
                     ((wn << 5) + (nt << 4) + l15) * 64 + (g4 << 4));
        #pragma unroll
        for (int mt = 0; mt < 4; ++mt)
            #pragma unroll
            for (int nt = 0; nt < 2; ++nt)
                acc[mt][nt] = __builtin_amdgcn_mfma_f32_16x16x32_f16(
                    af[mt], bf[nt], acc[mt][nt], 0, 0, 0);
    }

    #pragma unroll
    for (int mt = 0; mt < 4; ++mt) {
        int m = row0 + (wm << 6) + (mt << 4) + (g4 << 2);
        #pragma unroll
        for (int nt = 0; nt < 2; ++nt) {
            int gcol = col0 + (wn << 5) + (nt << 4) + l15;
            float bz = bias[gcol];
            #pragma unroll
            for (int r = 0; r < 4; ++r)
                outf[(size_t)(m + r) * EMB + gcol] = acc[mt][nt][r] + bz;
        }
    }
}

// ---------------------------------------------------------------------------
// Stage one 64-kv K tile + V^T tile into LDS via global_load_lds with
// pre-swizzled global source (LDS dest linear; chunk (row,u) holds global
// (row, u^(row&7)) -> read formulas identical to the verified K-frag path).
// ---------------------------------------------------------------------------
__device__ __forceinline__ void stage_kv_tile(
    const _Float16* __restrict__ KhB, const _Float16* __restrict__ VtB,
    int kv0, char* __restrict__ KsBuf, char* __restrict__ VtBuf,
    int w, int lane)
{
    #pragma unroll
    for (int i = 0; i < 2; ++i) {
        int c = (i << 8) + (w << 6) + lane;
        int row = c >> 3, u = c & 7;
        int us = u ^ (row & 7);
        stage16(&KhB[(size_t)(kv0 + row) * HEAD_D + (us << 3)],
                KsBuf + (i << 12) + (w << 10), lane);
        stage16(&VtB[(size_t)row * SEQ + kv0 + (us << 3)],
                VtBuf + (i << 12) + (w << 10), lane);
    }
}

// ---------------------------------------------------------------------------
// Single 64q x 64kv attention tile step (verified R15 form): S^T = K Q^T,
// shuffle-free defer-max softmax, per-lane partial l, P roundtrip, PV.
// ---------------------------------------------------------------------------
__device__ __forceinline__ void attn_tile(
    const char* __restrict__ KsC, const char* __restrict__ VtC,
    char* __restrict__ pwv,
    f16x8 qf0, f16x8 qf1, f32x4 (&acc)[4], float& m, float& l,
    bool diag, int qrel, int l15, int g)
{
    f32x4 st[4];
    #pragma unroll
    for (int nt = 0; nt < 4; ++nt) {
        int kvl = (nt << 4) + l15;
        f16x8 kf0 = *(const f16x8*)&KsC[kvl * 128 + (((g << 4)) ^ ((kvl & 7) << 4))];
        f16x8 kf1 = *(const f16x8*)&KsC[kvl * 128 + ((64 + (g << 4)) ^ ((kvl & 7) << 4))];
        f32x4 z = (f32x4){0.f, 0.f, 0.f, 0.f};
        z = __builtin_amdgcn_mfma_f32_16x16x32_f16(kf0, qf0, z, 0, 0, 0);
        z = __builtin_amdgcn_mfma_f32_16x16x32_f16(kf1, qf1, z, 0, 0, 0);
        st[nt] = z;
    }
    if (diag) {
        #pragma unroll
        for (int nt = 0; nt < 4; ++nt)
            #pragma unroll
            for (int r = 0; r < 4; ++r)
                if ((nt << 4) + (g << 2) + r > qrel) st[nt][r] = -1e30f;
    }

    float mx;
    {
        float a0 = fmaxf(fmaxf(st[0][0], st[0][1]), fmaxf(st[0][2], st[0][3]));
        float a1 = fmaxf(fmaxf(st[1][0], st[1][1]), fmaxf(st[1][2], st[1][3]));
        float a2 = fmaxf(fmaxf(st[2][0], st[2][1]), fmaxf(st[2][2], st[2][3]));
        float a3 = fmaxf(fmaxf(st[3][0], st[3][1]), fmaxf(st[3][2], st[3][3]));
        mx = fmaxf(fmaxf(a0, a1), fmaxf(a2, a3));
    }

    if (!__all(mx - m <= 8.0f)) {
        float mxr = fmaxf(mx, __shfl_xor(mx, 16));
        mxr = fmaxf(mxr, __shfl_xor(mxr, 32));
        float nm = fmaxf(m, mxr);
        float sc = fast_exp2(m - nm);   // row-uniform
        m = nm;
        l *= sc;
        #pragma unroll
        for (int r = 0; r < 4; ++r) {
            float scr = __shfl(sc, (g << 2) + r);
            acc[0][r] *= scr; acc[1][r] *= scr;
            acc[2][r] *= scr; acc[3][r] *= scr;
        }
    }

    float ps = 0.f;
    #pragma unroll
    for (int nt = 0; nt < 4; ++nt)
        #pragma unroll
        for (int r = 0; r < 4; ++r) {
            float p = fast_exp2(st[nt][r] - m);
            st[nt][r] = p;
            ps += p;
        }
    l += ps;

    #pragma unroll
    for (int nt = 0; nt < 4; ++nt)
        #pragma unroll
        for (int rr = 0; rr < 2; ++rr) {
            int kvb = (nt << 4) + (g << 2) + (rr << 1);
            f16x2 pv = cvt_pk_f16(st[nt][rr * 2], st[nt][rr * 2 + 1]);
            *(f16x2*)&pwv[l15 * 128 + ((kvb << 1) ^ ((l15 & 7) << 4))] = pv;
        }
    f16x8 pa0 = *(const f16x8*)&pwv[l15 * 128 + (((g << 4)) ^ ((l15 & 7) << 4))];
    f16x8 pa1 = *(const f16x8*)&pwv[l15 * 128 + ((64 + (g << 4)) ^ ((l15 & 7) << 4))];

    #pragma unroll
    for (int dn = 0; dn < 4; ++dn) {
        int d = (dn << 4) + l15;
        f16x8 vf0 = *(const f16x8*)&VtC[d * 128 + (((g << 4)) ^ ((d & 7) << 4))];
        f16x8 vf1 = *(const f16x8*)&VtC[d * 128 + ((64 + (g << 4)) ^ ((d & 7) << 4))];
        acc[dn] = __builtin_amdgcn_mfma_f32_16x16x32_f16(pa0, vf0, acc[dn], 0, 0, 0);
        acc[dn] = __builtin_amdgcn_mfma_f32_16x16x32_f16(pa1, vf1, acc[dn], 0, 0, 0);
    }
}

// ---------------------------------------------------------------------------
// R16: dual-kv tile step for one chain: QK over BOTH tiles, ONE merged
// softmax pass (single ballot + exp sweep over 32 values), two P->PV steps
// reusing the same wave-private P region (same-wave lgkmcnt orders the WAR).
// diag only ever on the SECOND tile (pairs end at qtB).
// ---------------------------------------------------------------------------
__device__ __forceinline__ void attn_tile2(
    const char* __restrict__ Ks0, const char* __restrict__ Vt0,
    const char* __restrict__ Ks1, const char* __restrict__ Vt1,
    char* __restrict__ pwv,
    f16x8 qf0, f16x8 qf1, f32x4 (&acc)[4], float& m, float& l,
    bool diag1, int qrel, int l15, int g)
{
    f32x4 st[8];
    #pragma unroll
    for (int nt = 0; nt < 4; ++nt) {
        int kvl = (nt << 4) + l15;
        int off0 = kvl * 128 + (((g << 4)) ^ ((kvl & 7) << 4));
        int off1 = kvl * 128 + ((64 + (g << 4)) ^ ((kvl & 7) << 4));
        f16x8 ka0 = *(const f16x8*)&Ks0[off0];
        f16x8 ka1 = *(const f16x8*)&Ks0[off1];
        f32x4 z = (f32x4){0.f, 0.f, 0.f, 0.f};
        z = __builtin_amdgcn_mfma_f32_16x16x32_f16(ka0, qf0, z, 0, 0, 0);
        z = __builtin_amdgcn_mfma_f32_16x16x32_f16(ka1, qf1, z, 0, 0, 0);
        st[nt] = z;
        f16x8 kb0 = *(const f16x8*)&Ks1[off0];
        f16x8 kb1 = *(const f16x8*)&Ks1[off1];
        f32x4 z2 = (f32x4){0.f, 0.f, 0.f, 0.f};
        z2 = __builtin_amdgcn_mfma_f32_16x16x32_f16(kb0, qf0, z2, 0, 0, 0);
        z2 = __builtin_amdgcn_mfma_f32_16x16x32_f16(kb1, qf1, z2, 0, 0, 0);
        st[4 + nt] = z2;
    }
    if (diag1) {
        #pragma unroll
        for (int nt = 0; nt < 4; ++nt)
            #pragma unroll
            for (int r = 0; r < 4; ++r)
                if ((nt << 4) + (g << 2) + r > qrel) st[4 + nt][r] = -1e30f;
    }

    float mx;
    {
        float a = -1e30f;
        #pragma unroll
        for (int i = 0; i < 8; ++i)
            a = fmaxf(a, fmaxf(fmaxf(st[i][0], st[i][1]),
                               fmaxf(st[i][2], st[i][3])));
        mx = a;
    }

    if (!__all(mx - m <= 8.0f)) {
        float mxr = fmaxf(mx, __shfl_xor(mx, 16));
        mxr = fmaxf(mxr, __shfl_xor(mxr, 32));
        float nm = fmaxf(m, mxr);
        float sc = fast_exp2(m - nm);
        m = nm;
        l *= sc;
        #pragma unroll
        for (int r = 0; r < 4; ++r) {
            float scr = __shfl(sc, (g << 2) + r);
            acc[0][r] *= scr; acc[1][r] *= scr;
            acc[2][r] *= scr; acc[3][r] *= scr;
        }
    }

    float ps = 0.f;
    #pragma unroll
    for (int i = 0; i < 8; ++i)
        #pragma unroll
        for (int r = 0; r < 4; ++r) {
            float p = fast_exp2(st[i][r] - m);
            st[i][r] = p;
            ps += p;
        }
    l += ps;

    // PV for tile 0, then tile 1 (same P region; same-wave ordering)
    #pragma unroll
    for (int tile = 0; tile < 2; ++tile) {
        const f32x4* s4 = &st[tile << 2];
        const char* Vt = tile ? Vt1 : Vt0;
        #pragma unroll
        for (int nt = 0; nt < 4; ++nt)
            #pragma unroll
            for (int rr = 0; rr < 2; ++rr) {
                int kvb = (nt << 4) + (g << 2) + (rr << 1);
                f16x2 pv = cvt_pk_f16(s4[nt][rr * 2], s4[nt][rr * 2 + 1]);
                *(f16x2*)&pwv[l15 * 128 + ((kvb << 1) ^ ((l15 & 7) << 4))] = pv;
            }
        f16x8 pa0 = *(const f16x8*)&pwv[l15 * 128 + (((g << 4)) ^ ((l15 & 7) << 4))];
        f16x8 pa1 = *(const f16x8*)&pwv[l15 * 128 + ((64 + (g << 4)) ^ ((l15 & 7) << 4))];
        #pragma unroll
        for (int dn = 0; dn < 4; ++dn) {
            int d = (dn << 4) + l15;
            f16x8 vf0 = *(const f16x8*)&Vt[d * 128 + (((g << 4)) ^ ((d & 7) << 4))];
            f16x8 vf1 = *(const f16x8*)&Vt[d * 128 + ((64 + (g << 4)) ^ ((d & 7) << 4))];
            acc[dn] = __builtin_amdgcn_mfma_f32_16x16x32_f16(pa0, vf0, acc[dn], 0, 0, 0);
            acc[dn] = __builtin_amdgcn_mfma_f32_16x16x32_f16(pa1, vf1, acc[dn], 0, 0, 0);
        }
    }
}

// ---------------------------------------------------------------------------
// Flash attention, causal, fp16 MFMA. R16: paired q-tiles (qtA, 31-qtA) with
// UNIFORM 17 iterations per block: (qtA+1) dual-chain single-kv iterations,
// 1 single-B, then (15-qtA) dual-kv B iterations (merged softmax). K/V^T in
// a 4-slot LDS ring (slot = kt & 3, prefetch distance 2, glds direct).
// ---------------------------------------------------------------------------
__global__ __launch_bounds__(256, 4) void attn_mfma(
    const _Float16* __restrict__ Qh, const _Float16* __restrict__ Kh,
    const _Float16* __restrict__ VhT, _Float16* __restrict__ O)
{
    __shared__ char lds[80 * 1024];
    // Ks slot s: s*8192 (32 KB) | Vt slot s: 32768 + s*8192 (32 KB)
    // PwA: 65536 + w*2048 | PwB: 73728 + w*2048
#define KSLOT(s) (lds + ((s) << 13))
#define VSLOT(s) (lds + 32768 + ((s) << 13))

    const int qtA = blockIdx.x;            // 0..15
    const int qtB = (SEQ / 64 - 1) - qtA;  // 31..16
    const int bh = blockIdx.y;
    const int q0A = qtA << 6, q0B = qtB << 6;
    const int tid = threadIdx.x;
    const int w = tid >> 6, lane = tid & 63;
    const int l15 = lane & 15, g = lane >> 4;

    const _Float16* KhB = Kh  + (size_t)bh * SEQ * HEAD_D;
    const _Float16* VtB = VhT + (size_t)bh * HEAD_D * SEQ;
    const size_t headbase = (size_t)bh * SEQ * HEAD_D;

    const int qrowA = q0A + (w << 4) + l15;
    const int qrowB = q0B + (w << 4) + l15;
    f16x8 qfA0 = *(const f16x8*)&Qh[headbase + (size_t)qrowA * HEAD_D + (g << 3)];
    f16x8 qfA1 = *(const f16x8*)&Qh[headbase + (size_t)qrowA * HEAD_D + 32 + (g << 3)];
    f16x8 qfB0 = *(const f16x8*)&Qh[headbase + (size_t)qrowB * HEAD_D + (g << 3)];
    f16x8 qfB1 = *(const f16x8*)&Qh[headbase + (size_t)qrowB * HEAD_D + 32 + (g << 3)];

    f32x4 accA[4], accB[4];
    #pragma unroll
    for (int dn = 0; dn < 4; ++dn) {
        accA[dn] = (f32x4){0.f, 0.f, 0.f, 0.f};
        accB[dn] = (f32x4){0.f, 0.f, 0.f, 0.f};
    }
    float mA = -1e30f, lA = 0.f, mB = -1e30f, lB = 0.f;

    // ---- prologue: stage tiles 0 and 1 ----
    stage_kv_tile(KhB, VtB, 0,  KSLOT(0), VSLOT(0), w, lane);
    stage_kv_tile(KhB, VtB, 64, KSLOT(1), VSLOT(1), w, lane);
    __syncthreads();

    char* pwvA = lds + 65536 + (w << 11);
    char* pwvB = lds + 73728 + (w << 11);
    const int qrel = (w << 4) + l15;

    // ---- phase 1: kt = 0..qtA, shared kv, dual chains ----
    for (int kt = 0; kt <= qtA; ++kt) {
        int pf = kt + 2;
        if (pf <= qtB)
            stage_kv_tile(KhB, VtB, pf << 6, KSLOT(pf & 3), VSLOT(pf & 3), w, lane);
        attn_tile(KSLOT(kt & 3), VSLOT(kt & 3), pwvA, qfA0, qfA1, accA, mA, lA,
                  kt == qtA, qrel, l15, g);
        attn_tile(KSLOT(kt & 3), VSLOT(kt & 3), pwvB, qfB0, qfB1, accB, mB, lB,
                  false, qrel, l15, g);
        __syncthreads();
    }

    // ---- phase 2 head: single B tile at kt = qtA+1 (diag iff == qtB) ----
    {
        int kt = qtA + 1;
        int pf = kt + 2;
        if (pf <= qtB)
            stage_kv_tile(KhB, VtB, pf << 6, KSLOT(pf & 3), VSLOT(pf & 3), w, lane);
        attn_tile(KSLOT(kt & 3), VSLOT(kt & 3), pwvB, qfB0, qfB1, accB, mB, lB,
                  kt == qtB, qrel, l15, g);
        __syncthreads();
    }

    // ---- phase 2 pairs: kt = qtA+2, step 2, through qtB ----
    for (int kt = qtA + 2; kt < qtB; kt += 2) {
        int pf0 = kt + 2, pf1 = kt + 3;
        if (pf0 <= qtB)
            stage_kv_tile(KhB, VtB, pf0 << 6, KSLOT(pf0 & 3), VSLOT(pf0 & 3), w, lane);
        if (pf1 <= qtB)
            stage_kv_tile(KhB, VtB, pf1 << 6, KSLOT(pf1 & 3), VSLOT(pf1 & 3), w, lane);
        attn_tile2(KSLOT(kt & 3), VSLOT(kt & 3),
                   KSLOT((kt + 1) & 3), VSLOT((kt + 1) & 3),
                   pwvB, qfB0, qfB1, accB, mB, lB,
                   (kt + 1) == qtB, qrel, l15, g);
        __syncthreads();
    }

    // ---- epilogue: deferred l reduction, normalize, store ----
    lA += __shfl_xor(lA, 16); lA += __shfl_xor(lA, 32);
    lB += __shfl_xor(lB, 16); lB += __shfl_xor(lB, 32);
    const int b = bh >> 4, h = bh & 15;
    const float rlA = 1.f / lA, rlB = 1.f / lB;
    #pragma unroll
    for (int r = 0; r < 4; ++r) {
        float invA = __shfl(rlA, (g << 2) + r);
        float invB = __shfl(rlB, (g << 2) + r);
        int tokA = (b << 11) + q0A + (w << 4) + (g << 2) + r;
        int tokB = (b << 11) + q0B + (w << 4) + (g << 2) + r;
        #pragma unroll
        for (int dn = 0; dn < 4; ++dn) {
            O[(size_t)tokA * EMB + (h << 6) + (dn << 4) + l15] =
                (_Float16)(accA[dn][r] * invA);
            O[(size_t)tokB * EMB + (h << 6) + (dn << 4) + l15] =
                (_Float16)(accB[dn][r] * invB);
        }
    }
#undef KSLOT
#undef VSLOT
}

// ---------------------------------------------------------------------------
extern "C" void kernel_launch(void* const* d_in, const int* in_sizes, int n_in,
                              void* d_out, int out_size, void* d_ws, size_t ws_size,
                              hipStream_t stream)
{
    const float* x  = (const float*)d_in[0];
    const float* Wq = (const float*)d_in[1];
    const float* Wk = (const float*)d_in[2];
    const float* Wv = (const float*)d_in[3];
    const float* Wo = (const float*)d_in[4];
    const float* bo = (const float*)d_in[5];
    float* out = (float*)d_out;

    const size_t ME = (size_t)MTOT * EMB;        // 4M elems
    const size_t WE = (size_t)EMB * EMB;         // 1M elems
    const size_t need = (5 * ME + 4 * WE) * sizeof(_Float16);
    if (ws_size < need) return;

    _Float16* xh  = (_Float16*)d_ws;
    _Float16* Wt  = xh + ME;
    _Float16* Wto = Wt + 3 * WE;
    _Float16* Qh  = Wto + WE;
    _Float16* Kh  = Qh + ME;
    _Float16* VhT = Kh + ME;   // V stored transposed [B,H,D,T] by the GEMM
    _Float16* Ow  = VhT + ME;

    prep_all<<<dim3(EMB / 32, EMB / 32, 5), 256, 0, stream>>>(
        x, Wq, Wk, Wv, Wo, xh, Wt, Wto);

    gemm_qkv<<<dim3(3 * EMB / 128, MTOT / 128), 256, 0, stream>>>(
        xh, Wt, Qh, Kh, VhT);

    attn_mfma<<<dim3(SEQ / 128, BATCH * NUM_HEADS), 256, 0, stream>>>(Qh, Kh, VhT, Ow);

    gemm_out<<<dim3(EMB / 64, MTOT / 128), 256, 0, stream>>>(
        Ow, Wto, out, bo);
}